// Round 1
// baseline (1750.597 us; speedup 1.0000x reference)
//
#include <hip/hip_runtime.h>
#include <stdint.h>

#define DEVFN static __device__ __forceinline__

typedef __attribute__((ext_vector_type(8))) short short8;
typedef __attribute__((ext_vector_type(4))) float floatx4;

// ---------------- Threefry-2x32 (20 rounds), exactly as JAX ----------------
DEVFN uint32_t rotl32(uint32_t v, int d) { return (v << d) | (v >> (32 - d)); }

DEVFN void tf2x32(uint32_t k0, uint32_t k1, uint32_t x0, uint32_t x1,
                  uint32_t& o0, uint32_t& o1) {
  uint32_t k2 = k0 ^ k1 ^ 0x1BD11BDAu;
  x0 += k0; x1 += k1;
  x0 += x1; x1 = rotl32(x1, 13); x1 ^= x0;
  x0 += x1; x1 = rotl32(x1, 15); x1 ^= x0;
  x0 += x1; x1 = rotl32(x1, 26); x1 ^= x0;
  x0 += x1; x1 = rotl32(x1, 6);  x1 ^= x0;
  x0 += k1; x1 += k2 + 1u;
  x0 += x1; x1 = rotl32(x1, 17); x1 ^= x0;
  x0 += x1; x1 = rotl32(x1, 29); x1 ^= x0;
  x0 += x1; x1 = rotl32(x1, 16); x1 ^= x0;
  x0 += x1; x1 = rotl32(x1, 24); x1 ^= x0;
  x0 += k2; x1 += k0 + 2u;
  x0 += x1; x1 = rotl32(x1, 13); x1 ^= x0;
  x0 += x1; x1 = rotl32(x1, 15); x1 ^= x0;
  x0 += x1; x1 = rotl32(x1, 26); x1 ^= x0;
  x0 += x1; x1 = rotl32(x1, 6);  x1 ^= x0;
  x0 += k0; x1 += k1 + 3u;
  x0 += x1; x1 = rotl32(x1, 17); x1 ^= x0;
  x0 += x1; x1 = rotl32(x1, 29); x1 ^= x0;
  x0 += x1; x1 = rotl32(x1, 16); x1 ^= x0;
  x0 += x1; x1 = rotl32(x1, 24); x1 ^= x0;
  x0 += k1; x1 += k2 + 4u;
  x0 += x1; x1 = rotl32(x1, 13); x1 ^= x0;
  x0 += x1; x1 = rotl32(x1, 15); x1 ^= x0;
  x0 += x1; x1 = rotl32(x1, 26); x1 ^= x0;
  x0 += x1; x1 = rotl32(x1, 6);  x1 ^= x0;
  x0 += k2; x1 += k0 + 5u;
  o0 = x0; o1 = x1;
}

// ---------------- XLA/CHLO f32 erf_inv (Giles), w = -log1p(-x^2) -----------
DEVFN float erfinv_f32(float x) {
#pragma clang fp contract(off)
  float w = -log1pf(-(x * x));
  float p;
  if (w < 5.0f) {
    w = w - 2.5f;
    p = 2.81022636e-08f;
    p = 3.43273939e-07f + p * w;
    p = -3.5233877e-06f + p * w;
    p = -4.39150654e-06f + p * w;
    p = 0.00021858087f + p * w;
    p = -0.00125372503f + p * w;
    p = -0.00417768164f + p * w;
    p = 0.246640727f + p * w;
    p = 1.50140941f + p * w;
  } else {
    w = __fsqrt_rn(w) - 3.0f;
    p = -0.000200214257f;
    p = 0.000100950558f + p * w;
    p = 0.00134934322f + p * w;
    p = -0.00367342844f + p * w;
    p = 0.00573950773f + p * w;
    p = -0.0076224613f + p * w;
    p = 0.00943887047f + p * w;
    p = 1.00167406f + p * w;
    p = 2.83297682f + p * w;
  }
  return p * x;
}

// jax.nn.softplus(x) = logaddexp(x,0) = max(x,0) + log1p(exp(-|x|))
DEVFN float softplus_ref(float v) {
#pragma clang fp contract(off)
  return fmaxf(v, 0.0f) + log1pf(expf(-fabsf(v)));
}

// fp32 -> bf16 RNE
DEVFN ushort f2bf(float f) {
  uint32_t u = __float_as_uint(f);
  uint32_t r = (u + 0x7FFFu + ((u >> 16) & 1u)) >> 16;
  return (ushort)r;
}

// async global->LDS, 16 B per lane; lds must be wave-uniform base
DEVFN void gl2lds16(const void* g, void* l) {
  __builtin_amdgcn_global_load_lds(
      (const __attribute__((address_space(1))) void*)g,
      (__attribute__((address_space(3))) void*)l, 16, 0, 0);
}

// ---------------- fp32 GEMM: C = act(A[M,K] @ W[K,N] + bias) ----------------
// BM=BN=128, BK=16, 256 threads, 8x8 per thread. (encoder: must stay fp32 —
// logalpha feeds discrete accept/reject; bf16 noise would flip accepts)
template <int ACT>
__global__ __launch_bounds__(256) void gemm128(
    const float* __restrict__ A, const float* __restrict__ W,
    const float* __restrict__ bias, float* __restrict__ C0,
    float* __restrict__ C1, int M, int N, int K, int split) {
  __shared__ float As[16][132];
  __shared__ float Bs[16][132];
  const int tid = threadIdx.x;
  const int m0 = blockIdx.y * 128;
  const int n0 = blockIdx.x * 128;
  const int tx = tid & 15;
  const int ty = tid >> 4;
  float acc[8][8];
#pragma unroll
  for (int i = 0; i < 8; i++)
#pragma unroll
    for (int j = 0; j < 8; j++) acc[i][j] = 0.0f;

  const int arow = tid >> 2;
  const int acol = (tid & 3) << 2;
  const int brow = tid >> 5;
  const int bcol = (tid & 31) << 2;

  for (int k0 = 0; k0 < K; k0 += 16) {
#pragma unroll
    for (int h = 0; h < 2; h++) {
      int r = arow + h * 64;
      float4 a = *(const float4*)(A + (size_t)(m0 + r) * K + k0 + acol);
      As[acol + 0][r] = a.x; As[acol + 1][r] = a.y;
      As[acol + 2][r] = a.z; As[acol + 3][r] = a.w;
    }
#pragma unroll
    for (int h = 0; h < 2; h++) {
      int r = brow + h * 8;
      *(float4*)&Bs[r][bcol] =
          *(const float4*)(W + (size_t)(k0 + r) * N + n0 + bcol);
    }
    __syncthreads();
#pragma unroll
    for (int k = 0; k < 16; k++) {
      float af[8], bf[8];
      *(float4*)&af[0] = *(const float4*)&As[k][ty * 8];
      *(float4*)&af[4] = *(const float4*)&As[k][ty * 8 + 4];
      *(float4*)&bf[0] = *(const float4*)&Bs[k][tx * 8];
      *(float4*)&bf[4] = *(const float4*)&Bs[k][tx * 8 + 4];
#pragma unroll
      for (int i = 0; i < 8; i++)
#pragma unroll
        for (int j = 0; j < 8; j++) acc[i][j] = fmaf(af[i], bf[j], acc[i][j]);
    }
    __syncthreads();
  }

#pragma unroll
  for (int i = 0; i < 8; i++) {
    size_t row = (size_t)(m0 + ty * 8 + i);
#pragma unroll
    for (int j = 0; j < 8; j++) {
      int col = n0 + tx * 8 + j;
      float v = acc[i][j] + bias[col];
      if (ACT == 1) {
        v = fmaxf(v, 0.0f);
        C0[row * (size_t)N + col] = v;
      } else if (ACT == 3) {
        v = 1e-6f + softplus_ref(v);
        if (col < split) C0[row * (size_t)split + col] = v;
        else             C1[row * (size_t)split + (col - split)] = v;
      } else {
        C0[row * (size_t)N + col] = v;
      }
    }
  }
}

// ---------------- fused fc41 + fc42 (N=64 each): 1e-6+softplus --------------
__global__ __launch_bounds__(256) void dual64(
    const float* __restrict__ A, const float* __restrict__ W1,
    const float* __restrict__ b1, const float* __restrict__ W2,
    const float* __restrict__ b2, float* __restrict__ O1,
    float* __restrict__ O2, int K) {
  __shared__ float As[16][68];
  __shared__ float Bs[16][132];
  const int tid = threadIdx.x;
  const int m0 = blockIdx.x * 64;
  const int tx = tid & 31;
  const int ty = tid >> 5;
  float acc[8][4];
#pragma unroll
  for (int i = 0; i < 8; i++)
#pragma unroll
    for (int j = 0; j < 4; j++) acc[i][j] = 0.0f;

  const int arow = tid >> 2;
  const int acol = (tid & 3) << 2;
  const int brow = tid >> 5;
  const int bcol = (tid & 31) << 2;

  for (int k0 = 0; k0 < K; k0 += 16) {
    {
      float4 a = *(const float4*)(A + (size_t)(m0 + arow) * K + k0 + acol);
      As[acol + 0][arow] = a.x; As[acol + 1][arow] = a.y;
      As[acol + 2][arow] = a.z; As[acol + 3][arow] = a.w;
    }
#pragma unroll
    for (int h = 0; h < 2; h++) {
      int r = brow + h * 8;
      const float* src = (bcol < 64) ? (W1 + (size_t)(k0 + r) * 64 + bcol)
                                     : (W2 + (size_t)(k0 + r) * 64 + (bcol - 64));
      *(float4*)&Bs[r][bcol] = *(const float4*)src;
    }
    __syncthreads();
#pragma unroll
    for (int k = 0; k < 16; k++) {
      float af[8], bf[4];
      *(float4*)&af[0] = *(const float4*)&As[k][ty * 8];
      *(float4*)&af[4] = *(const float4*)&As[k][ty * 8 + 4];
      *(float4*)&bf[0] = *(const float4*)&Bs[k][tx * 4];
#pragma unroll
      for (int i = 0; i < 8; i++)
#pragma unroll
        for (int j = 0; j < 4; j++) acc[i][j] = fmaf(af[i], bf[j], acc[i][j]);
    }
    __syncthreads();
  }

#pragma unroll
  for (int i = 0; i < 8; i++) {
    size_t row = (size_t)(m0 + ty * 8 + i);
#pragma unroll
    for (int j = 0; j < 4; j++) {
      int col = tx * 4 + j;
      float bb = (col < 64) ? b1[col] : b2[col - 64];
      float v = 1e-6f + softplus_ref(acc[i][j] + bb);
      if (col < 64) O1[row * 64 + col] = v;
      else          O2[row * 64 + (col - 64)] = v;
    }
  }
}

// ---------------- Marsaglia-Tsang sampler, JAX partitionable threefry -------
// NOTE (round-0 fix): JAX's partitionable threefry returns bits1 ^ bits2 for
// 32-bit draws (_threefry_random_bits_partitionable). Using o0 alone gives a
// valid-looking but WRONG stream -> wholesale z mismatch (absmax 468).
__global__ __launch_bounds__(256) void gamma_sampler(
    const float* __restrict__ la, const float* __restrict__ lb,
    float* __restrict__ z, ushort* __restrict__ zb) {
#pragma clang fp contract(off)
  const uint32_t i = blockIdx.x * 256u + threadIdx.x;
  uint32_t k1a, k1b, k2a, k2b;
  tf2x32(0u, 42u, 0u, 0u, k1a, k1b);  // split: child key = both output words
  tf2x32(0u, 42u, 0u, 1u, k2a, k2b);

  const float LO = __uint_as_float(0xBF7FFFFFu);
  const float SQRT2 = __uint_as_float(0x3FB504F3u);
  const float USCALE = 1.0f - 1e-7f;

  const float al = la[i];
  const float be = lb[i];
  const float d = (al + 1.0f) - 0.33333334f;
  const float c = 1.0f / __fsqrt_rn(9.0f * d);

  float es = 0.0f, us = 0.0f;
  bool done = false;
  for (int k = 0; k < 24; k++) {
    if (__all(done)) break;
    if (!done) {
      uint32_t n = (uint32_t)k * 524288u + i;
      uint32_t o0, o1, p0, p1;
      tf2x32(k1a, k1b, 0u, n, o0, o1);
      tf2x32(k2a, k2b, 0u, n, p0, p1);
      uint32_t eb = o0 ^ o1;  // JAX: bits = bits1 ^ bits2 (32-bit path)
      uint32_t ub = p0 ^ p1;
      float f = __uint_as_float((eb >> 9) | 0x3F800000u) - 1.0f;
      float un = f * 2.0f + LO;
      un = fmaxf(LO, un);
      float e = SQRT2 * erfinv_f32(un);
      float g = __uint_as_float((ub >> 9) | 0x3F800000u) - 1.0f;
      float u = g * USCALE + 1e-7f;
      u = fmaxf(1e-7f, u);
      if (k == 0) { es = e; us = u; }
      float v = 1.0f + c * e;
      if (v > 0.0f) {
        float v3 = (v * v) * v;
        float e2 = e * e;
        bool acc = false;
        float sq = 1.0f - (0.0331f * e2) * e2;
        if (u < sq) acc = true;
        else {
          float rhs = (0.5f * e) * e + d * ((1.0f - v3) + logf(v3));
          if (logf(u) < rhs) acc = true;
        }
        if (acc) { es = e; us = u; done = true; }
      }
    }
  }
  float vv = 1.0f + c * es;
  float vs = (vv * vv) * vv;
  float t = logf(d * vs + 1e-6f) + logf(us + 1e-6f) / (al + 1e-6f);
  float zv = expf(t) / (be + 1e-6f);
  z[i] = zv;
  zb[i] = f2bf(zv);
}

// ---------------- transpose + fp32->bf16: out[c][r] = bf16(in[r][c]) --------
__global__ __launch_bounds__(256) void transpose_bf16(
    const float* __restrict__ in, ushort* __restrict__ out, int R, int C) {
  __shared__ float tile[32][33];
  const int c0 = blockIdx.x * 32, r0 = blockIdx.y * 32;
  const int tx = threadIdx.x & 31, ty = threadIdx.x >> 5;
#pragma unroll
  for (int i = ty; i < 32; i += 8)
    tile[i][tx] = in[(size_t)(r0 + i) * C + c0 + tx];
  __syncthreads();
#pragma unroll
  for (int i = ty; i < 32; i += 8)
    out[(size_t)(c0 + i) * R + r0 + tx] = f2bf(tile[tx][i]);
}

// ---------------- bf16 MFMA GEMM (m97-style): C = act(A @ Bt^T + bias) ------
// A [M,K] bf16 row-major, Bt [N,K] bf16 row-major (i.e. W^T).
// 128x128 tile, BK=32, 256 thr = 4 waves in 2x2, 16x16x32 MFMA, 4x4/wave.
// ACT 0: relu -> bf16 C0b[M,N];  ACT 3: 1e-6+softplus split -> fp32 C0f/C1f
template <int ACT>
__global__ __launch_bounds__(256) void gemm_bf16(
    const ushort* __restrict__ A, const ushort* __restrict__ Bt,
    const float* __restrict__ bias, ushort* __restrict__ C0b,
    float* __restrict__ C0f, float* __restrict__ C1f,
    int M, int N, int K, int split) {
  __shared__ ushort As[128 * 32];
  __shared__ ushort Bs[128 * 32];
  const int tid = threadIdx.x;
  const int wave = tid >> 6, lane = tid & 63;
  const int m0 = blockIdx.y * 128, n0 = blockIdx.x * 128;
  const int lrow = lane & 15, lq = lane >> 4;
  const int wm = wave & 1, wn = wave >> 1;
  const int srow = lane >> 2;       // 16 rows per wave-call
  const int scol = (lane & 3) * 8;  // k offset (elements)

  floatx4 acc[4][4];
#pragma unroll
  for (int i = 0; i < 4; i++)
#pragma unroll
    for (int j = 0; j < 4; j++) acc[i][j] = (floatx4){0.f, 0.f, 0.f, 0.f};

  for (int k0 = 0; k0 < K; k0 += 32) {
#pragma unroll
    for (int h = 0; h < 2; h++) {
      int r0 = wave * 32 + h * 16;
      gl2lds16(A + (size_t)(m0 + r0 + srow) * K + k0 + scol, &As[r0 * 32]);
      gl2lds16(Bt + (size_t)(n0 + r0 + srow) * K + k0 + scol, &Bs[r0 * 32]);
    }
    __syncthreads();   // compiler drains vmcnt before s_barrier
    short8 a[4], b[4];
#pragma unroll
    for (int i = 0; i < 4; i++) {
      a[i] = *(const short8*)&As[(wm * 64 + i * 16 + lrow) * 32 + lq * 8];
      b[i] = *(const short8*)&Bs[(wn * 64 + i * 16 + lrow) * 32 + lq * 8];
    }
#pragma unroll
    for (int i = 0; i < 4; i++)
#pragma unroll
      for (int j = 0; j < 4; j++)
        acc[i][j] = __builtin_amdgcn_mfma_f32_16x16x32_bf16(a[i], b[j],
                                                            acc[i][j], 0, 0, 0);
    __syncthreads();
  }

  // C/D layout: col = lane&15, row = (lane>>4)*4 + reg  [measured m89/m91]
#pragma unroll
  for (int i = 0; i < 4; i++) {
#pragma unroll
    for (int j = 0; j < 4; j++) {
      int colg = n0 + wn * 64 + j * 16 + lrow;
      float bb = bias[colg];
#pragma unroll
      for (int r = 0; r < 4; r++) {
        int rowg = m0 + wm * 64 + i * 16 + lq * 4 + r;
        float v = acc[i][j][r] + bb;
        if (ACT == 0) {
          v = fmaxf(v, 0.0f);
          C0b[(size_t)rowg * N + colg] = f2bf(v);
        } else {
          v = 1e-6f + softplus_ref(v);
          if (colg < split) C0f[(size_t)rowg * split + colg] = v;
          else              C1f[(size_t)rowg * split + (colg - split)] = v;
        }
      }
    }
  }
}

// ---------------------------------------------------------------------------
extern "C" void kernel_launch(void* const* d_in, const int* in_sizes, int n_in,
                              void* d_out, int out_size, void* d_ws,
                              size_t ws_size, hipStream_t stream) {
  const float* x   = (const float*)d_in[0];
  const float* w1  = (const float*)d_in[1];  const float* b1  = (const float*)d_in[2];
  const float* w2  = (const float*)d_in[3];  const float* b2  = (const float*)d_in[4];
  const float* w3  = (const float*)d_in[5];  const float* b3  = (const float*)d_in[6];
  const float* w41 = (const float*)d_in[7];  const float* b41 = (const float*)d_in[8];
  const float* w42 = (const float*)d_in[9];  const float* b42 = (const float*)d_in[10];
  const float* w4  = (const float*)d_in[11]; const float* b4  = (const float*)d_in[12];
  const float* w5  = (const float*)d_in[13]; const float* b5  = (const float*)d_in[14];
  const float* w6  = (const float*)d_in[15]; const float* b6  = (const float*)d_in[16];
  const float* w7  = (const float*)d_in[17]; const float* b7  = (const float*)d_in[18];
  float* out = (float*)d_out;
  float* ws  = (float*)d_ws;
  ushort* wsu = (ushort*)d_ws;

  // output layout (floats): recon_al | recon_be | logalpha | logbeta | z
  float* recon_a = out;
  float* recon_b = out + 16777216;
  float* la      = out + 33554432;
  float* lb      = out + 34078720;
  float* zz      = out + 34603008;

  // encoder fp32 workspace (floats)
  float* h1 = ws;               // [0, 8388608)
  float* h2 = ws + 8388608;     // [8388608, 16777216)
  float* h3 = ws + 16777216;    // [16777216, 33554432)

  // decoder bf16 workspace (ushorts) — reuses encoder regions after death:
  // zb..w7T sit inside h1 (dead after fc2); h4b spans h1-tail+h2 (dead after
  // fc3); h5b inside h2; h6b inside h3 (dead after dual64).
  ushort* zb  = wsu;             // 8192*64
  ushort* w4T = wsu + 524288;    // [2048,64]
  ushort* w5T = wsu + 655360;    // [1024,2048]
  ushort* w6T = wsu + 2752512;   // [1024,1024]
  ushort* w7T = wsu + 3801088;   // [4096,1024]
  ushort* h4b = wsu + 7995392;   // [8192,2048]
  ushort* h5b = wsu + 24772608;  // [8192,1024]
  ushort* h6b = wsu + 33161216;  // [8192,1024]

  dim3 blk(256);
  // encoder (exact fp32 — feeds accept/reject decisions)
  gemm128<1><<<dim3(8, 64),  blk, 0, stream>>>(x,  w1, b1, h1, nullptr, 8192, 1024, 2048, 0);
  gemm128<1><<<dim3(8, 64),  blk, 0, stream>>>(h1, w2, b2, h2, nullptr, 8192, 1024, 1024, 0);
  // h1 dead: convert decoder weights (transposed, bf16)
  transpose_bf16<<<dim3(64, 2),   blk, 0, stream>>>(w4, w4T, 64,   2048);
  transpose_bf16<<<dim3(32, 64),  blk, 0, stream>>>(w5, w5T, 2048, 1024);
  transpose_bf16<<<dim3(32, 32),  blk, 0, stream>>>(w6, w6T, 1024, 1024);
  transpose_bf16<<<dim3(128, 32), blk, 0, stream>>>(w7, w7T, 1024, 4096);
  gemm128<1><<<dim3(16, 64), blk, 0, stream>>>(h2, w3, b3, h3, nullptr, 8192, 2048, 1024, 0);
  dual64<<<dim3(128), blk, 0, stream>>>(h3, w41, b41, w42, b42, la, lb, 2048);
  // reparameterize (exact fp32; also emits bf16 z)
  gamma_sampler<<<dim3(2048), blk, 0, stream>>>(la, lb, zz, zb);
  // decoder (bf16 MFMA)
  gemm_bf16<0><<<dim3(16, 64), blk, 0, stream>>>(zb,  w4T, b4, h4b, nullptr, nullptr, 8192, 2048, 64, 0);
  gemm_bf16<0><<<dim3(8, 64),  blk, 0, stream>>>(h4b, w5T, b5, h5b, nullptr, nullptr, 8192, 1024, 2048, 0);
  gemm_bf16<0><<<dim3(8, 64),  blk, 0, stream>>>(h5b, w6T, b6, h6b, nullptr, nullptr, 8192, 1024, 1024, 0);
  gemm_bf16<3><<<dim3(32, 64), blk, 0, stream>>>(h6b, w7T, b7, nullptr, recon_a, recon_b, 8192, 4096, 1024, 2048);
  (void)in_sizes; (void)n_in; (void)out_size; (void)ws_size;
}

// Round 3
// 1262.489 us; speedup vs baseline: 1.3866x; 1.3866x over previous
//
#include <hip/hip_runtime.h>
#include <stdint.h>

#define DEVFN static __device__ __forceinline__

typedef __attribute__((ext_vector_type(8))) short short8;
typedef __attribute__((ext_vector_type(4))) float floatx4;
typedef _Float16 half8 __attribute__((ext_vector_type(8)));

// ---------------- Threefry-2x32 (20 rounds), exactly as JAX ----------------
DEVFN uint32_t rotl32(uint32_t v, int d) { return (v << d) | (v >> (32 - d)); }

DEVFN void tf2x32(uint32_t k0, uint32_t k1, uint32_t x0, uint32_t x1,
                  uint32_t& o0, uint32_t& o1) {
  uint32_t k2 = k0 ^ k1 ^ 0x1BD11BDAu;
  x0 += k0; x1 += k1;
  x0 += x1; x1 = rotl32(x1, 13); x1 ^= x0;
  x0 += x1; x1 = rotl32(x1, 15); x1 ^= x0;
  x0 += x1; x1 = rotl32(x1, 26); x1 ^= x0;
  x0 += x1; x1 = rotl32(x1, 6);  x1 ^= x0;
  x0 += k1; x1 += k2 + 1u;
  x0 += x1; x1 = rotl32(x1, 17); x1 ^= x0;
  x0 += x1; x1 = rotl32(x1, 29); x1 ^= x0;
  x0 += x1; x1 = rotl32(x1, 16); x1 ^= x0;
  x0 += x1; x1 = rotl32(x1, 24); x1 ^= x0;
  x0 += k2; x1 += k0 + 2u;
  x0 += x1; x1 = rotl32(x1, 13); x1 ^= x0;
  x0 += x1; x1 = rotl32(x1, 15); x1 ^= x0;
  x0 += x1; x1 = rotl32(x1, 26); x1 ^= x0;
  x0 += x1; x1 = rotl32(x1, 6);  x1 ^= x0;
  x0 += k0; x1 += k1 + 3u;
  x0 += x1; x1 = rotl32(x1, 17); x1 ^= x0;
  x0 += x1; x1 = rotl32(x1, 29); x1 ^= x0;
  x0 += x1; x1 = rotl32(x1, 16); x1 ^= x0;
  x0 += x1; x1 = rotl32(x1, 24); x1 ^= x0;
  x0 += k1; x1 += k2 + 4u;
  x0 += x1; x1 = rotl32(x1, 13); x1 ^= x0;
  x0 += x1; x1 = rotl32(x1, 15); x1 ^= x0;
  x0 += x1; x1 = rotl32(x1, 26); x1 ^= x0;
  x0 += x1; x1 = rotl32(x1, 6);  x1 ^= x0;
  x0 += k2; x1 += k0 + 5u;
  o0 = x0; o1 = x1;
}

// ---------------- XLA/CHLO f32 erf_inv (Giles), w = -log1p(-x^2) -----------
DEVFN float erfinv_f32(float x) {
#pragma clang fp contract(off)
  float w = -log1pf(-(x * x));
  float p;
  if (w < 5.0f) {
    w = w - 2.5f;
    p = 2.81022636e-08f;
    p = 3.43273939e-07f + p * w;
    p = -3.5233877e-06f + p * w;
    p = -4.39150654e-06f + p * w;
    p = 0.00021858087f + p * w;
    p = -0.00125372503f + p * w;
    p = -0.00417768164f + p * w;
    p = 0.246640727f + p * w;
    p = 1.50140941f + p * w;
  } else {
    w = __fsqrt_rn(w) - 3.0f;
    p = -0.000200214257f;
    p = 0.000100950558f + p * w;
    p = 0.00134934322f + p * w;
    p = -0.00367342844f + p * w;
    p = 0.00573950773f + p * w;
    p = -0.0076224613f + p * w;
    p = 0.00943887047f + p * w;
    p = 1.00167406f + p * w;
    p = 2.83297682f + p * w;
  }
  return p * x;
}

// jax.nn.softplus(x) = logaddexp(x,0) = max(x,0) + log1p(exp(-|x|))
DEVFN float softplus_ref(float v) {
#pragma clang fp contract(off)
  return fmaxf(v, 0.0f) + log1pf(expf(-fabsf(v)));
}

// fp32 -> bf16 RNE
DEVFN ushort f2bf(float f) {
  uint32_t u = __float_as_uint(f);
  uint32_t r = (u + 0x7FFFu + ((u >> 16) & 1u)) >> 16;
  return (ushort)r;
}

// fp32 -> (f16 hi, f16 lo*2048) split. a = hi + lo/2048 + O(2^-23 |a|).
// lo pre-scaled by 2^11 so it stays in f16 normal range (weights ~0.02
// would otherwise put every lo in subnormal territory -> FTZ risk in MFMA).
DEVFN void split2(float a, ushort& hb, ushort& lb) {
  _Float16 h = (_Float16)a;
  float r = (a - (float)h) * 2048.0f;  // a-hf exact (Sterbenz); *2^11 exact
  _Float16 l = (_Float16)r;
  hb = __builtin_bit_cast(unsigned short, h);
  lb = __builtin_bit_cast(unsigned short, l);
}

// async global->LDS, 16 B per lane; lds must be wave-uniform base
DEVFN void gl2lds16(const void* g, void* l) {
  __builtin_amdgcn_global_load_lds(
      (const __attribute__((address_space(1))) void*)g,
      (__attribute__((address_space(3))) void*)l, 16, 0, 0);
}

// ---------------- elementwise split: x -> (xh, xl) f16 pairs ----------------
__global__ __launch_bounds__(256) void split_f16(
    const float* __restrict__ in, ushort* __restrict__ oh,
    ushort* __restrict__ ol, int n4) {
  int idx = blockIdx.x * 256 + threadIdx.x;
  int stride = gridDim.x * 256;
  for (int i = idx; i < n4; i += stride) {
    float4 a = ((const float4*)in)[i];
    ushort h0, h1, h2, h3, l0, l1, l2, l3;
    split2(a.x, h0, l0); split2(a.y, h1, l1);
    split2(a.z, h2, l2); split2(a.w, h3, l3);
    ushort4 hv; hv.x = h0; hv.y = h1; hv.z = h2; hv.w = h3;
    ushort4 lv; lv.x = l0; lv.y = l1; lv.z = l2; lv.w = l3;
    ((ushort4*)oh)[i] = hv;
    ((ushort4*)ol)[i] = lv;
  }
}

// ---------------- transpose + f16-split: out*[c][r] = split(in[r][c]) -------
__global__ __launch_bounds__(256) void transpose_split_f16(
    const float* __restrict__ in, ushort* __restrict__ oh,
    ushort* __restrict__ ol, int R, int C) {
  __shared__ float tile[32][33];
  const int c0 = blockIdx.x * 32, r0 = blockIdx.y * 32;
  const int tx = threadIdx.x & 31, ty = threadIdx.x >> 5;
#pragma unroll
  for (int i = ty; i < 32; i += 8)
    tile[i][tx] = in[(size_t)(r0 + i) * C + c0 + tx];
  __syncthreads();
#pragma unroll
  for (int i = ty; i < 32; i += 8) {
    ushort hb, lb;
    split2(tile[tx][i], hb, lb);
    size_t o = (size_t)(c0 + i) * R + r0 + tx;
    oh[o] = hb; ol[o] = lb;
  }
}

// ---------------- split-f16 MFMA GEMM: C = act(A @ Bt^T + bias) -------------
// A ~ (Ah + Al/2048), Bt ~ (Bh + Bl/2048), all [.,K] row-major f16.
// acc1 = Ah*Bh ; acc2 = Ah*Bl + Al*Bh ; result = acc1 + acc2/2048  (fp32).
// Dropped Al*Bl/2048^2 ~ 2^-22 rel -> below fp32-reorder noise already
// tolerated by the accept/reject path. 128x128 tile, BK=32, 4 waves.
// ACT 1: relu -> f16-split pair (Oh,Ol). ACT 2: relu -> fp32 Of.
template <int ACT>
__global__ __launch_bounds__(256) void gemm_f16x3(
    const ushort* __restrict__ Ah, const ushort* __restrict__ Al,
    const ushort* __restrict__ Bh, const ushort* __restrict__ Bl,
    const float* __restrict__ bias, ushort* __restrict__ Oh,
    ushort* __restrict__ Ol, float* __restrict__ Of, int M, int N, int K) {
  __shared__ ushort AsH[128 * 32];
  __shared__ ushort AsL[128 * 32];
  __shared__ ushort BsH[128 * 32];
  __shared__ ushort BsL[128 * 32];
  const int tid = threadIdx.x;
  const int wave = tid >> 6, lane = tid & 63;
  const int m0 = blockIdx.y * 128, n0 = blockIdx.x * 128;
  const int lrow = lane & 15, lq = lane >> 4;
  const int wm = wave & 1, wn = wave >> 1;
  const int srow = lane >> 2;
  const int scol = (lane & 3) * 8;

  floatx4 acc1[4][4], acc2[4][4];
#pragma unroll
  for (int i = 0; i < 4; i++)
#pragma unroll
    for (int j = 0; j < 4; j++) {
      acc1[i][j] = (floatx4){0.f, 0.f, 0.f, 0.f};
      acc2[i][j] = (floatx4){0.f, 0.f, 0.f, 0.f};
    }

  for (int k0 = 0; k0 < K; k0 += 32) {
#pragma unroll
    for (int h = 0; h < 2; h++) {
      int r0 = wave * 32 + h * 16;
      gl2lds16(Ah + (size_t)(m0 + r0 + srow) * K + k0 + scol, &AsH[r0 * 32]);
      gl2lds16(Al + (size_t)(m0 + r0 + srow) * K + k0 + scol, &AsL[r0 * 32]);
      gl2lds16(Bh + (size_t)(n0 + r0 + srow) * K + k0 + scol, &BsH[r0 * 32]);
      gl2lds16(Bl + (size_t)(n0 + r0 + srow) * K + k0 + scol, &BsL[r0 * 32]);
    }
    __syncthreads();
    half8 ah[4], al[4];
#pragma unroll
    for (int i = 0; i < 4; i++) {
      ah[i] = *(const half8*)&AsH[(wm * 64 + i * 16 + lrow) * 32 + lq * 8];
      al[i] = *(const half8*)&AsL[(wm * 64 + i * 16 + lrow) * 32 + lq * 8];
    }
#pragma unroll
    for (int j = 0; j < 4; j++) {
      half8 bh = *(const half8*)&BsH[(wn * 64 + j * 16 + lrow) * 32 + lq * 8];
      half8 bl = *(const half8*)&BsL[(wn * 64 + j * 16 + lrow) * 32 + lq * 8];
#pragma unroll
      for (int i = 0; i < 4; i++) {
        acc1[i][j] = __builtin_amdgcn_mfma_f32_16x16x32_f16(ah[i], bh,
                                                            acc1[i][j], 0, 0, 0);
        acc2[i][j] = __builtin_amdgcn_mfma_f32_16x16x32_f16(ah[i], bl,
                                                            acc2[i][j], 0, 0, 0);
        acc2[i][j] = __builtin_amdgcn_mfma_f32_16x16x32_f16(al[i], bh,
                                                            acc2[i][j], 0, 0, 0);
      }
    }
    __syncthreads();
  }

  // C/D layout: col = lane&15, row = (lane>>4)*4 + reg  [measured m89/m91]
  const float INV2048 = 4.8828125e-4f;
#pragma unroll
  for (int i = 0; i < 4; i++) {
#pragma unroll
    for (int j = 0; j < 4; j++) {
      int colg = n0 + wn * 64 + j * 16 + lrow;
      float bb = bias[colg];
#pragma unroll
      for (int r = 0; r < 4; r++) {
        int rowg = m0 + wm * 64 + i * 16 + lq * 4 + r;
        float v = acc1[i][j][r] + acc2[i][j][r] * INV2048 + bb;
        v = fmaxf(v, 0.0f);
        if (ACT == 1) {
          ushort hb, lb;
          split2(v, hb, lb);
          size_t o = (size_t)rowg * N + colg;
          Oh[o] = hb; Ol[o] = lb;
        } else {
          Of[(size_t)rowg * N + colg] = v;
        }
      }
    }
  }
}

// ---------------- fused fc41 + fc42 (N=64 each): 1e-6+softplus --------------
__global__ __launch_bounds__(256) void dual64(
    const float* __restrict__ A, const float* __restrict__ W1,
    const float* __restrict__ b1, const float* __restrict__ W2,
    const float* __restrict__ b2, float* __restrict__ O1,
    float* __restrict__ O2, int K) {
  __shared__ float As[16][68];
  __shared__ float Bs[16][132];
  const int tid = threadIdx.x;
  const int m0 = blockIdx.x * 64;
  const int tx = tid & 31;
  const int ty = tid >> 5;
  float acc[8][4];
#pragma unroll
  for (int i = 0; i < 8; i++)
#pragma unroll
    for (int j = 0; j < 4; j++) acc[i][j] = 0.0f;

  const int arow = tid >> 2;
  const int acol = (tid & 3) << 2;
  const int brow = tid >> 5;
  const int bcol = (tid & 31) << 2;

  for (int k0 = 0; k0 < K; k0 += 16) {
    {
      float4 a = *(const float4*)(A + (size_t)(m0 + arow) * K + k0 + acol);
      As[acol + 0][arow] = a.x; As[acol + 1][arow] = a.y;
      As[acol + 2][arow] = a.z; As[acol + 3][arow] = a.w;
    }
#pragma unroll
    for (int h = 0; h < 2; h++) {
      int r = brow + h * 8;
      const float* src = (bcol < 64) ? (W1 + (size_t)(k0 + r) * 64 + bcol)
                                     : (W2 + (size_t)(k0 + r) * 64 + (bcol - 64));
      *(float4*)&Bs[r][bcol] = *(const float4*)src;
    }
    __syncthreads();
#pragma unroll
    for (int k = 0; k < 16; k++) {
      float af[8], bf[4];
      *(float4*)&af[0] = *(const float4*)&As[k][ty * 8];
      *(float4*)&af[4] = *(const float4*)&As[k][ty * 8 + 4];
      *(float4*)&bf[0] = *(const float4*)&Bs[k][tx * 4];
#pragma unroll
      for (int i = 0; i < 8; i++)
#pragma unroll
        for (int j = 0; j < 4; j++) acc[i][j] = fmaf(af[i], bf[j], acc[i][j]);
    }
    __syncthreads();
  }

#pragma unroll
  for (int i = 0; i < 8; i++) {
    size_t row = (size_t)(m0 + ty * 8 + i);
#pragma unroll
    for (int j = 0; j < 4; j++) {
      int col = tx * 4 + j;
      float bb = (col < 64) ? b1[col] : b2[col - 64];
      float v = 1e-6f + softplus_ref(acc[i][j] + bb);
      if (col < 64) O1[row * 64 + col] = v;
      else          O2[row * 64 + (col - 64)] = v;
    }
  }
}

// ---------------- Marsaglia-Tsang sampler, JAX partitionable threefry -------
// JAX's partitionable threefry returns bits1 ^ bits2 for 32-bit draws.
__global__ __launch_bounds__(256) void gamma_sampler(
    const float* __restrict__ la, const float* __restrict__ lb,
    float* __restrict__ z, ushort* __restrict__ zb) {
#pragma clang fp contract(off)
  const uint32_t i = blockIdx.x * 256u + threadIdx.x;
  uint32_t k1a, k1b, k2a, k2b;
  tf2x32(0u, 42u, 0u, 0u, k1a, k1b);  // split: child key = both output words
  tf2x32(0u, 42u, 0u, 1u, k2a, k2b);

  const float LO = __uint_as_float(0xBF7FFFFFu);
  const float SQRT2 = __uint_as_float(0x3FB504F3u);
  const float USCALE = 1.0f - 1e-7f;

  const float al = la[i];
  const float be = lb[i];
  const float d = (al + 1.0f) - 0.33333334f;
  const float c = 1.0f / __fsqrt_rn(9.0f * d);

  float es = 0.0f, us = 0.0f;
  bool done = false;
  for (int k = 0; k < 24; k++) {
    if (__all(done)) break;
    if (!done) {
      uint32_t n = (uint32_t)k * 524288u + i;
      uint32_t o0, o1, p0, p1;
      tf2x32(k1a, k1b, 0u, n, o0, o1);
      tf2x32(k2a, k2b, 0u, n, p0, p1);
      uint32_t eb = o0 ^ o1;  // JAX: bits = bits1 ^ bits2 (32-bit path)
      uint32_t ub = p0 ^ p1;
      float f = __uint_as_float((eb >> 9) | 0x3F800000u) - 1.0f;
      float un = f * 2.0f + LO;
      un = fmaxf(LO, un);
      float e = SQRT2 * erfinv_f32(un);
      float g = __uint_as_float((ub >> 9) | 0x3F800000u) - 1.0f;
      float u = g * USCALE + 1e-7f;
      u = fmaxf(1e-7f, u);
      if (k == 0) { es = e; us = u; }
      float v = 1.0f + c * e;
      if (v > 0.0f) {
        float v3 = (v * v) * v;
        float e2 = e * e;
        bool acc = false;
        float sq = 1.0f - (0.0331f * e2) * e2;
        if (u < sq) acc = true;
        else {
          float rhs = (0.5f * e) * e + d * ((1.0f - v3) + logf(v3));
          if (logf(u) < rhs) acc = true;
        }
        if (acc) { es = e; us = u; done = true; }
      }
    }
  }
  float vv = 1.0f + c * es;
  float vs = (vv * vv) * vv;
  float t = logf(d * vs + 1e-6f) + logf(us + 1e-6f) / (al + 1e-6f);
  float zv = expf(t) / (be + 1e-6f);
  z[i] = zv;
  zb[i] = f2bf(zv);
}

// ---------------- transpose + fp32->bf16: out[c][r] = bf16(in[r][c]) --------
__global__ __launch_bounds__(256) void transpose_bf16(
    const float* __restrict__ in, ushort* __restrict__ out, int R, int C) {
  __shared__ float tile[32][33];
  const int c0 = blockIdx.x * 32, r0 = blockIdx.y * 32;
  const int tx = threadIdx.x & 31, ty = threadIdx.x >> 5;
#pragma unroll
  for (int i = ty; i < 32; i += 8)
    tile[i][tx] = in[(size_t)(r0 + i) * C + c0 + tx];
  __syncthreads();
#pragma unroll
  for (int i = ty; i < 32; i += 8)
    out[(size_t)(c0 + i) * R + r0 + tx] = f2bf(tile[tx][i]);
}

// ---------------- bf16 MFMA GEMM (m97-style): C = act(A @ Bt^T + bias) ------
template <int ACT>
__global__ __launch_bounds__(256) void gemm_bf16(
    const ushort* __restrict__ A, const ushort* __restrict__ Bt,
    const float* __restrict__ bias, ushort* __restrict__ C0b,
    float* __restrict__ C0f, float* __restrict__ C1f,
    int M, int N, int K, int split) {
  __shared__ ushort As[128 * 32];
  __shared__ ushort Bs[128 * 32];
  const int tid = threadIdx.x;
  const int wave = tid >> 6, lane = tid & 63;
  const int m0 = blockIdx.y * 128, n0 = blockIdx.x * 128;
  const int lrow = lane & 15, lq = lane >> 4;
  const int wm = wave & 1, wn = wave >> 1;
  const int srow = lane >> 2;
  const int scol = (lane & 3) * 8;

  floatx4 acc[4][4];
#pragma unroll
  for (int i = 0; i < 4; i++)
#pragma unroll
    for (int j = 0; j < 4; j++) acc[i][j] = (floatx4){0.f, 0.f, 0.f, 0.f};

  for (int k0 = 0; k0 < K; k0 += 32) {
#pragma unroll
    for (int h = 0; h < 2; h++) {
      int r0 = wave * 32 + h * 16;
      gl2lds16(A + (size_t)(m0 + r0 + srow) * K + k0 + scol, &As[r0 * 32]);
      gl2lds16(Bt + (size_t)(n0 + r0 + srow) * K + k0 + scol, &Bs[r0 * 32]);
    }
    __syncthreads();
    short8 a[4], b[4];
#pragma unroll
    for (int i = 0; i < 4; i++) {
      a[i] = *(const short8*)&As[(wm * 64 + i * 16 + lrow) * 32 + lq * 8];
      b[i] = *(const short8*)&Bs[(wn * 64 + i * 16 + lrow) * 32 + lq * 8];
    }
#pragma unroll
    for (int i = 0; i < 4; i++)
#pragma unroll
      for (int j = 0; j < 4; j++)
        acc[i][j] = __builtin_amdgcn_mfma_f32_16x16x32_bf16(a[i], b[j],
                                                            acc[i][j], 0, 0, 0);
    __syncthreads();
  }

#pragma unroll
  for (int i = 0; i < 4; i++) {
#pragma unroll
    for (int j = 0; j < 4; j++) {
      int colg = n0 + wn * 64 + j * 16 + lrow;
      float bb = bias[colg];
#pragma unroll
      for (int r = 0; r < 4; r++) {
        int rowg = m0 + wm * 64 + i * 16 + lq * 4 + r;
        float v = acc[i][j][r] + bb;
        if (ACT == 0) {
          v = fmaxf(v, 0.0f);
          C0b[(size_t)rowg * N + colg] = f2bf(v);
        } else {
          v = 1e-6f + softplus_ref(v);
          if (colg < split) C0f[(size_t)rowg * split + colg] = v;
          else              C1f[(size_t)rowg * split + (colg - split)] = v;
        }
      }
    }
  }
}

// ---------------------------------------------------------------------------
extern "C" void kernel_launch(void* const* d_in, const int* in_sizes, int n_in,
                              void* d_out, int out_size, void* d_ws,
                              size_t ws_size, hipStream_t stream) {
  const float* x   = (const float*)d_in[0];
  const float* w1  = (const float*)d_in[1];  const float* b1  = (const float*)d_in[2];
  const float* w2  = (const float*)d_in[3];  const float* b2  = (const float*)d_in[4];
  const float* w3  = (const float*)d_in[5];  const float* b3  = (const float*)d_in[6];
  const float* w41 = (const float*)d_in[7];  const float* b41 = (const float*)d_in[8];
  const float* w42 = (const float*)d_in[9];  const float* b42 = (const float*)d_in[10];
  const float* w4  = (const float*)d_in[11]; const float* b4  = (const float*)d_in[12];
  const float* w5  = (const float*)d_in[13]; const float* b5  = (const float*)d_in[14];
  const float* w6  = (const float*)d_in[15]; const float* b6  = (const float*)d_in[16];
  const float* w7  = (const float*)d_in[17]; const float* b7  = (const float*)d_in[18];
  float* out = (float*)d_out;
  float* ws  = (float*)d_ws;
  ushort* wsu = (ushort*)d_ws;

  // output layout (floats): recon_al | recon_be | logalpha | logbeta | z
  float* recon_a = out;
  float* recon_b = out + 16777216;
  float* la      = out + 33554432;
  float* lb      = out + 34078720;
  float* zz      = out + 34603008;

  // ---- workspace layout (ushort offsets unless noted); peak 124 MB,
  // under the 134.2 MB footprint of the previous passing version.
  ushort* xh   = wsu;              // [0, 16777216)            dead after fc1
  ushort* xl   = wsu + 16777216;   // [16777216, 33554432)     dead after fc1
  ushort* w1Th = wsu + 33554432;   // [.., 35651584)           dead after fc1
  ushort* w1Tl = wsu + 35651584;   // [.., 37748736)
  ushort* w2Th = wsu + 37748736;   // [.., 38797312)           dead after fc2
  ushort* w2Tl = wsu + 38797312;   // [.., 39845888)
  ushort* h1h  = wsu + 39845888;   // [.., 48234496)           dead after fc2
  ushort* h1l  = wsu + 48234496;   // [.., 56623104)
  ushort* w3Th = wsu + 16777216;   // overwrites xl AFTER fc1  dead after fc3
  ushort* w3Tl = wsu + 18874368;   // [.., 20971520)
  ushort* h2h  = wsu;              // overwrites xh AFTER fc1  dead after fc3
  ushort* h2l  = wsu + 8388608;    // [.., 16777216)
  float*  h3f  = ws  + 10485760;   // floats [10485760, 27262976) = byte [41.9M,109.1M)
                                   // (over dead w1T/w2T/h1) dead after dual64
  // decoder (bf16), byte [109.05M, 124.0M) — after h3, over dead h1l tail:
  ushort* w4T = wsu + 54525952;    // [64,2048]   -> 54657024
  ushort* w5T = wsu + 54657024;    // [1024,2048] -> 56754176
  ushort* w6T = wsu + 56754176;    // [1024,1024] -> 57802752
  ushort* w7T = wsu + 57802752;    // [4096,1024] -> 61997056
  ushort* zb  = wsu;               // [0, 524288)       (h2 dead by sampler)
  ushort* h4b = wsu + 20971520;    // [.., 37748736)    (over dead h3)
  ushort* h5b = wsu + 524288;      // [.., 8912896)     (over dead h2)
  ushort* h6b = wsu + 8912896;     // [.., 17301504)    (over dead h2l/w3T)

  dim3 blk(256);
  // ---- prep: split x and encoder weights into f16 (hi, lo*2^11) pairs
  split_f16<<<dim3(2048), blk, 0, stream>>>(x, xh, xl, 4194304);
  transpose_split_f16<<<dim3(32, 64), blk, 0, stream>>>(w1, w1Th, w1Tl, 2048, 1024);
  transpose_split_f16<<<dim3(32, 32), blk, 0, stream>>>(w2, w2Th, w2Tl, 1024, 1024);
  // ---- encoder: split-f16 MFMA (error ~1e-6 rel, below fp32-reorder noise)
  gemm_f16x3<1><<<dim3(8, 64), blk, 0, stream>>>(xh, xl, w1Th, w1Tl, b1,
                                                 h1h, h1l, nullptr, 8192, 1024, 2048);
  transpose_split_f16<<<dim3(64, 32), blk, 0, stream>>>(w3, w3Th, w3Tl, 1024, 2048);
  gemm_f16x3<1><<<dim3(8, 64), blk, 0, stream>>>(h1h, h1l, w2Th, w2Tl, b2,
                                                 h2h, h2l, nullptr, 8192, 1024, 1024);
  // decoder weight prep (regions free only after fc2 reads h1l)
  transpose_bf16<<<dim3(64, 2),   blk, 0, stream>>>(w4, w4T, 64,   2048);
  transpose_bf16<<<dim3(32, 64),  blk, 0, stream>>>(w5, w5T, 2048, 1024);
  transpose_bf16<<<dim3(32, 32),  blk, 0, stream>>>(w6, w6T, 1024, 1024);
  transpose_bf16<<<dim3(128, 32), blk, 0, stream>>>(w7, w7T, 1024, 4096);
  gemm_f16x3<2><<<dim3(16, 64), blk, 0, stream>>>(h2h, h2l, w3Th, w3Tl, b3,
                                                  nullptr, nullptr, h3f, 8192, 2048, 1024);
  dual64<<<dim3(128), blk, 0, stream>>>(h3f, w41, b41, w42, b42, la, lb, 2048);
  // reparameterize (exact fp32; also emits bf16 z)
  gamma_sampler<<<dim3(2048), blk, 0, stream>>>(la, lb, zz, zb);
  // decoder (bf16 MFMA)
  gemm_bf16<0><<<dim3(16, 64), blk, 0, stream>>>(zb,  w4T, b4, h4b, nullptr, nullptr, 8192, 2048, 64, 0);
  gemm_bf16<0><<<dim3(8, 64),  blk, 0, stream>>>(h4b, w5T, b5, h5b, nullptr, nullptr, 8192, 1024, 2048, 0);
  gemm_bf16<0><<<dim3(8, 64),  blk, 0, stream>>>(h5b, w6T, b6, h6b, nullptr, nullptr, 8192, 1024, 1024, 0);
  gemm_bf16<3><<<dim3(32, 64), blk, 0, stream>>>(h6b, w7T, b7, nullptr, recon_a, recon_b, 8192, 4096, 1024, 2048);
  (void)in_sizes; (void)n_in; (void)out_size; (void)ws_size;
}

// Round 4
// 1077.168 us; speedup vs baseline: 1.6252x; 1.1720x over previous
//
#include <hip/hip_runtime.h>
#include <stdint.h>

#define DEVFN static __device__ __forceinline__

typedef __attribute__((ext_vector_type(8))) short short8;
typedef __attribute__((ext_vector_type(4))) float floatx4;
typedef _Float16 half8 __attribute__((ext_vector_type(8)));

// ---------------- Threefry-2x32 (20 rounds), exactly as JAX ----------------
DEVFN uint32_t rotl32(uint32_t v, int d) { return (v << d) | (v >> (32 - d)); }

DEVFN void tf2x32(uint32_t k0, uint32_t k1, uint32_t x0, uint32_t x1,
                  uint32_t& o0, uint32_t& o1) {
  uint32_t k2 = k0 ^ k1 ^ 0x1BD11BDAu;
  x0 += k0; x1 += k1;
  x0 += x1; x1 = rotl32(x1, 13); x1 ^= x0;
  x0 += x1; x1 = rotl32(x1, 15); x1 ^= x0;
  x0 += x1; x1 = rotl32(x1, 26); x1 ^= x0;
  x0 += x1; x1 = rotl32(x1, 6);  x1 ^= x0;
  x0 += k1; x1 += k2 + 1u;
  x0 += x1; x1 = rotl32(x1, 17); x1 ^= x0;
  x0 += x1; x1 = rotl32(x1, 29); x1 ^= x0;
  x0 += x1; x1 = rotl32(x1, 16); x1 ^= x0;
  x0 += x1; x1 = rotl32(x1, 24); x1 ^= x0;
  x0 += k2; x1 += k0 + 2u;
  x0 += x1; x1 = rotl32(x1, 13); x1 ^= x0;
  x0 += x1; x1 = rotl32(x1, 15); x1 ^= x0;
  x0 += x1; x1 = rotl32(x1, 26); x1 ^= x0;
  x0 += x1; x1 = rotl32(x1, 6);  x1 ^= x0;
  x0 += k0; x1 += k1 + 3u;
  x0 += x1; x1 = rotl32(x1, 17); x1 ^= x0;
  x0 += x1; x1 = rotl32(x1, 29); x1 ^= x0;
  x0 += x1; x1 = rotl32(x1, 16); x1 ^= x0;
  x0 += x1; x1 = rotl32(x1, 24); x1 ^= x0;
  x0 += k1; x1 += k2 + 4u;
  x0 += x1; x1 = rotl32(x1, 13); x1 ^= x0;
  x0 += x1; x1 = rotl32(x1, 15); x1 ^= x0;
  x0 += x1; x1 = rotl32(x1, 26); x1 ^= x0;
  x0 += x1; x1 = rotl32(x1, 6);  x1 ^= x0;
  x0 += k2; x1 += k0 + 5u;
  o0 = x0; o1 = x1;
}

// ---------------- XLA/CHLO f32 erf_inv (Giles), w = -log1p(-x^2) -----------
DEVFN float erfinv_f32(float x) {
#pragma clang fp contract(off)
  float w = -log1pf(-(x * x));
  float p;
  if (w < 5.0f) {
    w = w - 2.5f;
    p = 2.81022636e-08f;
    p = 3.43273939e-07f + p * w;
    p = -3.5233877e-06f + p * w;
    p = -4.39150654e-06f + p * w;
    p = 0.00021858087f + p * w;
    p = -0.00125372503f + p * w;
    p = -0.00417768164f + p * w;
    p = 0.246640727f + p * w;
    p = 1.50140941f + p * w;
  } else {
    w = __fsqrt_rn(w) - 3.0f;
    p = -0.000200214257f;
    p = 0.000100950558f + p * w;
    p = 0.00134934322f + p * w;
    p = -0.00367342844f + p * w;
    p = 0.00573950773f + p * w;
    p = -0.0076224613f + p * w;
    p = 0.00943887047f + p * w;
    p = 1.00167406f + p * w;
    p = 2.83297682f + p * w;
  }
  return p * x;
}

// jax.nn.softplus(x) = logaddexp(x,0) = max(x,0) + log1p(exp(-|x|))
DEVFN float softplus_ref(float v) {
#pragma clang fp contract(off)
  return fmaxf(v, 0.0f) + log1pf(expf(-fabsf(v)));
}

// fp32 -> bf16 RNE
DEVFN ushort f2bf(float f) {
  uint32_t u = __float_as_uint(f);
  uint32_t r = (u + 0x7FFFu + ((u >> 16) & 1u)) >> 16;
  return (ushort)r;
}

// fp32 -> (f16 hi, f16 lo*2048) split. a = hi + lo/2048 + O(2^-23 |a|).
DEVFN void split2(float a, ushort& hb, ushort& lb) {
  _Float16 h = (_Float16)a;
  float r = (a - (float)h) * 2048.0f;  // a-hf exact (Sterbenz); *2^11 exact
  _Float16 l = (_Float16)r;
  hb = __builtin_bit_cast(unsigned short, h);
  lb = __builtin_bit_cast(unsigned short, l);
}

// async global->LDS, 16 B per lane; lds must be wave-uniform base
DEVFN void gl2lds16(const void* g, void* l) {
  __builtin_amdgcn_global_load_lds(
      (const __attribute__((address_space(1))) void*)g,
      (__attribute__((address_space(3))) void*)l, 16, 0, 0);
}

// ---------------- elementwise split: x -> (xh, xl) f16 pairs ----------------
__global__ __launch_bounds__(256) void split_f16(
    const float* __restrict__ in, ushort* __restrict__ oh,
    ushort* __restrict__ ol, int n4) {
  int idx = blockIdx.x * 256 + threadIdx.x;
  int stride = gridDim.x * 256;
  for (int i = idx; i < n4; i += stride) {
    float4 a = ((const float4*)in)[i];
    ushort h0, h1, h2, h3, l0, l1, l2, l3;
    split2(a.x, h0, l0); split2(a.y, h1, l1);
    split2(a.z, h2, l2); split2(a.w, h3, l3);
    ushort4 hv; hv.x = h0; hv.y = h1; hv.z = h2; hv.w = h3;
    ushort4 lv; lv.x = l0; lv.y = l1; lv.z = l2; lv.w = l3;
    ((ushort4*)oh)[i] = hv;
    ((ushort4*)ol)[i] = lv;
  }
}

// ---------------- transpose + f16-split: out*[c][r] = split(in[r][c]) -------
__global__ __launch_bounds__(256) void transpose_split_f16(
    const float* __restrict__ in, ushort* __restrict__ oh,
    ushort* __restrict__ ol, int R, int C) {
  __shared__ float tile[32][33];
  const int c0 = blockIdx.x * 32, r0 = blockIdx.y * 32;
  const int tx = threadIdx.x & 31, ty = threadIdx.x >> 5;
#pragma unroll
  for (int i = ty; i < 32; i += 8)
    tile[i][tx] = in[(size_t)(r0 + i) * C + c0 + tx];
  __syncthreads();
#pragma unroll
  for (int i = ty; i < 32; i += 8) {
    ushort hb, lb;
    split2(tile[tx][i], hb, lb);
    size_t o = (size_t)(c0 + i) * R + r0 + tx;
    oh[o] = hb; ol[o] = lb;
  }
}

// ---------------- split-f16 MFMA GEMM: C = act(A @ Bt^T + bias) -------------
// acc1 = Ah*Bh ; acc2 = Ah*Bl + Al*Bh ; result = acc1 + acc2/2048  (fp32).
// ACT 1: relu -> f16-split pair (Oh,Ol). ACT 2: relu -> fp32 Of.
template <int ACT>
__global__ __launch_bounds__(256) void gemm_f16x3(
    const ushort* __restrict__ Ah, const ushort* __restrict__ Al,
    const ushort* __restrict__ Bh, const ushort* __restrict__ Bl,
    const float* __restrict__ bias, ushort* __restrict__ Oh,
    ushort* __restrict__ Ol, float* __restrict__ Of, int M, int N, int K) {
  __shared__ ushort AsH[128 * 32];
  __shared__ ushort AsL[128 * 32];
  __shared__ ushort BsH[128 * 32];
  __shared__ ushort BsL[128 * 32];
  const int tid = threadIdx.x;
  const int wave = tid >> 6, lane = tid & 63;
  const int m0 = blockIdx.y * 128, n0 = blockIdx.x * 128;
  const int lrow = lane & 15, lq = lane >> 4;
  const int wm = wave & 1, wn = wave >> 1;
  const int srow = lane >> 2;
  const int scol = (lane & 3) * 8;

  floatx4 acc1[4][4], acc2[4][4];
#pragma unroll
  for (int i = 0; i < 4; i++)
#pragma unroll
    for (int j = 0; j < 4; j++) {
      acc1[i][j] = (floatx4){0.f, 0.f, 0.f, 0.f};
      acc2[i][j] = (floatx4){0.f, 0.f, 0.f, 0.f};
    }

  for (int k0 = 0; k0 < K; k0 += 32) {
#pragma unroll
    for (int h = 0; h < 2; h++) {
      int r0 = wave * 32 + h * 16;
      gl2lds16(Ah + (size_t)(m0 + r0 + srow) * K + k0 + scol, &AsH[r0 * 32]);
      gl2lds16(Al + (size_t)(m0 + r0 + srow) * K + k0 + scol, &AsL[r0 * 32]);
      gl2lds16(Bh + (size_t)(n0 + r0 + srow) * K + k0 + scol, &BsH[r0 * 32]);
      gl2lds16(Bl + (size_t)(n0 + r0 + srow) * K + k0 + scol, &BsL[r0 * 32]);
    }
    __syncthreads();
    half8 ah[4], al[4];
#pragma unroll
    for (int i = 0; i < 4; i++) {
      ah[i] = *(const half8*)&AsH[(wm * 64 + i * 16 + lrow) * 32 + lq * 8];
      al[i] = *(const half8*)&AsL[(wm * 64 + i * 16 + lrow) * 32 + lq * 8];
    }
#pragma unroll
    for (int j = 0; j < 4; j++) {
      half8 bh = *(const half8*)&BsH[(wn * 64 + j * 16 + lrow) * 32 + lq * 8];
      half8 bl = *(const half8*)&BsL[(wn * 64 + j * 16 + lrow) * 32 + lq * 8];
#pragma unroll
      for (int i = 0; i < 4; i++) {
        acc1[i][j] = __builtin_amdgcn_mfma_f32_16x16x32_f16(ah[i], bh,
                                                            acc1[i][j], 0, 0, 0);
        acc2[i][j] = __builtin_amdgcn_mfma_f32_16x16x32_f16(ah[i], bl,
                                                            acc2[i][j], 0, 0, 0);
        acc2[i][j] = __builtin_amdgcn_mfma_f32_16x16x32_f16(al[i], bh,
                                                            acc2[i][j], 0, 0, 0);
      }
    }
    __syncthreads();
  }

  // C/D layout: col = lane&15, row = (lane>>4)*4 + reg  [measured m89/m91]
  const float INV2048 = 4.8828125e-4f;
#pragma unroll
  for (int i = 0; i < 4; i++) {
#pragma unroll
    for (int j = 0; j < 4; j++) {
      int colg = n0 + wn * 64 + j * 16 + lrow;
      float bb = bias[colg];
#pragma unroll
      for (int r = 0; r < 4; r++) {
        int rowg = m0 + wm * 64 + i * 16 + lq * 4 + r;
        float v = acc1[i][j][r] + acc2[i][j][r] * INV2048 + bb;
        v = fmaxf(v, 0.0f);
        if (ACT == 1) {
          ushort hb, lb;
          split2(v, hb, lb);
          size_t o = (size_t)rowg * N + colg;
          Oh[o] = hb; Ol[o] = lb;
        } else {
          Of[(size_t)rowg * N + colg] = v;
        }
      }
    }
  }
}

// ---------------- fc41+fc42 via split-K MFMA ---------------------------------
// logits[8192,128] = h3(split) @ wcat(split)^T, K=2048 in 8 chunks of 256.
// grid (8, 64): bx = k-chunk, by = m-block. Partials P[8][8192][128] fp32.
// (replaces dual64: 242us latency-bound, 128 blocks / 6% occupancy / VALU)
__global__ __launch_bounds__(256) void dual_mfma(
    const ushort* __restrict__ Ah, const ushort* __restrict__ Al,
    const ushort* __restrict__ Bh, const ushort* __restrict__ Bl,
    float* __restrict__ P) {
  __shared__ ushort AsH[128 * 32];
  __shared__ ushort AsL[128 * 32];
  __shared__ ushort BsH[128 * 32];
  __shared__ ushort BsL[128 * 32];
  const int K = 2048;
  const int tid = threadIdx.x;
  const int wave = tid >> 6, lane = tid & 63;
  const int m0 = blockIdx.y * 128;
  const int kbase = blockIdx.x * 256;
  const int lrow = lane & 15, lq = lane >> 4;
  const int wm = wave & 1, wn = wave >> 1;
  const int srow = lane >> 2;
  const int scol = (lane & 3) * 8;

  floatx4 acc1[4][4], acc2[4][4];
#pragma unroll
  for (int i = 0; i < 4; i++)
#pragma unroll
    for (int j = 0; j < 4; j++) {
      acc1[i][j] = (floatx4){0.f, 0.f, 0.f, 0.f};
      acc2[i][j] = (floatx4){0.f, 0.f, 0.f, 0.f};
    }

  for (int kk = 0; kk < 256; kk += 32) {
    int k0 = kbase + kk;
#pragma unroll
    for (int h = 0; h < 2; h++) {
      int r0 = wave * 32 + h * 16;
      gl2lds16(Ah + (size_t)(m0 + r0 + srow) * K + k0 + scol, &AsH[r0 * 32]);
      gl2lds16(Al + (size_t)(m0 + r0 + srow) * K + k0 + scol, &AsL[r0 * 32]);
      gl2lds16(Bh + (size_t)(r0 + srow) * K + k0 + scol, &BsH[r0 * 32]);
      gl2lds16(Bl + (size_t)(r0 + srow) * K + k0 + scol, &BsL[r0 * 32]);
    }
    __syncthreads();
    half8 ah[4], al[4];
#pragma unroll
    for (int i = 0; i < 4; i++) {
      ah[i] = *(const half8*)&AsH[(wm * 64 + i * 16 + lrow) * 32 + lq * 8];
      al[i] = *(const half8*)&AsL[(wm * 64 + i * 16 + lrow) * 32 + lq * 8];
    }
#pragma unroll
    for (int j = 0; j < 4; j++) {
      half8 bh = *(const half8*)&BsH[(wn * 64 + j * 16 + lrow) * 32 + lq * 8];
      half8 bl = *(const half8*)&BsL[(wn * 64 + j * 16 + lrow) * 32 + lq * 8];
#pragma unroll
      for (int i = 0; i < 4; i++) {
        acc1[i][j] = __builtin_amdgcn_mfma_f32_16x16x32_f16(ah[i], bh,
                                                            acc1[i][j], 0, 0, 0);
        acc2[i][j] = __builtin_amdgcn_mfma_f32_16x16x32_f16(ah[i], bl,
                                                            acc2[i][j], 0, 0, 0);
        acc2[i][j] = __builtin_amdgcn_mfma_f32_16x16x32_f16(al[i], bh,
                                                            acc2[i][j], 0, 0, 0);
      }
    }
    __syncthreads();
  }

  const float INV2048 = 4.8828125e-4f;
#pragma unroll
  for (int i = 0; i < 4; i++) {
#pragma unroll
    for (int j = 0; j < 4; j++) {
      int colg = wn * 64 + j * 16 + lrow;
#pragma unroll
      for (int r = 0; r < 4; r++) {
        int rowg = m0 + wm * 64 + i * 16 + lq * 4 + r;
        float v = acc1[i][j][r] + acc2[i][j][r] * INV2048;
        P[((size_t)blockIdx.x * 8192 + rowg) * 128 + colg] = v;
      }
    }
  }
}

// ---------------- reduce 8 split-K partials + bias + softplus ---------------
// Fixed k-order sum -> deterministic. 262144 float4s over [8192 x 32 col4s].
__global__ __launch_bounds__(256) void dual_reduce(
    const float* __restrict__ P, const float* __restrict__ b41,
    const float* __restrict__ b42, float* __restrict__ la,
    float* __restrict__ lb) {
#pragma clang fp contract(off)
  int idx = blockIdx.x * 256 + threadIdx.x;  // [0, 262144)
  int row = idx >> 5;
  int c4 = (idx & 31) * 4;
  float4 s = {0.f, 0.f, 0.f, 0.f};
#pragma unroll
  for (int k = 0; k < 8; k++) {
    float4 p = *(const float4*)&P[((size_t)k * 8192 + row) * 128 + c4];
    s.x += p.x; s.y += p.y; s.z += p.z; s.w += p.w;
  }
  float o[4];
  const float* bb = (c4 < 64) ? (b41 + c4) : (b42 + c4 - 64);
#pragma unroll
  for (int q = 0; q < 4; q++) {
    float v = (&s.x)[q] + bb[q];
    o[q] = 1e-6f + softplus_ref(v);
  }
  float* dst = (c4 < 64) ? (la + (size_t)row * 64 + c4)
                         : (lb + (size_t)row * 64 + (c4 - 64));
  *(float4*)dst = *(float4*)o;
}

// ---------------- Marsaglia-Tsang sampler, JAX partitionable threefry -------
// JAX's partitionable threefry returns bits1 ^ bits2 for 32-bit draws.
__global__ __launch_bounds__(256) void gamma_sampler(
    const float* __restrict__ la, const float* __restrict__ lb,
    float* __restrict__ z, ushort* __restrict__ zb) {
#pragma clang fp contract(off)
  const uint32_t i = blockIdx.x * 256u + threadIdx.x;
  uint32_t k1a, k1b, k2a, k2b;
  tf2x32(0u, 42u, 0u, 0u, k1a, k1b);  // split: child key = both output words
  tf2x32(0u, 42u, 0u, 1u, k2a, k2b);

  const float LO = __uint_as_float(0xBF7FFFFFu);
  const float SQRT2 = __uint_as_float(0x3FB504F3u);
  const float USCALE = 1.0f - 1e-7f;

  const float al = la[i];
  const float be = lb[i];
  const float d = (al + 1.0f) - 0.33333334f;
  const float c = 1.0f / __fsqrt_rn(9.0f * d);

  float es = 0.0f, us = 0.0f;
  bool done = false;
  for (int k = 0; k < 24; k++) {
    if (__all(done)) break;
    if (!done) {
      uint32_t n = (uint32_t)k * 524288u + i;
      uint32_t o0, o1, p0, p1;
      tf2x32(k1a, k1b, 0u, n, o0, o1);
      tf2x32(k2a, k2b, 0u, n, p0, p1);
      uint32_t eb = o0 ^ o1;  // JAX: bits = bits1 ^ bits2 (32-bit path)
      uint32_t ub = p0 ^ p1;
      float f = __uint_as_float((eb >> 9) | 0x3F800000u) - 1.0f;
      float un = f * 2.0f + LO;
      un = fmaxf(LO, un);
      float e = SQRT2 * erfinv_f32(un);
      float g = __uint_as_float((ub >> 9) | 0x3F800000u) - 1.0f;
      float u = g * USCALE + 1e-7f;
      u = fmaxf(1e-7f, u);
      if (k == 0) { es = e; us = u; }
      float v = 1.0f + c * e;
      if (v > 0.0f) {
        float v3 = (v * v) * v;
        float e2 = e * e;
        bool acc = false;
        float sq = 1.0f - (0.0331f * e2) * e2;
        if (u < sq) acc = true;
        else {
          float rhs = (0.5f * e) * e + d * ((1.0f - v3) + logf(v3));
          if (logf(u) < rhs) acc = true;
        }
        if (acc) { es = e; us = u; done = true; }
      }
    }
  }
  float vv = 1.0f + c * es;
  float vs = (vv * vv) * vv;
  float t = logf(d * vs + 1e-6f) + logf(us + 1e-6f) / (al + 1e-6f);
  float zv = expf(t) / (be + 1e-6f);
  z[i] = zv;
  zb[i] = f2bf(zv);
}

// ---------------- transpose + fp32->bf16: out[c][r] = bf16(in[r][c]) --------
__global__ __launch_bounds__(256) void transpose_bf16(
    const float* __restrict__ in, ushort* __restrict__ out, int R, int C) {
  __shared__ float tile[32][33];
  const int c0 = blockIdx.x * 32, r0 = blockIdx.y * 32;
  const int tx = threadIdx.x & 31, ty = threadIdx.x >> 5;
#pragma unroll
  for (int i = ty; i < 32; i += 8)
    tile[i][tx] = in[(size_t)(r0 + i) * C + c0 + tx];
  __syncthreads();
#pragma unroll
  for (int i = ty; i < 32; i += 8)
    out[(size_t)(c0 + i) * R + r0 + tx] = f2bf(tile[tx][i]);
}

// ---------------- bf16 MFMA GEMM (m97-style): C = act(A @ Bt^T + bias) ------
template <int ACT>
__global__ __launch_bounds__(256) void gemm_bf16(
    const ushort* __restrict__ A, const ushort* __restrict__ Bt,
    const float* __restrict__ bias, ushort* __restrict__ C0b,
    float* __restrict__ C0f, float* __restrict__ C1f,
    int M, int N, int K, int split) {
  __shared__ ushort As[128 * 32];
  __shared__ ushort Bs[128 * 32];
  const int tid = threadIdx.x;
  const int wave = tid >> 6, lane = tid & 63;
  const int m0 = blockIdx.y * 128, n0 = blockIdx.x * 128;
  const int lrow = lane & 15, lq = lane >> 4;
  const int wm = wave & 1, wn = wave >> 1;
  const int srow = lane >> 2;
  const int scol = (lane & 3) * 8;

  floatx4 acc[4][4];
#pragma unroll
  for (int i = 0; i < 4; i++)
#pragma unroll
    for (int j = 0; j < 4; j++) acc[i][j] = (floatx4){0.f, 0.f, 0.f, 0.f};

  for (int k0 = 0; k0 < K; k0 += 32) {
#pragma unroll
    for (int h = 0; h < 2; h++) {
      int r0 = wave * 32 + h * 16;
      gl2lds16(A + (size_t)(m0 + r0 + srow) * K + k0 + scol, &As[r0 * 32]);
      gl2lds16(Bt + (size_t)(n0 + r0 + srow) * K + k0 + scol, &Bs[r0 * 32]);
    }
    __syncthreads();
    short8 a[4], b[4];
#pragma unroll
    for (int i = 0; i < 4; i++) {
      a[i] = *(const short8*)&As[(wm * 64 + i * 16 + lrow) * 32 + lq * 8];
      b[i] = *(const short8*)&Bs[(wn * 64 + i * 16 + lrow) * 32 + lq * 8];
    }
#pragma unroll
    for (int i = 0; i < 4; i++)
#pragma unroll
      for (int j = 0; j < 4; j++)
        acc[i][j] = __builtin_amdgcn_mfma_f32_16x16x32_bf16(a[i], b[j],
                                                            acc[i][j], 0, 0, 0);
    __syncthreads();
  }

#pragma unroll
  for (int i = 0; i < 4; i++) {
#pragma unroll
    for (int j = 0; j < 4; j++) {
      int colg = n0 + wn * 64 + j * 16 + lrow;
      float bb = bias[colg];
#pragma unroll
      for (int r = 0; r < 4; r++) {
        int rowg = m0 + wm * 64 + i * 16 + lq * 4 + r;
        float v = acc[i][j][r] + bb;
        if (ACT == 0) {
          v = fmaxf(v, 0.0f);
          C0b[(size_t)rowg * N + colg] = f2bf(v);
        } else {
          v = 1e-6f + softplus_ref(v);
          if (colg < split) C0f[(size_t)rowg * split + colg] = v;
          else              C1f[(size_t)rowg * split + (colg - split)] = v;
        }
      }
    }
  }
}

// ---------------------------------------------------------------------------
extern "C" void kernel_launch(void* const* d_in, const int* in_sizes, int n_in,
                              void* d_out, int out_size, void* d_ws,
                              size_t ws_size, hipStream_t stream) {
  const float* x   = (const float*)d_in[0];
  const float* w1  = (const float*)d_in[1];  const float* b1  = (const float*)d_in[2];
  const float* w2  = (const float*)d_in[3];  const float* b2  = (const float*)d_in[4];
  const float* w3  = (const float*)d_in[5];  const float* b3  = (const float*)d_in[6];
  const float* w41 = (const float*)d_in[7];  const float* b41 = (const float*)d_in[8];
  const float* w42 = (const float*)d_in[9];  const float* b42 = (const float*)d_in[10];
  const float* w4  = (const float*)d_in[11]; const float* b4  = (const float*)d_in[12];
  const float* w5  = (const float*)d_in[13]; const float* b5  = (const float*)d_in[14];
  const float* w6  = (const float*)d_in[15]; const float* b6  = (const float*)d_in[16];
  const float* w7  = (const float*)d_in[17]; const float* b7  = (const float*)d_in[18];
  float* out = (float*)d_out;
  float* ws  = (float*)d_ws;
  ushort* wsu = (ushort*)d_ws;

  // output layout (floats): recon_al | recon_be | logalpha | logbeta | z
  float* recon_a = out;
  float* recon_b = out + 16777216;
  float* la      = out + 33554432;
  float* lb      = out + 34078720;
  float* zz      = out + 34603008;

  // ---- workspace layout (ushort offsets unless noted); peak 124 MB.
  ushort* xh   = wsu;              // [0, 16777216)            dead after fc1
  ushort* xl   = wsu + 16777216;   // [16777216, 33554432)     dead after fc1
  ushort* w1Th = wsu + 33554432;   // [.., 35651584)           dead after fc1
  ushort* w1Tl = wsu + 35651584;   // [.., 37748736)
  ushort* w2Th = wsu + 37748736;   // [.., 38797312)           dead after fc2
  ushort* w2Tl = wsu + 38797312;   // [.., 39845888)
  ushort* h1h  = wsu + 39845888;   // [.., 48234496)           dead after fc2
  ushort* h1l  = wsu + 48234496;   // [.., 56623104)
  ushort* w3Th = wsu + 16777216;   // overwrites xl AFTER fc1  dead after fc3
  ushort* w3Tl = wsu + 18874368;   // [.., 20971520)
  ushort* h2h  = wsu;              // overwrites xh AFTER fc1  dead after fc3
  ushort* h2l  = wsu + 8388608;    // [.., 16777216)
  // fc3 output: split pair, same footprint as old fp32 h3 (over dead
  // w1T/w2T/h1 region): dead after dual_mfma
  ushort* h3h  = wsu + 20971520;   // [20971520, 37748736)
  ushort* h3l  = wsu + 37748736;   // [37748736, 54525952)
  // fc41|fc42 concat weights, transposed+split [128, 2048]:
  // over dead w3T (free after fc3); dead after dual_mfma
  ushort* wcatTh = wsu + 16777216; // [16777216, 17039360)
  ushort* wcatTl = wsu + 17039360; // [17039360, 17301504)
  // split-K partials [8][8192][128] fp32 = 33.5 MB over dead x/h2 region
  // (free after fc3); dead after dual_reduce (before zb/h5b/h6b writes)
  float*  Ppart = ws;              // float [0, 8388608) = ushort [0,16777216)
  // decoder (bf16), after h3 region — over dead h1l tail:
  ushort* w4T = wsu + 54525952;    // [64,2048]   -> 54657024
  ushort* w5T = wsu + 54657024;    // [1024,2048] -> 56754176
  ushort* w6T = wsu + 56754176;    // [1024,1024] -> 57802752
  ushort* w7T = wsu + 57802752;    // [4096,1024] -> 61997056
  ushort* zb  = wsu;               // [0, 524288)       (Ppart dead by sampler)
  ushort* h4b = wsu + 20971520;    // [.., 37748736)    (over dead h3h)
  ushort* h5b = wsu + 524288;      // [.., 8912896)     (over dead Ppart)
  ushort* h6b = wsu + 8912896;     // [.., 17301504)    (over dead Ppart/wcat)

  dim3 blk(256);
  // ---- prep: split x and encoder weights into f16 (hi, lo*2^11) pairs
  split_f16<<<dim3(2048), blk, 0, stream>>>(x, xh, xl, 4194304);
  transpose_split_f16<<<dim3(32, 64), blk, 0, stream>>>(w1, w1Th, w1Tl, 2048, 1024);
  transpose_split_f16<<<dim3(32, 32), blk, 0, stream>>>(w2, w2Th, w2Tl, 1024, 1024);
  // ---- encoder: split-f16 MFMA (error ~1e-6 rel, below fp32-reorder noise)
  gemm_f16x3<1><<<dim3(8, 64), blk, 0, stream>>>(xh, xl, w1Th, w1Tl, b1,
                                                 h1h, h1l, nullptr, 8192, 1024, 2048);
  transpose_split_f16<<<dim3(64, 32), blk, 0, stream>>>(w3, w3Th, w3Tl, 1024, 2048);
  gemm_f16x3<1><<<dim3(8, 64), blk, 0, stream>>>(h1h, h1l, w2Th, w2Tl, b2,
                                                 h2h, h2l, nullptr, 8192, 1024, 1024);
  // decoder weight prep (regions free only after fc2 reads h1l)
  transpose_bf16<<<dim3(64, 2),   blk, 0, stream>>>(w4, w4T, 64,   2048);
  transpose_bf16<<<dim3(32, 64),  blk, 0, stream>>>(w5, w5T, 2048, 1024);
  transpose_bf16<<<dim3(32, 32),  blk, 0, stream>>>(w6, w6T, 1024, 1024);
  transpose_bf16<<<dim3(128, 32), blk, 0, stream>>>(w7, w7T, 1024, 4096);
  // fc3 -> split pair (feeds MFMA fc41/42)
  gemm_f16x3<1><<<dim3(16, 64), blk, 0, stream>>>(h2h, h2l, w3Th, w3Tl, b3,
                                                  h3h, h3l, nullptr, 8192, 2048, 1024);
  // fc41/42: transpose+split weights (after fc3 frees w3T region), then
  // split-K MFMA (512 blocks vs dual64's 128) + deterministic reduce
  transpose_split_f16<<<dim3(2, 64), blk, 0, stream>>>(w41, wcatTh, wcatTl, 2048, 64);
  transpose_split_f16<<<dim3(2, 64), blk, 0, stream>>>(w42, wcatTh + 64 * 2048,
                                                       wcatTl + 64 * 2048, 2048, 64);
  dual_mfma<<<dim3(8, 64), blk, 0, stream>>>(h3h, h3l, wcatTh, wcatTl, Ppart);
  dual_reduce<<<dim3(1024), blk, 0, stream>>>(Ppart, b41, b42, la, lb);
  // reparameterize (exact fp32; also emits bf16 z)
  gamma_sampler<<<dim3(2048), blk, 0, stream>>>(la, lb, zz, zb);
  // decoder (bf16 MFMA)
  gemm_bf16<0><<<dim3(16, 64), blk, 0, stream>>>(zb,  w4T, b4, h4b, nullptr, nullptr, 8192, 2048, 64, 0);
  gemm_bf16<0><<<dim3(8, 64),  blk, 0, stream>>>(h4b, w5T, b5, h5b, nullptr, nullptr, 8192, 1024, 2048, 0);
  gemm_bf16<0><<<dim3(8, 64),  blk, 0, stream>>>(h5b, w6T, b6, h6b, nullptr, nullptr, 8192, 1024, 1024, 0);
  gemm_bf16<3><<<dim3(32, 64), blk, 0, stream>>>(h6b, w7T, b7, nullptr, recon_a, recon_b, 8192, 4096, 1024, 2048);
  (void)in_sizes; (void)n_in; (void)out_size; (void)ws_size;
}

// Round 5
// 922.144 us; speedup vs baseline: 1.8984x; 1.1681x over previous
//
#include <hip/hip_runtime.h>
#include <stdint.h>

#define DEVFN static __device__ __forceinline__

typedef __attribute__((ext_vector_type(8))) short short8;
typedef __attribute__((ext_vector_type(4))) float floatx4;
typedef _Float16 half8 __attribute__((ext_vector_type(8)));

// ---------------- Threefry-2x32 (20 rounds), exactly as JAX ----------------
DEVFN uint32_t rotl32(uint32_t v, int d) { return (v << d) | (v >> (32 - d)); }

DEVFN void tf2x32(uint32_t k0, uint32_t k1, uint32_t x0, uint32_t x1,
                  uint32_t& o0, uint32_t& o1) {
  uint32_t k2 = k0 ^ k1 ^ 0x1BD11BDAu;
  x0 += k0; x1 += k1;
  x0 += x1; x1 = rotl32(x1, 13); x1 ^= x0;
  x0 += x1; x1 = rotl32(x1, 15); x1 ^= x0;
  x0 += x1; x1 = rotl32(x1, 26); x1 ^= x0;
  x0 += x1; x1 = rotl32(x1, 6);  x1 ^= x0;
  x0 += k1; x1 += k2 + 1u;
  x0 += x1; x1 = rotl32(x1, 17); x1 ^= x0;
  x0 += x1; x1 = rotl32(x1, 29); x1 ^= x0;
  x0 += x1; x1 = rotl32(x1, 16); x1 ^= x0;
  x0 += x1; x1 = rotl32(x1, 24); x1 ^= x0;
  x0 += k2; x1 += k0 + 2u;
  x0 += x1; x1 = rotl32(x1, 13); x1 ^= x0;
  x0 += x1; x1 = rotl32(x1, 15); x1 ^= x0;
  x0 += x1; x1 = rotl32(x1, 26); x1 ^= x0;
  x0 += x1; x1 = rotl32(x1, 6);  x1 ^= x0;
  x0 += k0; x1 += k1 + 3u;
  x0 += x1; x1 = rotl32(x1, 17); x1 ^= x0;
  x0 += x1; x1 = rotl32(x1, 29); x1 ^= x0;
  x0 += x1; x1 = rotl32(x1, 16); x1 ^= x0;
  x0 += x1; x1 = rotl32(x1, 24); x1 ^= x0;
  x0 += k1; x1 += k2 + 4u;
  x0 += x1; x1 = rotl32(x1, 13); x1 ^= x0;
  x0 += x1; x1 = rotl32(x1, 15); x1 ^= x0;
  x0 += x1; x1 = rotl32(x1, 26); x1 ^= x0;
  x0 += x1; x1 = rotl32(x1, 6);  x1 ^= x0;
  x0 += k2; x1 += k0 + 5u;
  o0 = x0; o1 = x1;
}

// ---------------- XLA/CHLO f32 erf_inv (Giles), w = -log1p(-x^2) -----------
DEVFN float erfinv_f32(float x) {
#pragma clang fp contract(off)
  float w = -log1pf(-(x * x));
  float p;
  if (w < 5.0f) {
    w = w - 2.5f;
    p = 2.81022636e-08f;
    p = 3.43273939e-07f + p * w;
    p = -3.5233877e-06f + p * w;
    p = -4.39150654e-06f + p * w;
    p = 0.00021858087f + p * w;
    p = -0.00125372503f + p * w;
    p = -0.00417768164f + p * w;
    p = 0.246640727f + p * w;
    p = 1.50140941f + p * w;
  } else {
    w = __fsqrt_rn(w) - 3.0f;
    p = -0.000200214257f;
    p = 0.000100950558f + p * w;
    p = 0.00134934322f + p * w;
    p = -0.00367342844f + p * w;
    p = 0.00573950773f + p * w;
    p = -0.0076224613f + p * w;
    p = 0.00943887047f + p * w;
    p = 1.00167406f + p * w;
    p = 2.83297682f + p * w;
  }
  return p * x;
}

// jax.nn.softplus(x) = logaddexp(x,0) = max(x,0) + log1p(exp(-|x|))
// EXACT version (feeds discrete accept/reject via logalpha)
DEVFN float softplus_ref(float v) {
#pragma clang fp contract(off)
  return fmaxf(v, 0.0f) + log1pf(expf(-fabsf(v)));
}

// FAST version for recon outputs only (abs err ~1e-6 << 0.23 threshold):
// replaces branchy log1pf library seq (~40 ops) with v_exp+v_log (~10 ops)
DEVFN float softplus_fast(float v) {
  float e = __expf(-fabsf(v));
  return fmaxf(v, 0.0f) + __logf(1.0f + e);
}

// fp32 -> bf16 RNE
DEVFN ushort f2bf(float f) {
  uint32_t u = __float_as_uint(f);
  uint32_t r = (u + 0x7FFFu + ((u >> 16) & 1u)) >> 16;
  return (ushort)r;
}

// fp32 -> (f16 hi, f16 lo*2048) split. a = hi + lo/2048 + O(2^-23 |a|).
DEVFN void split2(float a, ushort& hb, ushort& lb) {
  _Float16 h = (_Float16)a;
  float r = (a - (float)h) * 2048.0f;  // a-hf exact (Sterbenz); *2^11 exact
  _Float16 l = (_Float16)r;
  hb = __builtin_bit_cast(unsigned short, h);
  lb = __builtin_bit_cast(unsigned short, l);
}

// async global->LDS, 16 B per lane; lds must be wave-uniform base
DEVFN void gl2lds16(const void* g, void* l) {
  __builtin_amdgcn_global_load_lds(
      (const __attribute__((address_space(1))) void*)g,
      (__attribute__((address_space(3))) void*)l, 16, 0, 0);
}

// XCD-chunked blockIdx swizzle (T1/m204): bijective when nwg % 8 == 0.
DEVFN int xcd_swizzle(int bid, int nwg) {
  if ((nwg & 7) == 0) return (bid & 7) * (nwg >> 3) + (bid >> 3);
  return bid;
}

// ---------------- elementwise split: x -> (xh, xl) f16 pairs ----------------
__global__ __launch_bounds__(256) void split_f16(
    const float* __restrict__ in, ushort* __restrict__ oh,
    ushort* __restrict__ ol, int n4) {
  int idx = blockIdx.x * 256 + threadIdx.x;
  int stride = gridDim.x * 256;
  for (int i = idx; i < n4; i += stride) {
    float4 a = ((const float4*)in)[i];
    ushort h0, h1, h2, h3, l0, l1, l2, l3;
    split2(a.x, h0, l0); split2(a.y, h1, l1);
    split2(a.z, h2, l2); split2(a.w, h3, l3);
    ushort4 hv; hv.x = h0; hv.y = h1; hv.z = h2; hv.w = h3;
    ushort4 lv; lv.x = l0; lv.y = l1; lv.z = l2; lv.w = l3;
    ((ushort4*)oh)[i] = hv;
    ((ushort4*)ol)[i] = lv;
  }
}

// ---------------- transpose + f16-split: out*[c][r] = split(in[r][c]) -------
__global__ __launch_bounds__(256) void transpose_split_f16(
    const float* __restrict__ in, ushort* __restrict__ oh,
    ushort* __restrict__ ol, int R, int C) {
  __shared__ float tile[32][33];
  const int c0 = blockIdx.x * 32, r0 = blockIdx.y * 32;
  const int tx = threadIdx.x & 31, ty = threadIdx.x >> 5;
#pragma unroll
  for (int i = ty; i < 32; i += 8)
    tile[i][tx] = in[(size_t)(r0 + i) * C + c0 + tx];
  __syncthreads();
#pragma unroll
  for (int i = ty; i < 32; i += 8) {
    ushort hb, lb;
    split2(tile[tx][i], hb, lb);
    size_t o = (size_t)(c0 + i) * R + r0 + tx;
    oh[o] = hb; ol[o] = lb;
  }
}

// ---------------- split-f16 MFMA GEMM: C = act(A @ Bt^T + bias) -------------
// acc1 = Ah*Bh ; acc2 = Ah*Bl + Al*Bh ; result = acc1 + acc2/2048  (fp32).
// 2-phase pipelined (T3-minimum): dbuf LDS, stage(t+1) issued before
// compute(t), single raw barrier + vmcnt(0) drain per k-step (loads are
// nearly complete by then -> latency hidden under ds_read+MFMA).
// ACT 1: relu -> f16-split pair (Oh,Ol). ACT 2: relu -> fp32 Of.
template <int ACT>
__global__ __launch_bounds__(256) void gemm_f16x3(
    const ushort* __restrict__ Ah, const ushort* __restrict__ Al,
    const ushort* __restrict__ Bh, const ushort* __restrict__ Bl,
    const float* __restrict__ bias, ushort* __restrict__ Oh,
    ushort* __restrict__ Ol, float* __restrict__ Of, int M, int N, int K) {
  __shared__ ushort AsH[2][128 * 32];
  __shared__ ushort AsL[2][128 * 32];
  __shared__ ushort BsH[2][128 * 32];
  __shared__ ushort BsL[2][128 * 32];
  const int tid = threadIdx.x;
  const int wave = tid >> 6, lane = tid & 63;
  const int nbx = gridDim.x;
  const int bid = xcd_swizzle(blockIdx.y * nbx + blockIdx.x, nbx * gridDim.y);
  const int m0 = (bid / nbx) * 128, n0 = (bid % nbx) * 128;
  const int lrow = lane & 15, lq = lane >> 4;
  const int wm = wave & 1, wn = wave >> 1;
  const int srow = lane >> 2;
  const int scol = (lane & 3) * 8;

  floatx4 acc1[4][4], acc2[4][4];
#pragma unroll
  for (int i = 0; i < 4; i++)
#pragma unroll
    for (int j = 0; j < 4; j++) {
      acc1[i][j] = (floatx4){0.f, 0.f, 0.f, 0.f};
      acc2[i][j] = (floatx4){0.f, 0.f, 0.f, 0.f};
    }

  auto stage = [&](int k0, int pp) {
#pragma unroll
    for (int h = 0; h < 2; h++) {
      int r0 = wave * 32 + h * 16;
      gl2lds16(Ah + (size_t)(m0 + r0 + srow) * K + k0 + scol, &AsH[pp][r0 * 32]);
      gl2lds16(Al + (size_t)(m0 + r0 + srow) * K + k0 + scol, &AsL[pp][r0 * 32]);
      gl2lds16(Bh + (size_t)(n0 + r0 + srow) * K + k0 + scol, &BsH[pp][r0 * 32]);
      gl2lds16(Bl + (size_t)(n0 + r0 + srow) * K + k0 + scol, &BsL[pp][r0 * 32]);
    }
  };

  const int nt = K >> 5;
  stage(0, 0);
  asm volatile("s_waitcnt vmcnt(0)" ::: "memory");
  __builtin_amdgcn_s_barrier();
  int cur = 0;
  for (int t = 0; t < nt; t++) {
    if (t + 1 < nt) stage((t + 1) << 5, cur ^ 1);
    half8 ah[4], al[4];
#pragma unroll
    for (int i = 0; i < 4; i++) {
      ah[i] = *(const half8*)&AsH[cur][(wm * 64 + i * 16 + lrow) * 32 + lq * 8];
      al[i] = *(const half8*)&AsL[cur][(wm * 64 + i * 16 + lrow) * 32 + lq * 8];
    }
#pragma unroll
    for (int j = 0; j < 4; j++) {
      half8 bh = *(const half8*)&BsH[cur][(wn * 64 + j * 16 + lrow) * 32 + lq * 8];
      half8 bl = *(const half8*)&BsL[cur][(wn * 64 + j * 16 + lrow) * 32 + lq * 8];
#pragma unroll
      for (int i = 0; i < 4; i++) {
        acc1[i][j] = __builtin_amdgcn_mfma_f32_16x16x32_f16(ah[i], bh,
                                                            acc1[i][j], 0, 0, 0);
        acc2[i][j] = __builtin_amdgcn_mfma_f32_16x16x32_f16(ah[i], bl,
                                                            acc2[i][j], 0, 0, 0);
        acc2[i][j] = __builtin_amdgcn_mfma_f32_16x16x32_f16(al[i], bh,
                                                            acc2[i][j], 0, 0, 0);
      }
    }
    // ds_reads retired (in-order before MFMA issue); drain DMA + barrier ->
    // next iter may safely DMA into buf[cur] and read buf[cur^1].
    asm volatile("s_waitcnt vmcnt(0)" ::: "memory");
    __builtin_amdgcn_sched_barrier(0);
    __builtin_amdgcn_s_barrier();
    cur ^= 1;
  }

  // C/D layout: col = lane&15, row = (lane>>4)*4 + reg  [measured m89/m91]
  const float INV2048 = 4.8828125e-4f;
#pragma unroll
  for (int i = 0; i < 4; i++) {
#pragma unroll
    for (int j = 0; j < 4; j++) {
      int colg = n0 + wn * 64 + j * 16 + lrow;
      float bb = bias[colg];
#pragma unroll
      for (int r = 0; r < 4; r++) {
        int rowg = m0 + wm * 64 + i * 16 + lq * 4 + r;
        float v = acc1[i][j][r] + acc2[i][j][r] * INV2048 + bb;
        v = fmaxf(v, 0.0f);
        if (ACT == 1) {
          ushort hb, lb;
          split2(v, hb, lb);
          size_t o = (size_t)rowg * N + colg;
          Oh[o] = hb; Ol[o] = lb;
        } else {
          Of[(size_t)rowg * N + colg] = v;
        }
      }
    }
  }
}

// ---------------- fc41+fc42 via split-K MFMA ---------------------------------
// logits[8192,128] = h3(split) @ wcat(split)^T, K=2048 in 8 chunks of 256.
__global__ __launch_bounds__(256) void dual_mfma(
    const ushort* __restrict__ Ah, const ushort* __restrict__ Al,
    const ushort* __restrict__ Bh, const ushort* __restrict__ Bl,
    float* __restrict__ P) {
  __shared__ ushort AsH[128 * 32];
  __shared__ ushort AsL[128 * 32];
  __shared__ ushort BsH[128 * 32];
  __shared__ ushort BsL[128 * 32];
  const int K = 2048;
  const int tid = threadIdx.x;
  const int wave = tid >> 6, lane = tid & 63;
  const int m0 = blockIdx.y * 128;
  const int kbase = blockIdx.x * 256;
  const int lrow = lane & 15, lq = lane >> 4;
  const int wm = wave & 1, wn = wave >> 1;
  const int srow = lane >> 2;
  const int scol = (lane & 3) * 8;

  floatx4 acc1[4][4], acc2[4][4];
#pragma unroll
  for (int i = 0; i < 4; i++)
#pragma unroll
    for (int j = 0; j < 4; j++) {
      acc1[i][j] = (floatx4){0.f, 0.f, 0.f, 0.f};
      acc2[i][j] = (floatx4){0.f, 0.f, 0.f, 0.f};
    }

  for (int kk = 0; kk < 256; kk += 32) {
    int k0 = kbase + kk;
#pragma unroll
    for (int h = 0; h < 2; h++) {
      int r0 = wave * 32 + h * 16;
      gl2lds16(Ah + (size_t)(m0 + r0 + srow) * K + k0 + scol, &AsH[r0 * 32]);
      gl2lds16(Al + (size_t)(m0 + r0 + srow) * K + k0 + scol, &AsL[r0 * 32]);
      gl2lds16(Bh + (size_t)(r0 + srow) * K + k0 + scol, &BsH[r0 * 32]);
      gl2lds16(Bl + (size_t)(r0 + srow) * K + k0 + scol, &BsL[r0 * 32]);
    }
    __syncthreads();
    half8 ah[4], al[4];
#pragma unroll
    for (int i = 0; i < 4; i++) {
      ah[i] = *(const half8*)&AsH[(wm * 64 + i * 16 + lrow) * 32 + lq * 8];
      al[i] = *(const half8*)&AsL[(wm * 64 + i * 16 + lrow) * 32 + lq * 8];
    }
#pragma unroll
    for (int j = 0; j < 4; j++) {
      half8 bh = *(const half8*)&BsH[(wn * 64 + j * 16 + lrow) * 32 + lq * 8];
      half8 bl = *(const half8*)&BsL[(wn * 64 + j * 16 + lrow) * 32 + lq * 8];
#pragma unroll
      for (int i = 0; i < 4; i++) {
        acc1[i][j] = __builtin_amdgcn_mfma_f32_16x16x32_f16(ah[i], bh,
                                                            acc1[i][j], 0, 0, 0);
        acc2[i][j] = __builtin_amdgcn_mfma_f32_16x16x32_f16(ah[i], bl,
                                                            acc2[i][j], 0, 0, 0);
        acc2[i][j] = __builtin_amdgcn_mfma_f32_16x16x32_f16(al[i], bh,
                                                            acc2[i][j], 0, 0, 0);
      }
    }
    __syncthreads();
  }

  const float INV2048 = 4.8828125e-4f;
#pragma unroll
  for (int i = 0; i < 4; i++) {
#pragma unroll
    for (int j = 0; j < 4; j++) {
      int colg = wn * 64 + j * 16 + lrow;
#pragma unroll
      for (int r = 0; r < 4; r++) {
        int rowg = m0 + wm * 64 + i * 16 + lq * 4 + r;
        float v = acc1[i][j][r] + acc2[i][j][r] * INV2048;
        P[((size_t)blockIdx.x * 8192 + rowg) * 128 + colg] = v;
      }
    }
  }
}

// ---------------- reduce 8 split-K partials + bias + softplus ---------------
// Fixed k-order sum -> deterministic. EXACT softplus (feeds accepts).
__global__ __launch_bounds__(256) void dual_reduce(
    const float* __restrict__ P, const float* __restrict__ b41,
    const float* __restrict__ b42, float* __restrict__ la,
    float* __restrict__ lb) {
#pragma clang fp contract(off)
  int idx = blockIdx.x * 256 + threadIdx.x;  // [0, 262144)
  int row = idx >> 5;
  int c4 = (idx & 31) * 4;
  float4 s = {0.f, 0.f, 0.f, 0.f};
#pragma unroll
  for (int k = 0; k < 8; k++) {
    float4 p = *(const float4*)&P[((size_t)k * 8192 + row) * 128 + c4];
    s.x += p.x; s.y += p.y; s.z += p.z; s.w += p.w;
  }
  float o[4];
  const float* bb = (c4 < 64) ? (b41 + c4) : (b42 + c4 - 64);
#pragma unroll
  for (int q = 0; q < 4; q++) {
    float v = (&s.x)[q] + bb[q];
    o[q] = 1e-6f + softplus_ref(v);
  }
  float* dst = (c4 < 64) ? (la + (size_t)row * 64 + c4)
                         : (lb + (size_t)row * 64 + (c4 - 64));
  *(float4*)dst = *(float4*)o;
}

// ---------------- Marsaglia-Tsang sampler, JAX partitionable threefry -------
// JAX's partitionable threefry returns bits1 ^ bits2 for 32-bit draws.
__global__ __launch_bounds__(256) void gamma_sampler(
    const float* __restrict__ la, const float* __restrict__ lb,
    float* __restrict__ z, ushort* __restrict__ zb) {
#pragma clang fp contract(off)
  const uint32_t i = blockIdx.x * 256u + threadIdx.x;
  uint32_t k1a, k1b, k2a, k2b;
  tf2x32(0u, 42u, 0u, 0u, k1a, k1b);  // split: child key = both output words
  tf2x32(0u, 42u, 0u, 1u, k2a, k2b);

  const float LO = __uint_as_float(0xBF7FFFFFu);
  const float SQRT2 = __uint_as_float(0x3FB504F3u);
  const float USCALE = 1.0f - 1e-7f;

  const float al = la[i];
  const float be = lb[i];
  const float d = (al + 1.0f) - 0.33333334f;
  const float c = 1.0f / __fsqrt_rn(9.0f * d);

  float es = 0.0f, us = 0.0f;
  bool done = false;
  for (int k = 0; k < 24; k++) {
    if (__all(done)) break;
    if (!done) {
      uint32_t n = (uint32_t)k * 524288u + i;
      uint32_t o0, o1, p0, p1;
      tf2x32(k1a, k1b, 0u, n, o0, o1);
      tf2x32(k2a, k2b, 0u, n, p0, p1);
      uint32_t eb = o0 ^ o1;  // JAX: bits = bits1 ^ bits2 (32-bit path)
      uint32_t ub = p0 ^ p1;
      float f = __uint_as_float((eb >> 9) | 0x3F800000u) - 1.0f;
      float un = f * 2.0f + LO;
      un = fmaxf(LO, un);
      float e = SQRT2 * erfinv_f32(un);
      float g = __uint_as_float((ub >> 9) | 0x3F800000u) - 1.0f;
      float u = g * USCALE + 1e-7f;
      u = fmaxf(1e-7f, u);
      if (k == 0) { es = e; us = u; }
      float v = 1.0f + c * e;
      if (v > 0.0f) {
        float v3 = (v * v) * v;
        float e2 = e * e;
        bool acc = false;
        float sq = 1.0f - (0.0331f * e2) * e2;
        if (u < sq) acc = true;
        else {
          float rhs = (0.5f * e) * e + d * ((1.0f - v3) + logf(v3));
          if (logf(u) < rhs) acc = true;
        }
        if (acc) { es = e; us = u; done = true; }
      }
    }
  }
  float vv = 1.0f + c * es;
  float vs = (vv * vv) * vv;
  float t = logf(d * vs + 1e-6f) + logf(us + 1e-6f) / (al + 1e-6f);
  float zv = expf(t) / (be + 1e-6f);
  z[i] = zv;
  zb[i] = f2bf(zv);
}

// ---------------- transpose + fp32->bf16: out[c][r] = bf16(in[r][c]) --------
__global__ __launch_bounds__(256) void transpose_bf16(
    const float* __restrict__ in, ushort* __restrict__ out, int R, int C) {
  __shared__ float tile[32][33];
  const int c0 = blockIdx.x * 32, r0 = blockIdx.y * 32;
  const int tx = threadIdx.x & 31, ty = threadIdx.x >> 5;
#pragma unroll
  for (int i = ty; i < 32; i += 8)
    tile[i][tx] = in[(size_t)(r0 + i) * C + c0 + tx];
  __syncthreads();
#pragma unroll
  for (int i = ty; i < 32; i += 8)
    out[(size_t)(c0 + i) * R + r0 + tx] = f2bf(tile[tx][i]);
}

// ---------------- bf16 MFMA GEMM, 2-phase pipelined -------------------------
// ACT 0: relu -> bf16 C0b[M,N];  ACT 3: 1e-6+softplus_fast split -> C0f/C1f
template <int ACT>
__global__ __launch_bounds__(256) void gemm_bf16(
    const ushort* __restrict__ A, const ushort* __restrict__ Bt,
    const float* __restrict__ bias, ushort* __restrict__ C0b,
    float* __restrict__ C0f, float* __restrict__ C1f,
    int M, int N, int K, int split) {
  __shared__ ushort As[2][128 * 32];
  __shared__ ushort Bs[2][128 * 32];
  const int tid = threadIdx.x;
  const int wave = tid >> 6, lane = tid & 63;
  const int nbx = gridDim.x;
  const int bid = xcd_swizzle(blockIdx.y * nbx + blockIdx.x, nbx * gridDim.y);
  const int m0 = (bid / nbx) * 128, n0 = (bid % nbx) * 128;
  const int lrow = lane & 15, lq = lane >> 4;
  const int wm = wave & 1, wn = wave >> 1;
  const int srow = lane >> 2;
  const int scol = (lane & 3) * 8;

  floatx4 acc[4][4];
#pragma unroll
  for (int i = 0; i < 4; i++)
#pragma unroll
    for (int j = 0; j < 4; j++) acc[i][j] = (floatx4){0.f, 0.f, 0.f, 0.f};

  auto stage = [&](int k0, int pp) {
#pragma unroll
    for (int h = 0; h < 2; h++) {
      int r0 = wave * 32 + h * 16;
      gl2lds16(A + (size_t)(m0 + r0 + srow) * K + k0 + scol, &As[pp][r0 * 32]);
      gl2lds16(Bt + (size_t)(n0 + r0 + srow) * K + k0 + scol, &Bs[pp][r0 * 32]);
    }
  };

  const int nt = K >> 5;
  stage(0, 0);
  asm volatile("s_waitcnt vmcnt(0)" ::: "memory");
  __builtin_amdgcn_s_barrier();
  int cur = 0;
  for (int t = 0; t < nt; t++) {
    if (t + 1 < nt) stage((t + 1) << 5, cur ^ 1);
    short8 a[4], b[4];
#pragma unroll
    for (int i = 0; i < 4; i++) {
      a[i] = *(const short8*)&As[cur][(wm * 64 + i * 16 + lrow) * 32 + lq * 8];
      b[i] = *(const short8*)&Bs[cur][(wn * 64 + i * 16 + lrow) * 32 + lq * 8];
    }
#pragma unroll
    for (int i = 0; i < 4; i++)
#pragma unroll
      for (int j = 0; j < 4; j++)
        acc[i][j] = __builtin_amdgcn_mfma_f32_16x16x32_bf16(a[i], b[j],
                                                            acc[i][j], 0, 0, 0);
    asm volatile("s_waitcnt vmcnt(0)" ::: "memory");
    __builtin_amdgcn_sched_barrier(0);
    __builtin_amdgcn_s_barrier();
    cur ^= 1;
  }

#pragma unroll
  for (int i = 0; i < 4; i++) {
#pragma unroll
    for (int j = 0; j < 4; j++) {
      int colg = n0 + wn * 64 + j * 16 + lrow;
      float bb = bias[colg];
#pragma unroll
      for (int r = 0; r < 4; r++) {
        int rowg = m0 + wm * 64 + i * 16 + lq * 4 + r;
        float v = acc[i][j][r] + bb;
        if (ACT == 0) {
          v = fmaxf(v, 0.0f);
          C0b[(size_t)rowg * N + colg] = f2bf(v);
        } else {
          v = 1e-6f + softplus_fast(v);
          if (colg < split) C0f[(size_t)rowg * split + colg] = v;
          else              C1f[(size_t)rowg * split + (colg - split)] = v;
        }
      }
    }
  }
}

// ---------------------------------------------------------------------------
extern "C" void kernel_launch(void* const* d_in, const int* in_sizes, int n_in,
                              void* d_out, int out_size, void* d_ws,
                              size_t ws_size, hipStream_t stream) {
  const float* x   = (const float*)d_in[0];
  const float* w1  = (const float*)d_in[1];  const float* b1  = (const float*)d_in[2];
  const float* w2  = (const float*)d_in[3];  const float* b2  = (const float*)d_in[4];
  const float* w3  = (const float*)d_in[5];  const float* b3  = (const float*)d_in[6];
  const float* w41 = (const float*)d_in[7];  const float* b41 = (const float*)d_in[8];
  const float* w42 = (const float*)d_in[9];  const float* b42 = (const float*)d_in[10];
  const float* w4  = (const float*)d_in[11]; const float* b4  = (const float*)d_in[12];
  const float* w5  = (const float*)d_in[13]; const float* b5  = (const float*)d_in[14];
  const float* w6  = (const float*)d_in[15]; const float* b6  = (const float*)d_in[16];
  const float* w7  = (const float*)d_in[17]; const float* b7  = (const float*)d_in[18];
  float* out = (float*)d_out;
  float* ws  = (float*)d_ws;
  ushort* wsu = (ushort*)d_ws;

  // output layout (floats): recon_al | recon_be | logalpha | logbeta | z
  float* recon_a = out;
  float* recon_b = out + 16777216;
  float* la      = out + 33554432;
  float* lb      = out + 34078720;
  float* zz      = out + 34603008;

  // ---- workspace layout (ushort offsets unless noted); peak 124 MB.
  ushort* xh   = wsu;              // [0, 16777216)            dead after fc1
  ushort* xl   = wsu + 16777216;   // [16777216, 33554432)     dead after fc1
  ushort* w1Th = wsu + 33554432;   // [.., 35651584)           dead after fc1
  ushort* w1Tl = wsu + 35651584;   // [.., 37748736)
  ushort* w2Th = wsu + 37748736;   // [.., 38797312)           dead after fc2
  ushort* w2Tl = wsu + 38797312;   // [.., 39845888)
  ushort* h1h  = wsu + 39845888;   // [.., 48234496)           dead after fc2
  ushort* h1l  = wsu + 48234496;   // [.., 56623104)
  ushort* w3Th = wsu + 16777216;   // overwrites xl AFTER fc1  dead after fc3
  ushort* w3Tl = wsu + 18874368;   // [.., 20971520)
  ushort* h2h  = wsu;              // overwrites xh AFTER fc1  dead after fc3
  ushort* h2l  = wsu + 8388608;    // [.., 16777216)
  // fc3 output: split pair (over dead w1T/w2T/h1); dead after dual_mfma
  ushort* h3h  = wsu + 20971520;   // [20971520, 37748736)
  ushort* h3l  = wsu + 37748736;   // [37748736, 54525952)
  // fc41|fc42 concat weights, transposed+split [128, 2048] over dead w3T
  ushort* wcatTh = wsu + 16777216; // [16777216, 17039360)
  ushort* wcatTl = wsu + 17039360; // [17039360, 17301504)
  // split-K partials [8][8192][128] fp32 = 33.5 MB over dead x/h2 region
  float*  Ppart = ws;              // float [0, 8388608) = ushort [0,16777216)
  // decoder (bf16), after h3 region — over dead h1l tail:
  ushort* w4T = wsu + 54525952;    // [64,2048]   -> 54657024
  ushort* w5T = wsu + 54657024;    // [1024,2048] -> 56754176
  ushort* w6T = wsu + 56754176;    // [1024,1024] -> 57802752
  ushort* w7T = wsu + 57802752;    // [4096,1024] -> 61997056
  ushort* zb  = wsu;               // [0, 524288)       (Ppart dead by sampler)
  ushort* h4b = wsu + 20971520;    // [.., 37748736)    (over dead h3h)
  ushort* h5b = wsu + 524288;      // [.., 8912896)     (over dead Ppart)
  ushort* h6b = wsu + 8912896;     // [.., 17301504)    (over dead Ppart/wcat)

  dim3 blk(256);
  // ---- prep: split x and encoder weights into f16 (hi, lo*2^11) pairs
  split_f16<<<dim3(2048), blk, 0, stream>>>(x, xh, xl, 4194304);
  transpose_split_f16<<<dim3(32, 64), blk, 0, stream>>>(w1, w1Th, w1Tl, 2048, 1024);
  transpose_split_f16<<<dim3(32, 32), blk, 0, stream>>>(w2, w2Th, w2Tl, 1024, 1024);
  // ---- encoder: split-f16 MFMA (error ~1e-6 rel)
  gemm_f16x3<1><<<dim3(8, 64), blk, 0, stream>>>(xh, xl, w1Th, w1Tl, b1,
                                                 h1h, h1l, nullptr, 8192, 1024, 2048);
  transpose_split_f16<<<dim3(64, 32), blk, 0, stream>>>(w3, w3Th, w3Tl, 1024, 2048);
  gemm_f16x3<1><<<dim3(8, 64), blk, 0, stream>>>(h1h, h1l, w2Th, w2Tl, b2,
                                                 h2h, h2l, nullptr, 8192, 1024, 1024);
  // decoder weight prep (regions free only after fc2 reads h1l)
  transpose_bf16<<<dim3(64, 2),   blk, 0, stream>>>(w4, w4T, 64,   2048);
  transpose_bf16<<<dim3(32, 64),  blk, 0, stream>>>(w5, w5T, 2048, 1024);
  transpose_bf16<<<dim3(32, 32),  blk, 0, stream>>>(w6, w6T, 1024, 1024);
  transpose_bf16<<<dim3(128, 32), blk, 0, stream>>>(w7, w7T, 1024, 4096);
  // fc3 -> split pair (feeds MFMA fc41/42)
  gemm_f16x3<1><<<dim3(16, 64), blk, 0, stream>>>(h2h, h2l, w3Th, w3Tl, b3,
                                                  h3h, h3l, nullptr, 8192, 2048, 1024);
  // fc41/42: split-K MFMA + deterministic reduce
  transpose_split_f16<<<dim3(2, 64), blk, 0, stream>>>(w41, wcatTh, wcatTl, 2048, 64);
  transpose_split_f16<<<dim3(2, 64), blk, 0, stream>>>(w42, wcatTh + 64 * 2048,
                                                       wcatTl + 64 * 2048, 2048, 64);
  dual_mfma<<<dim3(8, 64), blk, 0, stream>>>(h3h, h3l, wcatTh, wcatTl, Ppart);
  dual_reduce<<<dim3(1024), blk, 0, stream>>>(Ppart, b41, b42, la, lb);
  // reparameterize (exact fp32; also emits bf16 z)
  gamma_sampler<<<dim3(2048), blk, 0, stream>>>(la, lb, zz, zb);
  // decoder (bf16 MFMA)
  gemm_bf16<0><<<dim3(16, 64), blk, 0, stream>>>(zb,  w4T, b4, h4b, nullptr, nullptr, 8192, 2048, 64, 0);
  gemm_bf16<0><<<dim3(8, 64),  blk, 0, stream>>>(h4b, w5T, b5, h5b, nullptr, nullptr, 8192, 1024, 2048, 0);
  gemm_bf16<0><<<dim3(8, 64),  blk, 0, stream>>>(h5b, w6T, b6, h6b, nullptr, nullptr, 8192, 1024, 1024, 0);
  gemm_bf16<3><<<dim3(32, 64), blk, 0, stream>>>(h6b, w7T, b7, nullptr, recon_a, recon_b, 8192, 4096, 1024, 2048);
  (void)in_sizes; (void)n_in; (void)out_size; (void)ws_size;
}

// Round 6
// 917.976 us; speedup vs baseline: 1.9070x; 1.0045x over previous
//
#include <hip/hip_runtime.h>
#include <stdint.h>

#define DEVFN static __device__ __forceinline__

typedef __attribute__((ext_vector_type(8))) short short8;
typedef __attribute__((ext_vector_type(4))) float floatx4;
typedef _Float16 half8 __attribute__((ext_vector_type(8)));

// ---------------- Threefry-2x32 (20 rounds), exactly as JAX ----------------
DEVFN uint32_t rotl32(uint32_t v, int d) { return (v << d) | (v >> (32 - d)); }

DEVFN void tf2x32(uint32_t k0, uint32_t k1, uint32_t x0, uint32_t x1,
                  uint32_t& o0, uint32_t& o1) {
  uint32_t k2 = k0 ^ k1 ^ 0x1BD11BDAu;
  x0 += k0; x1 += k1;
  x0 += x1; x1 = rotl32(x1, 13); x1 ^= x0;
  x0 += x1; x1 = rotl32(x1, 15); x1 ^= x0;
  x0 += x1; x1 = rotl32(x1, 26); x1 ^= x0;
  x0 += x1; x1 = rotl32(x1, 6);  x1 ^= x0;
  x0 += k1; x1 += k2 + 1u;
  x0 += x1; x1 = rotl32(x1, 17); x1 ^= x0;
  x0 += x1; x1 = rotl32(x1, 29); x1 ^= x0;
  x0 += x1; x1 = rotl32(x1, 16); x1 ^= x0;
  x0 += x1; x1 = rotl32(x1, 24); x1 ^= x0;
  x0 += k2; x1 += k0 + 2u;
  x0 += x1; x1 = rotl32(x1, 13); x1 ^= x0;
  x0 += x1; x1 = rotl32(x1, 15); x1 ^= x0;
  x0 += x1; x1 = rotl32(x1, 26); x1 ^= x0;
  x0 += x1; x1 = rotl32(x1, 6);  x1 ^= x0;
  x0 += k0; x1 += k1 + 3u;
  x0 += x1; x1 = rotl32(x1, 17); x1 ^= x0;
  x0 += x1; x1 = rotl32(x1, 29); x1 ^= x0;
  x0 += x1; x1 = rotl32(x1, 16); x1 ^= x0;
  x0 += x1; x1 = rotl32(x1, 24); x1 ^= x0;
  x0 += k1; x1 += k2 + 4u;
  x0 += x1; x1 = rotl32(x1, 13); x1 ^= x0;
  x0 += x1; x1 = rotl32(x1, 15); x1 ^= x0;
  x0 += x1; x1 = rotl32(x1, 26); x1 ^= x0;
  x0 += x1; x1 = rotl32(x1, 6);  x1 ^= x0;
  x0 += k2; x1 += k0 + 5u;
  o0 = x0; o1 = x1;
}

// ---------------- XLA/CHLO f32 erf_inv (Giles), w = -log1p(-x^2) -----------
DEVFN float erfinv_f32(float x) {
#pragma clang fp contract(off)
  float w = -log1pf(-(x * x));
  float p;
  if (w < 5.0f) {
    w = w - 2.5f;
    p = 2.81022636e-08f;
    p = 3.43273939e-07f + p * w;
    p = -3.5233877e-06f + p * w;
    p = -4.39150654e-06f + p * w;
    p = 0.00021858087f + p * w;
    p = -0.00125372503f + p * w;
    p = -0.00417768164f + p * w;
    p = 0.246640727f + p * w;
    p = 1.50140941f + p * w;
  } else {
    w = __fsqrt_rn(w) - 3.0f;
    p = -0.000200214257f;
    p = 0.000100950558f + p * w;
    p = 0.00134934322f + p * w;
    p = -0.00367342844f + p * w;
    p = 0.00573950773f + p * w;
    p = -0.0076224613f + p * w;
    p = 0.00943887047f + p * w;
    p = 1.00167406f + p * w;
    p = 2.83297682f + p * w;
  }
  return p * x;
}

// jax.nn.softplus(x) = logaddexp(x,0) = max(x,0) + log1p(exp(-|x|))
// EXACT version (feeds discrete accept/reject via logalpha)
DEVFN float softplus_ref(float v) {
#pragma clang fp contract(off)
  return fmaxf(v, 0.0f) + log1pf(expf(-fabsf(v)));
}

// FAST version for recon outputs only (abs err ~1e-6 << 0.23 threshold)
DEVFN float softplus_fast(float v) {
  float e = __expf(-fabsf(v));
  return fmaxf(v, 0.0f) + __logf(1.0f + e);
}

// fp32 -> bf16 RNE
DEVFN ushort f2bf(float f) {
  uint32_t u = __float_as_uint(f);
  uint32_t r = (u + 0x7FFFu + ((u >> 16) & 1u)) >> 16;
  return (ushort)r;
}

// fp32 -> (f16 hi, f16 lo*2048) split. a = hi + lo/2048 + O(2^-23 |a|).
DEVFN void split2(float a, ushort& hb, ushort& lb) {
  _Float16 h = (_Float16)a;
  float r = (a - (float)h) * 2048.0f;  // a-hf exact (Sterbenz); *2^11 exact
  _Float16 l = (_Float16)r;
  hb = __builtin_bit_cast(unsigned short, h);
  lb = __builtin_bit_cast(unsigned short, l);
}

// async global->LDS, 16 B per lane; lds must be wave-uniform base
DEVFN void gl2lds16(const void* g, void* l) {
  __builtin_amdgcn_global_load_lds(
      (const __attribute__((address_space(1))) void*)g,
      (__attribute__((address_space(3))) void*)l, 16, 0, 0);
}

// XCD-chunked blockIdx swizzle (T1/m204): bijective when nwg % 8 == 0.
DEVFN int xcd_swizzle(int bid, int nwg) {
  if ((nwg & 7) == 0) return (bid & 7) * (nwg >> 3) + (bid >> 3);
  return bid;
}

// ---------------- elementwise split: x -> (xh, xl) f16 pairs ----------------
__global__ __launch_bounds__(256) void split_f16(
    const float* __restrict__ in, ushort* __restrict__ oh,
    ushort* __restrict__ ol, int n4) {
  int idx = blockIdx.x * 256 + threadIdx.x;
  int stride = gridDim.x * 256;
  for (int i = idx; i < n4; i += stride) {
    float4 a = ((const float4*)in)[i];
    ushort h0, h1, h2, h3, l0, l1, l2, l3;
    split2(a.x, h0, l0); split2(a.y, h1, l1);
    split2(a.z, h2, l2); split2(a.w, h3, l3);
    ushort4 hv; hv.x = h0; hv.y = h1; hv.z = h2; hv.w = h3;
    ushort4 lv; lv.x = l0; lv.y = l1; lv.z = l2; lv.w = l3;
    ((ushort4*)oh)[i] = hv;
    ((ushort4*)ol)[i] = lv;
  }
}

// ---------------- transpose + f16-split: out*[c][r] = split(in[r][c]) -------
__global__ __launch_bounds__(256) void transpose_split_f16(
    const float* __restrict__ in, ushort* __restrict__ oh,
    ushort* __restrict__ ol, int R, int C) {
  __shared__ float tile[32][33];
  const int c0 = blockIdx.x * 32, r0 = blockIdx.y * 32;
  const int tx = threadIdx.x & 31, ty = threadIdx.x >> 5;
#pragma unroll
  for (int i = ty; i < 32; i += 8)
    tile[i][tx] = in[(size_t)(r0 + i) * C + c0 + tx];
  __syncthreads();
#pragma unroll
  for (int i = ty; i < 32; i += 8) {
    ushort hb, lb;
    split2(tile[tx][i], hb, lb);
    size_t o = (size_t)(c0 + i) * R + r0 + tx;
    oh[o] = hb; ol[o] = lb;
  }
}

// ---------------- split-f16 MFMA GEMM: C = act(A @ Bt^T + bias) -------------
// acc1 = Ah*Bh ; acc2 = Ah*Bl + Al*Bh ; result = acc1 + acc2/2048  (fp32).
// 2-deep counted-vmcnt pipeline (T4): stage(t+1) issued at iter t, waited
// with vmcnt(8) at iter t+1 (one full iteration of latency hiding, never a
// full drain mid-loop). Two barriers/iter separate DMA-writes from readers.
// ACT 1: relu -> f16-split pair (Oh,Ol). ACT 2: relu -> fp32 Of.
template <int ACT>
__global__ __launch_bounds__(256) void gemm_f16x3(
    const ushort* __restrict__ Ah, const ushort* __restrict__ Al,
    const ushort* __restrict__ Bh, const ushort* __restrict__ Bl,
    const float* __restrict__ bias, ushort* __restrict__ Oh,
    ushort* __restrict__ Ol, float* __restrict__ Of, int M, int N, int K) {
  __shared__ ushort AsH[2][128 * 32];
  __shared__ ushort AsL[2][128 * 32];
  __shared__ ushort BsH[2][128 * 32];
  __shared__ ushort BsL[2][128 * 32];
  const int tid = threadIdx.x;
  const int wave = tid >> 6, lane = tid & 63;
  const int nbx = gridDim.x;
  const int bid = xcd_swizzle(blockIdx.y * nbx + blockIdx.x, nbx * gridDim.y);
  const int m0 = (bid / nbx) * 128, n0 = (bid % nbx) * 128;
  const int lrow = lane & 15, lq = lane >> 4;
  const int wm = wave & 1, wn = wave >> 1;
  const int srow = lane >> 2;
  const int scol = (lane & 3) * 8;

  floatx4 acc1[4][4], acc2[4][4];
#pragma unroll
  for (int i = 0; i < 4; i++)
#pragma unroll
    for (int j = 0; j < 4; j++) {
      acc1[i][j] = (floatx4){0.f, 0.f, 0.f, 0.f};
      acc2[i][j] = (floatx4){0.f, 0.f, 0.f, 0.f};
    }

  // 8 gl2lds16 per wave per stage (S=8)
  auto stage = [&](int k0, int pp) {
#pragma unroll
    for (int h = 0; h < 2; h++) {
      int r0 = wave * 32 + h * 16;
      gl2lds16(Ah + (size_t)(m0 + r0 + srow) * K + k0 + scol, &AsH[pp][r0 * 32]);
      gl2lds16(Al + (size_t)(m0 + r0 + srow) * K + k0 + scol, &AsL[pp][r0 * 32]);
      gl2lds16(Bh + (size_t)(n0 + r0 + srow) * K + k0 + scol, &BsH[pp][r0 * 32]);
      gl2lds16(Bl + (size_t)(n0 + r0 + srow) * K + k0 + scol, &BsL[pp][r0 * 32]);
    }
  };

  const int nt = K >> 5;
  stage(0, 0);
  int cur = 0;
  for (int t = 0; t < nt; t++) {
    if (t + 1 < nt) {
      stage((t + 1) << 5, cur ^ 1);
      asm volatile("s_waitcnt vmcnt(8)" ::: "memory");  // stage(t) landed
    } else {
      asm volatile("s_waitcnt vmcnt(0)" ::: "memory");
    }
    __builtin_amdgcn_sched_barrier(0);
    __builtin_amdgcn_s_barrier();   // all waves' stage(t) visible
    __builtin_amdgcn_sched_barrier(0);
    half8 ah[4], al[4];
#pragma unroll
    for (int i = 0; i < 4; i++) {
      ah[i] = *(const half8*)&AsH[cur][(wm * 64 + i * 16 + lrow) * 32 + lq * 8];
      al[i] = *(const half8*)&AsL[cur][(wm * 64 + i * 16 + lrow) * 32 + lq * 8];
    }
#pragma unroll
    for (int j = 0; j < 4; j++) {
      half8 bh = *(const half8*)&BsH[cur][(wn * 64 + j * 16 + lrow) * 32 + lq * 8];
      half8 bl = *(const half8*)&BsL[cur][(wn * 64 + j * 16 + lrow) * 32 + lq * 8];
#pragma unroll
      for (int i = 0; i < 4; i++) {
        acc1[i][j] = __builtin_amdgcn_mfma_f32_16x16x32_f16(ah[i], bh,
                                                            acc1[i][j], 0, 0, 0);
        acc2[i][j] = __builtin_amdgcn_mfma_f32_16x16x32_f16(ah[i], bl,
                                                            acc2[i][j], 0, 0, 0);
        acc2[i][j] = __builtin_amdgcn_mfma_f32_16x16x32_f16(al[i], bh,
                                                            acc2[i][j], 0, 0, 0);
      }
    }
    __builtin_amdgcn_sched_barrier(0);
    __builtin_amdgcn_s_barrier();   // readers of buf[cur] done -> reusable
    __builtin_amdgcn_sched_barrier(0);
    cur ^= 1;
  }

  // C/D layout: col = lane&15, row = (lane>>4)*4 + reg  [measured m89/m91]
  const float INV2048 = 4.8828125e-4f;
#pragma unroll
  for (int i = 0; i < 4; i++) {
#pragma unroll
    for (int j = 0; j < 4; j++) {
      int colg = n0 + wn * 64 + j * 16 + lrow;
      float bb = bias[colg];
#pragma unroll
      for (int r = 0; r < 4; r++) {
        int rowg = m0 + wm * 64 + i * 16 + lq * 4 + r;
        float v = acc1[i][j][r] + acc2[i][j][r] * INV2048 + bb;
        v = fmaxf(v, 0.0f);
        if (ACT == 1) {
          ushort hb, lb;
          split2(v, hb, lb);
          size_t o = (size_t)rowg * N + colg;
          Oh[o] = hb; Ol[o] = lb;
        } else {
          Of[(size_t)rowg * N + colg] = v;
        }
      }
    }
  }
}

// ---------------- fc41+fc42 via split-K MFMA ---------------------------------
// logits[8192,128] = h3(split) @ wcat(split)^T, K=2048 in 8 chunks of 256.
__global__ __launch_bounds__(256) void dual_mfma(
    const ushort* __restrict__ Ah, const ushort* __restrict__ Al,
    const ushort* __restrict__ Bh, const ushort* __restrict__ Bl,
    float* __restrict__ P) {
  __shared__ ushort AsH[128 * 32];
  __shared__ ushort AsL[128 * 32];
  __shared__ ushort BsH[128 * 32];
  __shared__ ushort BsL[128 * 32];
  const int K = 2048;
  const int tid = threadIdx.x;
  const int wave = tid >> 6, lane = tid & 63;
  const int m0 = blockIdx.y * 128;
  const int kbase = blockIdx.x * 256;
  const int lrow = lane & 15, lq = lane >> 4;
  const int wm = wave & 1, wn = wave >> 1;
  const int srow = lane >> 2;
  const int scol = (lane & 3) * 8;

  floatx4 acc1[4][4], acc2[4][4];
#pragma unroll
  for (int i = 0; i < 4; i++)
#pragma unroll
    for (int j = 0; j < 4; j++) {
      acc1[i][j] = (floatx4){0.f, 0.f, 0.f, 0.f};
      acc2[i][j] = (floatx4){0.f, 0.f, 0.f, 0.f};
    }

  for (int kk = 0; kk < 256; kk += 32) {
    int k0 = kbase + kk;
#pragma unroll
    for (int h = 0; h < 2; h++) {
      int r0 = wave * 32 + h * 16;
      gl2lds16(Ah + (size_t)(m0 + r0 + srow) * K + k0 + scol, &AsH[r0 * 32]);
      gl2lds16(Al + (size_t)(m0 + r0 + srow) * K + k0 + scol, &AsL[r0 * 32]);
      gl2lds16(Bh + (size_t)(r0 + srow) * K + k0 + scol, &BsH[r0 * 32]);
      gl2lds16(Bl + (size_t)(r0 + srow) * K + k0 + scol, &BsL[r0 * 32]);
    }
    __syncthreads();
    half8 ah[4], al[4];
#pragma unroll
    for (int i = 0; i < 4; i++) {
      ah[i] = *(const half8*)&AsH[(wm * 64 + i * 16 + lrow) * 32 + lq * 8];
      al[i] = *(const half8*)&AsL[(wm * 64 + i * 16 + lrow) * 32 + lq * 8];
    }
#pragma unroll
    for (int j = 0; j < 4; j++) {
      half8 bh = *(const half8*)&BsH[(wn * 64 + j * 16 + lrow) * 32 + lq * 8];
      half8 bl = *(const half8*)&BsL[(wn * 64 + j * 16 + lrow) * 32 + lq * 8];
#pragma unroll
      for (int i = 0; i < 4; i++) {
        acc1[i][j] = __builtin_amdgcn_mfma_f32_16x16x32_f16(ah[i], bh,
                                                            acc1[i][j], 0, 0, 0);
        acc2[i][j] = __builtin_amdgcn_mfma_f32_16x16x32_f16(ah[i], bl,
                                                            acc2[i][j], 0, 0, 0);
        acc2[i][j] = __builtin_amdgcn_mfma_f32_16x16x32_f16(al[i], bh,
                                                            acc2[i][j], 0, 0, 0);
      }
    }
    __syncthreads();
  }

  const float INV2048 = 4.8828125e-4f;
#pragma unroll
  for (int i = 0; i < 4; i++) {
#pragma unroll
    for (int j = 0; j < 4; j++) {
      int colg = wn * 64 + j * 16 + lrow;
#pragma unroll
      for (int r = 0; r < 4; r++) {
        int rowg = m0 + wm * 64 + i * 16 + lq * 4 + r;
        float v = acc1[i][j][r] + acc2[i][j][r] * INV2048;
        P[((size_t)blockIdx.x * 8192 + rowg) * 128 + colg] = v;
      }
    }
  }
}

// ---------------- reduce 8 split-K partials + bias + softplus ---------------
// Fixed k-order sum -> deterministic. EXACT softplus (feeds accepts).
__global__ __launch_bounds__(256) void dual_reduce(
    const float* __restrict__ P, const float* __restrict__ b41,
    const float* __restrict__ b42, float* __restrict__ la,
    float* __restrict__ lb) {
#pragma clang fp contract(off)
  int idx = blockIdx.x * 256 + threadIdx.x;  // [0, 262144)
  int row = idx >> 5;
  int c4 = (idx & 31) * 4;
  float4 s = {0.f, 0.f, 0.f, 0.f};
#pragma unroll
  for (int k = 0; k < 8; k++) {
    float4 p = *(const float4*)&P[((size_t)k * 8192 + row) * 128 + c4];
    s.x += p.x; s.y += p.y; s.z += p.z; s.w += p.w;
  }
  float o[4];
  const float* bb = (c4 < 64) ? (b41 + c4) : (b42 + c4 - 64);
#pragma unroll
  for (int q = 0; q < 4; q++) {
    float v = (&s.x)[q] + bb[q];
    o[q] = 1e-6f + softplus_ref(v);
  }
  float* dst = (c4 < 64) ? (la + (size_t)row * 64 + c4)
                         : (lb + (size_t)row * 64 + (c4 - 64));
  *(float4*)dst = *(float4*)o;
}

// ---------------- Marsaglia-Tsang sampler, JAX partitionable threefry -------
// JAX's partitionable threefry returns bits1 ^ bits2 for 32-bit draws.
__global__ __launch_bounds__(256) void gamma_sampler(
    const float* __restrict__ la, const float* __restrict__ lb,
    float* __restrict__ z, ushort* __restrict__ zb) {
#pragma clang fp contract(off)
  const uint32_t i = blockIdx.x * 256u + threadIdx.x;
  uint32_t k1a, k1b, k2a, k2b;
  tf2x32(0u, 42u, 0u, 0u, k1a, k1b);  // split: child key = both output words
  tf2x32(0u, 42u, 0u, 1u, k2a, k2b);

  const float LO = __uint_as_float(0xBF7FFFFFu);
  const float SQRT2 = __uint_as_float(0x3FB504F3u);
  const float USCALE = 1.0f - 1e-7f;

  const float al = la[i];
  const float be = lb[i];
  const float d = (al + 1.0f) - 0.33333334f;
  const float c = 1.0f / __fsqrt_rn(9.0f * d);

  float es = 0.0f, us = 0.0f;
  bool done = false;
  for (int k = 0; k < 24; k++) {
    if (__all(done)) break;
    if (!done) {
      uint32_t n = (uint32_t)k * 524288u + i;
      uint32_t o0, o1, p0, p1;
      tf2x32(k1a, k1b, 0u, n, o0, o1);
      tf2x32(k2a, k2b, 0u, n, p0, p1);
      uint32_t eb = o0 ^ o1;  // JAX: bits = bits1 ^ bits2 (32-bit path)
      uint32_t ub = p0 ^ p1;
      float f = __uint_as_float((eb >> 9) | 0x3F800000u) - 1.0f;
      float un = f * 2.0f + LO;
      un = fmaxf(LO, un);
      float e = SQRT2 * erfinv_f32(un);
      float g = __uint_as_float((ub >> 9) | 0x3F800000u) - 1.0f;
      float u = g * USCALE + 1e-7f;
      u = fmaxf(1e-7f, u);
      if (k == 0) { es = e; us = u; }
      float v = 1.0f + c * e;
      if (v > 0.0f) {
        float v3 = (v * v) * v;
        float e2 = e * e;
        bool acc = false;
        float sq = 1.0f - (0.0331f * e2) * e2;
        if (u < sq) acc = true;
        else {
          float rhs = (0.5f * e) * e + d * ((1.0f - v3) + logf(v3));
          if (logf(u) < rhs) acc = true;
        }
        if (acc) { es = e; us = u; done = true; }
      }
    }
  }
  float vv = 1.0f + c * es;
  float vs = (vv * vv) * vv;
  float t = logf(d * vs + 1e-6f) + logf(us + 1e-6f) / (al + 1e-6f);
  float zv = expf(t) / (be + 1e-6f);
  z[i] = zv;
  zb[i] = f2bf(zv);
}

// ---------------- transpose + fp32->bf16: out[c][r] = bf16(in[r][c]) --------
__global__ __launch_bounds__(256) void transpose_bf16(
    const float* __restrict__ in, ushort* __restrict__ out, int R, int C) {
  __shared__ float tile[32][33];
  const int c0 = blockIdx.x * 32, r0 = blockIdx.y * 32;
  const int tx = threadIdx.x & 31, ty = threadIdx.x >> 5;
#pragma unroll
  for (int i = ty; i < 32; i += 8)
    tile[i][tx] = in[(size_t)(r0 + i) * C + c0 + tx];
  __syncthreads();
#pragma unroll
  for (int i = ty; i < 32; i += 8)
    out[(size_t)(c0 + i) * R + r0 + tx] = f2bf(tile[tx][i]);
}

// ---------------- bf16 MFMA GEMM, 3-deep counted-vmcnt pipeline -------------
// LDS ring of 3 tiles (48 KB -> 3 blocks/CU). stage(t) issued 2 iters ahead;
// vmcnt(8) = 2 stages x 4 loads in flight, never a mid-loop drain (T4).
// ACT 0: relu -> bf16 C0b[M,N];  ACT 3: 1e-6+softplus_fast split -> C0f/C1f
template <int ACT>
__global__ __launch_bounds__(256) void gemm_bf16(
    const ushort* __restrict__ A, const ushort* __restrict__ Bt,
    const float* __restrict__ bias, ushort* __restrict__ C0b,
    float* __restrict__ C0f, float* __restrict__ C1f,
    int M, int N, int K, int split) {
  __shared__ ushort As[3][128 * 32];
  __shared__ ushort Bs[3][128 * 32];
  const int tid = threadIdx.x;
  const int wave = tid >> 6, lane = tid & 63;
  const int nbx = gridDim.x;
  const int bid = xcd_swizzle(blockIdx.y * nbx + blockIdx.x, nbx * gridDim.y);
  const int m0 = (bid / nbx) * 128, n0 = (bid % nbx) * 128;
  const int lrow = lane & 15, lq = lane >> 4;
  const int wm = wave & 1, wn = wave >> 1;
  const int srow = lane >> 2;
  const int scol = (lane & 3) * 8;

  floatx4 acc[4][4];
#pragma unroll
  for (int i = 0; i < 4; i++)
#pragma unroll
    for (int j = 0; j < 4; j++) acc[i][j] = (floatx4){0.f, 0.f, 0.f, 0.f};

  // 4 gl2lds16 per wave per stage (S=4)
  auto stage = [&](int k0, int pp) {
#pragma unroll
    for (int h = 0; h < 2; h++) {
      int r0 = wave * 32 + h * 16;
      gl2lds16(A + (size_t)(m0 + r0 + srow) * K + k0 + scol, &As[pp][r0 * 32]);
      gl2lds16(Bt + (size_t)(n0 + r0 + srow) * K + k0 + scol, &Bs[pp][r0 * 32]);
    }
  };

  const int nt = K >> 5;  // >= 2 for all layers (K >= 64)
  stage(0, 0);
  stage(32, 1);
  int cur = 0;
  for (int t = 0; t < nt; t++) {
    if (t + 2 < nt) {
      int nb = cur + 2; if (nb >= 3) nb -= 3;
      stage((t + 2) << 5, nb);
      asm volatile("s_waitcnt vmcnt(8)" ::: "memory");  // stage(t) landed
    } else if (t + 1 < nt) {
      asm volatile("s_waitcnt vmcnt(4)" ::: "memory");
    } else {
      asm volatile("s_waitcnt vmcnt(0)" ::: "memory");
    }
    __builtin_amdgcn_sched_barrier(0);
    __builtin_amdgcn_s_barrier();   // all waves' stage(t) visible
    __builtin_amdgcn_sched_barrier(0);
    short8 a[4], b[4];
#pragma unroll
    for (int i = 0; i < 4; i++) {
      a[i] = *(const short8*)&As[cur][(wm * 64 + i * 16 + lrow) * 32 + lq * 8];
      b[i] = *(const short8*)&Bs[cur][(wn * 64 + i * 16 + lrow) * 32 + lq * 8];
    }
#pragma unroll
    for (int i = 0; i < 4; i++)
#pragma unroll
      for (int j = 0; j < 4; j++)
        acc[i][j] = __builtin_amdgcn_mfma_f32_16x16x32_bf16(a[i], b[j],
                                                            acc[i][j], 0, 0, 0);
    __builtin_amdgcn_sched_barrier(0);
    __builtin_amdgcn_s_barrier();   // readers of buf[cur] done -> reusable
    __builtin_amdgcn_sched_barrier(0);
    cur = cur + 1; if (cur == 3) cur = 0;
  }

#pragma unroll
  for (int i = 0; i < 4; i++) {
#pragma unroll
    for (int j = 0; j < 4; j++) {
      int colg = n0 + wn * 64 + j * 16 + lrow;
      float bb = bias[colg];
#pragma unroll
      for (int r = 0; r < 4; r++) {
        int rowg = m0 + wm * 64 + i * 16 + lq * 4 + r;
        float v = acc[i][j][r] + bb;
        if (ACT == 0) {
          v = fmaxf(v, 0.0f);
          C0b[(size_t)rowg * N + colg] = f2bf(v);
        } else {
          v = 1e-6f + softplus_fast(v);
          if (colg < split) C0f[(size_t)rowg * split + colg] = v;
          else              C1f[(size_t)rowg * split + (colg - split)] = v;
        }
      }
    }
  }
}

// ---------------------------------------------------------------------------
extern "C" void kernel_launch(void* const* d_in, const int* in_sizes, int n_in,
                              void* d_out, int out_size, void* d_ws,
                              size_t ws_size, hipStream_t stream) {
  const float* x   = (const float*)d_in[0];
  const float* w1  = (const float*)d_in[1];  const float* b1  = (const float*)d_in[2];
  const float* w2  = (const float*)d_in[3];  const float* b2  = (const float*)d_in[4];
  const float* w3  = (const float*)d_in[5];  const float* b3  = (const float*)d_in[6];
  const float* w41 = (const float*)d_in[7];  const float* b41 = (const float*)d_in[8];
  const float* w42 = (const float*)d_in[9];  const float* b42 = (const float*)d_in[10];
  const float* w4  = (const float*)d_in[11]; const float* b4  = (const float*)d_in[12];
  const float* w5  = (const float*)d_in[13]; const float* b5  = (const float*)d_in[14];
  const float* w6  = (const float*)d_in[15]; const float* b6  = (const float*)d_in[16];
  const float* w7  = (const float*)d_in[17]; const float* b7  = (const float*)d_in[18];
  float* out = (float*)d_out;
  float* ws  = (float*)d_ws;
  ushort* wsu = (ushort*)d_ws;

  // output layout (floats): recon_al | recon_be | logalpha | logbeta | z
  float* recon_a = out;
  float* recon_b = out + 16777216;
  float* la      = out + 33554432;
  float* lb      = out + 34078720;
  float* zz      = out + 34603008;

  // ---- workspace layout (ushort offsets unless noted); peak 124 MB.
  ushort* xh   = wsu;              // [0, 16777216)            dead after fc1
  ushort* xl   = wsu + 16777216;   // [16777216, 33554432)     dead after fc1
  ushort* w1Th = wsu + 33554432;   // [.., 35651584)           dead after fc1
  ushort* w1Tl = wsu + 35651584;   // [.., 37748736)
  ushort* w2Th = wsu + 37748736;   // [.., 38797312)           dead after fc2
  ushort* w2Tl = wsu + 38797312;   // [.., 39845888)
  ushort* h1h  = wsu + 39845888;   // [.., 48234496)           dead after fc2
  ushort* h1l  = wsu + 48234496;   // [.., 56623104)
  ushort* w3Th = wsu + 16777216;   // overwrites xl AFTER fc1  dead after fc3
  ushort* w3Tl = wsu + 18874368;   // [.., 20971520)
  ushort* h2h  = wsu;              // overwrites xh AFTER fc1  dead after fc3
  ushort* h2l  = wsu + 8388608;    // [.., 16777216)
  // fc3 output: split pair (over dead w1T/w2T/h1); dead after dual_mfma
  ushort* h3h  = wsu + 20971520;   // [20971520, 37748736)
  ushort* h3l  = wsu + 37748736;   // [37748736, 54525952)
  // fc41|fc42 concat weights, transposed+split [128, 2048] over dead w3T
  ushort* wcatTh = wsu + 16777216; // [16777216, 17039360)
  ushort* wcatTl = wsu + 17039360; // [17039360, 17301504)
  // split-K partials [8][8192][128] fp32 = 33.5 MB over dead x/h2 region
  float*  Ppart = ws;              // float [0, 8388608) = ushort [0,16777216)
  // decoder (bf16), after h3 region — over dead h1l tail:
  ushort* w4T = wsu + 54525952;    // [64,2048]   -> 54657024
  ushort* w5T = wsu + 54657024;    // [1024,2048] -> 56754176
  ushort* w6T = wsu + 56754176;    // [1024,1024] -> 57802752
  ushort* w7T = wsu + 57802752;    // [4096,1024] -> 61997056
  ushort* zb  = wsu;               // [0, 524288)       (Ppart dead by sampler)
  ushort* h4b = wsu + 20971520;    // [.., 37748736)    (over dead h3h)
  ushort* h5b = wsu + 524288;      // [.., 8912896)     (over dead Ppart)
  ushort* h6b = wsu + 8912896;     // [.., 17301504)    (over dead Ppart/wcat)

  dim3 blk(256);
  // ---- prep: split x and encoder weights into f16 (hi, lo*2^11) pairs
  split_f16<<<dim3(2048), blk, 0, stream>>>(x, xh, xl, 4194304);
  transpose_split_f16<<<dim3(32, 64), blk, 0, stream>>>(w1, w1Th, w1Tl, 2048, 1024);
  transpose_split_f16<<<dim3(32, 32), blk, 0, stream>>>(w2, w2Th, w2Tl, 1024, 1024);
  // ---- encoder: split-f16 MFMA (error ~1e-6 rel)
  gemm_f16x3<1><<<dim3(8, 64), blk, 0, stream>>>(xh, xl, w1Th, w1Tl, b1,
                                                 h1h, h1l, nullptr, 8192, 1024, 2048);
  transpose_split_f16<<<dim3(64, 32), blk, 0, stream>>>(w3, w3Th, w3Tl, 1024, 2048);
  gemm_f16x3<1><<<dim3(8, 64), blk, 0, stream>>>(h1h, h1l, w2Th, w2Tl, b2,
                                                 h2h, h2l, nullptr, 8192, 1024, 1024);
  // decoder weight prep (regions free only after fc2 reads h1l)
  transpose_bf16<<<dim3(64, 2),   blk, 0, stream>>>(w4, w4T, 64,   2048);
  transpose_bf16<<<dim3(32, 64),  blk, 0, stream>>>(w5, w5T, 2048, 1024);
  transpose_bf16<<<dim3(32, 32),  blk, 0, stream>>>(w6, w6T, 1024, 1024);
  transpose_bf16<<<dim3(128, 32), blk, 0, stream>>>(w7, w7T, 1024, 4096);
  // fc3 -> split pair (feeds MFMA fc41/42)
  gemm_f16x3<1><<<dim3(16, 64), blk, 0, stream>>>(h2h, h2l, w3Th, w3Tl, b3,
                                                  h3h, h3l, nullptr, 8192, 2048, 1024);
  // fc41/42: split-K MFMA + deterministic reduce
  transpose_split_f16<<<dim3(2, 64), blk, 0, stream>>>(w41, wcatTh, wcatTl, 2048, 64);
  transpose_split_f16<<<dim3(2, 64), blk, 0, stream>>>(w42, wcatTh + 64 * 2048,
                                                       wcatTl + 64 * 2048, 2048, 64);
  dual_mfma<<<dim3(8, 64), blk, 0, stream>>>(h3h, h3l, wcatTh, wcatTl, Ppart);
  dual_reduce<<<dim3(1024), blk, 0, stream>>>(Ppart, b41, b42, la, lb);
  // reparameterize (exact fp32; also emits bf16 z)
  gamma_sampler<<<dim3(2048), blk, 0, stream>>>(la, lb, zz, zb);
  // decoder (bf16 MFMA)
  gemm_bf16<0><<<dim3(16, 64), blk, 0, stream>>>(zb,  w4T, b4, h4b, nullptr, nullptr, 8192, 2048, 64, 0);
  gemm_bf16<0><<<dim3(8, 64),  blk, 0, stream>>>(h4b, w5T, b5, h5b, nullptr, nullptr, 8192, 1024, 2048, 0);
  gemm_bf16<0><<<dim3(8, 64),  blk, 0, stream>>>(h5b, w6T, b6, h6b, nullptr, nullptr, 8192, 1024, 1024, 0);
  gemm_bf16<3><<<dim3(32, 64), blk, 0, stream>>>(h6b, w7T, b7, nullptr, recon_a, recon_b, 8192, 4096, 1024, 2048);
  (void)in_sizes; (void)n_in; (void)out_size; (void)ws_size;
}

// Round 7
// 915.963 us; speedup vs baseline: 1.9112x; 1.0022x over previous
//
#include <hip/hip_runtime.h>
#include <stdint.h>

#define DEVFN static __device__ __forceinline__

typedef __attribute__((ext_vector_type(8))) short short8;
typedef __attribute__((ext_vector_type(4))) float floatx4;
typedef _Float16 half8 __attribute__((ext_vector_type(8)));

// ---------------- Threefry-2x32 (20 rounds), exactly as JAX ----------------
DEVFN uint32_t rotl32(uint32_t v, int d) { return (v << d) | (v >> (32 - d)); }

DEVFN void tf2x32(uint32_t k0, uint32_t k1, uint32_t x0, uint32_t x1,
                  uint32_t& o0, uint32_t& o1) {
  uint32_t k2 = k0 ^ k1 ^ 0x1BD11BDAu;
  x0 += k0; x1 += k1;
  x0 += x1; x1 = rotl32(x1, 13); x1 ^= x0;
  x0 += x1; x1 = rotl32(x1, 15); x1 ^= x0;
  x0 += x1; x1 = rotl32(x1, 26); x1 ^= x0;
  x0 += x1; x1 = rotl32(x1, 6);  x1 ^= x0;
  x0 += k1; x1 += k2 + 1u;
  x0 += x1; x1 = rotl32(x1, 17); x1 ^= x0;
  x0 += x1; x1 = rotl32(x1, 29); x1 ^= x0;
  x0 += x1; x1 = rotl32(x1, 16); x1 ^= x0;
  x0 += x1; x1 = rotl32(x1, 24); x1 ^= x0;
  x0 += k2; x1 += k0 + 2u;
  x0 += x1; x1 = rotl32(x1, 13); x1 ^= x0;
  x0 += x1; x1 = rotl32(x1, 15); x1 ^= x0;
  x0 += x1; x1 = rotl32(x1, 26); x1 ^= x0;
  x0 += x1; x1 = rotl32(x1, 6);  x1 ^= x0;
  x0 += k0; x1 += k1 + 3u;
  x0 += x1; x1 = rotl32(x1, 17); x1 ^= x0;
  x0 += x1; x1 = rotl32(x1, 29); x1 ^= x0;
  x0 += x1; x1 = rotl32(x1, 16); x1 ^= x0;
  x0 += x1; x1 = rotl32(x1, 24); x1 ^= x0;
  x0 += k1; x1 += k2 + 4u;
  x0 += x1; x1 = rotl32(x1, 13); x1 ^= x0;
  x0 += x1; x1 = rotl32(x1, 15); x1 ^= x0;
  x0 += x1; x1 = rotl32(x1, 26); x1 ^= x0;
  x0 += x1; x1 = rotl32(x1, 6);  x1 ^= x0;
  x0 += k2; x1 += k0 + 5u;
  o0 = x0; o1 = x1;
}

// ---------------- XLA/CHLO f32 erf_inv (Giles), w = -log1p(-x^2) -----------
DEVFN float erfinv_f32(float x) {
#pragma clang fp contract(off)
  float w = -log1pf(-(x * x));
  float p;
  if (w < 5.0f) {
    w = w - 2.5f;
    p = 2.81022636e-08f;
    p = 3.43273939e-07f + p * w;
    p = -3.5233877e-06f + p * w;
    p = -4.39150654e-06f + p * w;
    p = 0.00021858087f + p * w;
    p = -0.00125372503f + p * w;
    p = -0.00417768164f + p * w;
    p = 0.246640727f + p * w;
    p = 1.50140941f + p * w;
  } else {
    w = __fsqrt_rn(w) - 3.0f;
    p = -0.000200214257f;
    p = 0.000100950558f + p * w;
    p = 0.00134934322f + p * w;
    p = -0.00367342844f + p * w;
    p = 0.00573950773f + p * w;
    p = -0.0076224613f + p * w;
    p = 0.00943887047f + p * w;
    p = 1.00167406f + p * w;
    p = 2.83297682f + p * w;
  }
  return p * x;
}

// jax.nn.softplus(x) = logaddexp(x,0) = max(x,0) + log1p(exp(-|x|))
// EXACT version (feeds discrete accept/reject via logalpha)
DEVFN float softplus_ref(float v) {
#pragma clang fp contract(off)
  return fmaxf(v, 0.0f) + log1pf(expf(-fabsf(v)));
}

// FAST version for recon outputs only (abs err ~1e-6 << 0.23 threshold)
DEVFN float softplus_fast(float v) {
  float e = __expf(-fabsf(v));
  return fmaxf(v, 0.0f) + __logf(1.0f + e);
}

// fp32 -> bf16 RNE
DEVFN ushort f2bf(float f) {
  uint32_t u = __float_as_uint(f);
  uint32_t r = (u + 0x7FFFu + ((u >> 16) & 1u)) >> 16;
  return (ushort)r;
}

// fp32 -> (f16 hi, f16 lo*2048) split. a = hi + lo/2048 + O(2^-23 |a|).
DEVFN void split2(float a, ushort& hb, ushort& lb) {
  _Float16 h = (_Float16)a;
  float r = (a - (float)h) * 2048.0f;  // a-hf exact (Sterbenz); *2^11 exact
  _Float16 l = (_Float16)r;
  hb = __builtin_bit_cast(unsigned short, h);
  lb = __builtin_bit_cast(unsigned short, l);
}

// async global->LDS, 16 B per lane; lds must be wave-uniform base
DEVFN void gl2lds16(const void* g, void* l) {
  __builtin_amdgcn_global_load_lds(
      (const __attribute__((address_space(1))) void*)g,
      (__attribute__((address_space(3))) void*)l, 16, 0, 0);
}

// XCD-chunked blockIdx swizzle (T1/m204): bijective when nwg % 8 == 0.
DEVFN int xcd_swizzle(int bid, int nwg) {
  if ((nwg & 7) == 0) return (bid & 7) * (nwg >> 3) + (bid >> 3);
  return bid;
}

// ---------------- elementwise split: x -> (xh, xl) f16 pairs ----------------
__global__ __launch_bounds__(256) void split_f16(
    const float* __restrict__ in, ushort* __restrict__ oh,
    ushort* __restrict__ ol, int n4) {
  int idx = blockIdx.x * 256 + threadIdx.x;
  int stride = gridDim.x * 256;
  for (int i = idx; i < n4; i += stride) {
    float4 a = ((const float4*)in)[i];
    ushort h0, h1, h2, h3, l0, l1, l2, l3;
    split2(a.x, h0, l0); split2(a.y, h1, l1);
    split2(a.z, h2, l2); split2(a.w, h3, l3);
    ushort4 hv; hv.x = h0; hv.y = h1; hv.z = h2; hv.w = h3;
    ushort4 lv; lv.x = l0; lv.y = l1; lv.z = l2; lv.w = l3;
    ((ushort4*)oh)[i] = hv;
    ((ushort4*)ol)[i] = lv;
  }
}

// ---------------- transpose + f16-split: out*[c][r] = split(in[r][c]) -------
__global__ __launch_bounds__(256) void transpose_split_f16(
    const float* __restrict__ in, ushort* __restrict__ oh,
    ushort* __restrict__ ol, int R, int C) {
  __shared__ float tile[32][33];
  const int c0 = blockIdx.x * 32, r0 = blockIdx.y * 32;
  const int tx = threadIdx.x & 31, ty = threadIdx.x >> 5;
#pragma unroll
  for (int i = ty; i < 32; i += 8)
    tile[i][tx] = in[(size_t)(r0 + i) * C + c0 + tx];
  __syncthreads();
#pragma unroll
  for (int i = ty; i < 32; i += 8) {
    ushort hb, lb;
    split2(tile[tx][i], hb, lb);
    size_t o = (size_t)(c0 + i) * R + r0 + tx;
    oh[o] = hb; ol[o] = lb;
  }
}

// ---------------- split-f16 MFMA GEMM: C = act(A @ Bt^T + bias) -------------
// acc1 = Ah*Bh ; acc2 = Ah*Bl + Al*Bh ; result = acc1 + acc2/2048  (fp32).
// 2-deep counted-vmcnt pipeline. ACT 1: relu -> split pair. ACT 2: fp32.
template <int ACT>
__global__ __launch_bounds__(256) void gemm_f16x3(
    const ushort* __restrict__ Ah, const ushort* __restrict__ Al,
    const ushort* __restrict__ Bh, const ushort* __restrict__ Bl,
    const float* __restrict__ bias, ushort* __restrict__ Oh,
    ushort* __restrict__ Ol, float* __restrict__ Of, int M, int N, int K) {
  __shared__ ushort AsH[2][128 * 32];
  __shared__ ushort AsL[2][128 * 32];
  __shared__ ushort BsH[2][128 * 32];
  __shared__ ushort BsL[2][128 * 32];
  const int tid = threadIdx.x;
  const int wave = tid >> 6, lane = tid & 63;
  const int nbx = gridDim.x;
  const int bid = xcd_swizzle(blockIdx.y * nbx + blockIdx.x, nbx * gridDim.y);
  const int m0 = (bid / nbx) * 128, n0 = (bid % nbx) * 128;
  const int lrow = lane & 15, lq = lane >> 4;
  const int wm = wave & 1, wn = wave >> 1;
  const int srow = lane >> 2;
  const int scol = (lane & 3) * 8;

  floatx4 acc1[4][4], acc2[4][4];
#pragma unroll
  for (int i = 0; i < 4; i++)
#pragma unroll
    for (int j = 0; j < 4; j++) {
      acc1[i][j] = (floatx4){0.f, 0.f, 0.f, 0.f};
      acc2[i][j] = (floatx4){0.f, 0.f, 0.f, 0.f};
    }

  // 8 gl2lds16 per wave per stage (S=8)
  auto stage = [&](int k0, int pp) {
#pragma unroll
    for (int h = 0; h < 2; h++) {
      int r0 = wave * 32 + h * 16;
      gl2lds16(Ah + (size_t)(m0 + r0 + srow) * K + k0 + scol, &AsH[pp][r0 * 32]);
      gl2lds16(Al + (size_t)(m0 + r0 + srow) * K + k0 + scol, &AsL[pp][r0 * 32]);
      gl2lds16(Bh + (size_t)(n0 + r0 + srow) * K + k0 + scol, &BsH[pp][r0 * 32]);
      gl2lds16(Bl + (size_t)(n0 + r0 + srow) * K + k0 + scol, &BsL[pp][r0 * 32]);
    }
  };

  const int nt = K >> 5;
  stage(0, 0);
  int cur = 0;
  for (int t = 0; t < nt; t++) {
    if (t + 1 < nt) {
      stage((t + 1) << 5, cur ^ 1);
      asm volatile("s_waitcnt vmcnt(8)" ::: "memory");  // stage(t) landed
    } else {
      asm volatile("s_waitcnt vmcnt(0)" ::: "memory");
    }
    __builtin_amdgcn_sched_barrier(0);
    __builtin_amdgcn_s_barrier();   // all waves' stage(t) visible
    __builtin_amdgcn_sched_barrier(0);
    half8 ah[4], al[4];
#pragma unroll
    for (int i = 0; i < 4; i++) {
      ah[i] = *(const half8*)&AsH[cur][(wm * 64 + i * 16 + lrow) * 32 + lq * 8];
      al[i] = *(const half8*)&AsL[cur][(wm * 64 + i * 16 + lrow) * 32 + lq * 8];
    }
#pragma unroll
    for (int j = 0; j < 4; j++) {
      half8 bh = *(const half8*)&BsH[cur][(wn * 64 + j * 16 + lrow) * 32 + lq * 8];
      half8 bl = *(const half8*)&BsL[cur][(wn * 64 + j * 16 + lrow) * 32 + lq * 8];
#pragma unroll
      for (int i = 0; i < 4; i++) {
        acc1[i][j] = __builtin_amdgcn_mfma_f32_16x16x32_f16(ah[i], bh,
                                                            acc1[i][j], 0, 0, 0);
        acc2[i][j] = __builtin_amdgcn_mfma_f32_16x16x32_f16(ah[i], bl,
                                                            acc2[i][j], 0, 0, 0);
        acc2[i][j] = __builtin_amdgcn_mfma_f32_16x16x32_f16(al[i], bh,
                                                            acc2[i][j], 0, 0, 0);
      }
    }
    __builtin_amdgcn_sched_barrier(0);
    __builtin_amdgcn_s_barrier();   // readers of buf[cur] done -> reusable
    __builtin_amdgcn_sched_barrier(0);
    cur ^= 1;
  }

  // C/D layout: col = lane&15, row = (lane>>4)*4 + reg  [measured m89/m91]
  const float INV2048 = 4.8828125e-4f;
#pragma unroll
  for (int i = 0; i < 4; i++) {
#pragma unroll
    for (int j = 0; j < 4; j++) {
      int colg = n0 + wn * 64 + j * 16 + lrow;
      float bb = bias[colg];
#pragma unroll
      for (int r = 0; r < 4; r++) {
        int rowg = m0 + wm * 64 + i * 16 + lq * 4 + r;
        float v = acc1[i][j][r] + acc2[i][j][r] * INV2048 + bb;
        v = fmaxf(v, 0.0f);
        if (ACT == 1) {
          ushort hb, lb;
          split2(v, hb, lb);
          size_t o = (size_t)rowg * N + colg;
          Oh[o] = hb; Ol[o] = lb;
        } else {
          Of[(size_t)rowg * N + colg] = v;
        }
      }
    }
  }
}

// ---------------- fc41+fc42 via split-K MFMA ---------------------------------
// logits[8192,128] = h3(split) @ wcat(split)^T, K=2048 in 8 chunks of 256.
__global__ __launch_bounds__(256) void dual_mfma(
    const ushort* __restrict__ Ah, const ushort* __restrict__ Al,
    const ushort* __restrict__ Bh, const ushort* __restrict__ Bl,
    float* __restrict__ P) {
  __shared__ ushort AsH[128 * 32];
  __shared__ ushort AsL[128 * 32];
  __shared__ ushort BsH[128 * 32];
  __shared__ ushort BsL[128 * 32];
  const int K = 2048;
  const int tid = threadIdx.x;
  const int wave = tid >> 6, lane = tid & 63;
  const int m0 = blockIdx.y * 128;
  const int kbase = blockIdx.x * 256;
  const int lrow = lane & 15, lq = lane >> 4;
  const int wm = wave & 1, wn = wave >> 1;
  const int srow = lane >> 2;
  const int scol = (lane & 3) * 8;

  floatx4 acc1[4][4], acc2[4][4];
#pragma unroll
  for (int i = 0; i < 4; i++)
#pragma unroll
    for (int j = 0; j < 4; j++) {
      acc1[i][j] = (floatx4){0.f, 0.f, 0.f, 0.f};
      acc2[i][j] = (floatx4){0.f, 0.f, 0.f, 0.f};
    }

  for (int kk = 0; kk < 256; kk += 32) {
    int k0 = kbase + kk;
#pragma unroll
    for (int h = 0; h < 2; h++) {
      int r0 = wave * 32 + h * 16;
      gl2lds16(Ah + (size_t)(m0 + r0 + srow) * K + k0 + scol, &AsH[r0 * 32]);
      gl2lds16(Al + (size_t)(m0 + r0 + srow) * K + k0 + scol, &AsL[r0 * 32]);
      gl2lds16(Bh + (size_t)(r0 + srow) * K + k0 + scol, &BsH[r0 * 32]);
      gl2lds16(Bl + (size_t)(r0 + srow) * K + k0 + scol, &BsL[r0 * 32]);
    }
    __syncthreads();
    half8 ah[4], al[4];
#pragma unroll
    for (int i = 0; i < 4; i++) {
      ah[i] = *(const half8*)&AsH[(wm * 64 + i * 16 + lrow) * 32 + lq * 8];
      al[i] = *(const half8*)&AsL[(wm * 64 + i * 16 + lrow) * 32 + lq * 8];
    }
#pragma unroll
    for (int j = 0; j < 4; j++) {
      half8 bh = *(const half8*)&BsH[(wn * 64 + j * 16 + lrow) * 32 + lq * 8];
      half8 bl = *(const half8*)&BsL[(wn * 64 + j * 16 + lrow) * 32 + lq * 8];
#pragma unroll
      for (int i = 0; i < 4; i++) {
        acc1[i][j] = __builtin_amdgcn_mfma_f32_16x16x32_f16(ah[i], bh,
                                                            acc1[i][j], 0, 0, 0);
        acc2[i][j] = __builtin_amdgcn_mfma_f32_16x16x32_f16(ah[i], bl,
                                                            acc2[i][j], 0, 0, 0);
        acc2[i][j] = __builtin_amdgcn_mfma_f32_16x16x32_f16(al[i], bh,
                                                            acc2[i][j], 0, 0, 0);
      }
    }
    __syncthreads();
  }

  const float INV2048 = 4.8828125e-4f;
#pragma unroll
  for (int i = 0; i < 4; i++) {
#pragma unroll
    for (int j = 0; j < 4; j++) {
      int colg = wn * 64 + j * 16 + lrow;
#pragma unroll
      for (int r = 0; r < 4; r++) {
        int rowg = m0 + wm * 64 + i * 16 + lq * 4 + r;
        float v = acc1[i][j][r] + acc2[i][j][r] * INV2048;
        P[((size_t)blockIdx.x * 8192 + rowg) * 128 + colg] = v;
      }
    }
  }
}

// ---------------- Marsaglia-Tsang sampler + fused split-K reduce ------------
// Reduces 8 partials (fixed k-order, bit-identical to old dual_reduce),
// applies EXACT softplus, writes la/lb, then samples. JAX partitionable
// threefry (bits = bits1 ^ bits2 for 32-bit draws).
__global__ __launch_bounds__(256) void gamma_sampler(
    const float* __restrict__ P, const float* __restrict__ b41,
    const float* __restrict__ b42, float* __restrict__ la,
    float* __restrict__ lb, float* __restrict__ z, ushort* __restrict__ zb) {
#pragma clang fp contract(off)
  const uint32_t i = blockIdx.x * 256u + threadIdx.x;
  const int row = i >> 6, col = i & 63;
  float sa = 0.0f, sb = 0.0f;
#pragma unroll
  for (int k = 0; k < 8; k++) {
    sa += P[((size_t)k * 8192 + row) * 128 + col];
    sb += P[((size_t)k * 8192 + row) * 128 + 64 + col];
  }
  const float al = 1e-6f + softplus_ref(sa + b41[col]);
  const float be = 1e-6f + softplus_ref(sb + b42[col]);
  la[i] = al;
  lb[i] = be;

  uint32_t k1a, k1b, k2a, k2b;
  tf2x32(0u, 42u, 0u, 0u, k1a, k1b);  // split: child key = both output words
  tf2x32(0u, 42u, 0u, 1u, k2a, k2b);

  const float LO = __uint_as_float(0xBF7FFFFFu);
  const float SQRT2 = __uint_as_float(0x3FB504F3u);
  const float USCALE = 1.0f - 1e-7f;

  const float d = (al + 1.0f) - 0.33333334f;
  const float c = 1.0f / __fsqrt_rn(9.0f * d);

  float es = 0.0f, us = 0.0f;
  bool done = false;
  for (int k = 0; k < 24; k++) {
    if (__all(done)) break;
    if (!done) {
      uint32_t n = (uint32_t)k * 524288u + i;
      uint32_t o0, o1, p0, p1;
      tf2x32(k1a, k1b, 0u, n, o0, o1);
      tf2x32(k2a, k2b, 0u, n, p0, p1);
      uint32_t eb = o0 ^ o1;  // JAX: bits = bits1 ^ bits2 (32-bit path)
      uint32_t ub = p0 ^ p1;
      float f = __uint_as_float((eb >> 9) | 0x3F800000u) - 1.0f;
      float un = f * 2.0f + LO;
      un = fmaxf(LO, un);
      float e = SQRT2 * erfinv_f32(un);
      float g = __uint_as_float((ub >> 9) | 0x3F800000u) - 1.0f;
      float u = g * USCALE + 1e-7f;
      u = fmaxf(1e-7f, u);
      if (k == 0) { es = e; us = u; }
      float v = 1.0f + c * e;
      if (v > 0.0f) {
        float v3 = (v * v) * v;
        float e2 = e * e;
        bool acc = false;
        float sq = 1.0f - (0.0331f * e2) * e2;
        if (u < sq) acc = true;
        else {
          float rhs = (0.5f * e) * e + d * ((1.0f - v3) + logf(v3));
          if (logf(u) < rhs) acc = true;
        }
        if (acc) { es = e; us = u; done = true; }
      }
    }
  }
  float vv = 1.0f + c * es;
  float vs = (vv * vv) * vv;
  float t = logf(d * vs + 1e-6f) + logf(us + 1e-6f) / (al + 1e-6f);
  float zv = expf(t) / (be + 1e-6f);
  z[i] = zv;
  zb[i] = f2bf(zv);
}

// ---------------- transpose + fp32->bf16: out[c][r] = bf16(in[r][c]) --------
__global__ __launch_bounds__(256) void transpose_bf16(
    const float* __restrict__ in, ushort* __restrict__ out, int R, int C) {
  __shared__ float tile[32][33];
  const int c0 = blockIdx.x * 32, r0 = blockIdx.y * 32;
  const int tx = threadIdx.x & 31, ty = threadIdx.x >> 5;
#pragma unroll
  for (int i = ty; i < 32; i += 8)
    tile[i][tx] = in[(size_t)(r0 + i) * C + c0 + tx];
  __syncthreads();
#pragma unroll
  for (int i = ty; i < 32; i += 8)
    out[(size_t)(c0 + i) * R + r0 + tx] = f2bf(tile[tx][i]);
}

// ---------------- bf16 MFMA GEMM, 3-deep counted-vmcnt pipeline (128²) ------
template <int ACT>
__global__ __launch_bounds__(256) void gemm_bf16(
    const ushort* __restrict__ A, const ushort* __restrict__ Bt,
    const float* __restrict__ bias, ushort* __restrict__ C0b,
    float* __restrict__ C0f, float* __restrict__ C1f,
    int M, int N, int K, int split) {
  __shared__ ushort As[3][128 * 32];
  __shared__ ushort Bs[3][128 * 32];
  const int tid = threadIdx.x;
  const int wave = tid >> 6, lane = tid & 63;
  const int nbx = gridDim.x;
  const int bid = xcd_swizzle(blockIdx.y * nbx + blockIdx.x, nbx * gridDim.y);
  const int m0 = (bid / nbx) * 128, n0 = (bid % nbx) * 128;
  const int lrow = lane & 15, lq = lane >> 4;
  const int wm = wave & 1, wn = wave >> 1;
  const int srow = lane >> 2;
  const int scol = (lane & 3) * 8;

  floatx4 acc[4][4];
#pragma unroll
  for (int i = 0; i < 4; i++)
#pragma unroll
    for (int j = 0; j < 4; j++) acc[i][j] = (floatx4){0.f, 0.f, 0.f, 0.f};

  auto stage = [&](int k0, int pp) {
#pragma unroll
    for (int h = 0; h < 2; h++) {
      int r0 = wave * 32 + h * 16;
      gl2lds16(A + (size_t)(m0 + r0 + srow) * K + k0 + scol, &As[pp][r0 * 32]);
      gl2lds16(Bt + (size_t)(n0 + r0 + srow) * K + k0 + scol, &Bs[pp][r0 * 32]);
    }
  };

  const int nt = K >> 5;  // >= 2 for all layers (K >= 64)
  stage(0, 0);
  stage(32, 1);
  int cur = 0;
  for (int t = 0; t < nt; t++) {
    if (t + 2 < nt) {
      int nb = cur + 2; if (nb >= 3) nb -= 3;
      stage((t + 2) << 5, nb);
      asm volatile("s_waitcnt vmcnt(8)" ::: "memory");  // stage(t) landed
    } else if (t + 1 < nt) {
      asm volatile("s_waitcnt vmcnt(4)" ::: "memory");
    } else {
      asm volatile("s_waitcnt vmcnt(0)" ::: "memory");
    }
    __builtin_amdgcn_sched_barrier(0);
    __builtin_amdgcn_s_barrier();   // all waves' stage(t) visible
    __builtin_amdgcn_sched_barrier(0);
    short8 a[4], b[4];
#pragma unroll
    for (int i = 0; i < 4; i++) {
      a[i] = *(const short8*)&As[cur][(wm * 64 + i * 16 + lrow) * 32 + lq * 8];
      b[i] = *(const short8*)&Bs[cur][(wn * 64 + i * 16 + lrow) * 32 + lq * 8];
    }
#pragma unroll
    for (int i = 0; i < 4; i++)
#pragma unroll
      for (int j = 0; j < 4; j++)
        acc[i][j] = __builtin_amdgcn_mfma_f32_16x16x32_bf16(a[i], b[j],
                                                            acc[i][j], 0, 0, 0);
    __builtin_amdgcn_sched_barrier(0);
    __builtin_amdgcn_s_barrier();   // readers of buf[cur] done -> reusable
    __builtin_amdgcn_sched_barrier(0);
    cur = cur + 1; if (cur == 3) cur = 0;
  }

#pragma unroll
  for (int i = 0; i < 4; i++) {
#pragma unroll
    for (int j = 0; j < 4; j++) {
      int colg = n0 + wn * 64 + j * 16 + lrow;
      float bb = bias[colg];
#pragma unroll
      for (int r = 0; r < 4; r++) {
        int rowg = m0 + wm * 64 + i * 16 + lq * 4 + r;
        float v = acc[i][j][r] + bb;
        if (ACT == 0) {
          v = fmaxf(v, 0.0f);
          C0b[(size_t)rowg * N + colg] = f2bf(v);
        } else {
          v = 1e-6f + softplus_fast(v);
          if (colg < split) C0f[(size_t)rowg * split + colg] = v;
          else              C1f[(size_t)rowg * split + (colg - split)] = v;
        }
      }
    }
  }
}

// ---------------- bf16 MFMA GEMM, 256x256 tile, 8 waves, 2-deep pipeline ----
// Per-wave output 128x64 -> 32 MFMA per barrier-pair (2x the 128² kernel) at
// identical per-wave staging (4 gl2lds16) -> halves barrier cost per MFMA
// (mechanism verified by learn_hip m230/m248: 256²-2ph = 655-682 TF).
// Requires grid % 8 == 0 and N % 256 == 0. Used for fc7 (512 blocks = 2/CU).
template <int ACT>
__global__ __launch_bounds__(512) void gemm_bf16_256(
    const ushort* __restrict__ A, const ushort* __restrict__ Bt,
    const float* __restrict__ bias, ushort* __restrict__ C0b,
    float* __restrict__ C0f, float* __restrict__ C1f,
    int M, int N, int K, int split) {
  __shared__ ushort As[2][256 * 32];
  __shared__ ushort Bs[2][256 * 32];
  const int tid = threadIdx.x;
  const int wave = tid >> 6, lane = tid & 63;
  const int nbx = gridDim.x;
  const int bid = xcd_swizzle(blockIdx.y * nbx + blockIdx.x, nbx * gridDim.y);
  const int m0 = (bid / nbx) * 256, n0 = (bid % nbx) * 256;
  const int lrow = lane & 15, lq = lane >> 4;
  const int wm = wave >> 2;        // 2 M-groups of 128 rows
  const int wnn = wave & 3;        // 4 N-groups of 64 cols
  const int srow = lane >> 2;
  const int scol = (lane & 3) * 8;

  floatx4 acc[8][4];
#pragma unroll
  for (int i = 0; i < 8; i++)
#pragma unroll
    for (int j = 0; j < 4; j++) acc[i][j] = (floatx4){0.f, 0.f, 0.f, 0.f};

  // 8 waves x (2 A + 2 B) gl2lds16 cover 256 rows of A and B per k-step
  auto stage = [&](int k0, int pp) {
#pragma unroll
    for (int h = 0; h < 2; h++) {
      int r0 = wave * 32 + h * 16;
      gl2lds16(A + (size_t)(m0 + r0 + srow) * K + k0 + scol, &As[pp][r0 * 32]);
      gl2lds16(Bt + (size_t)(n0 + r0 + srow) * K + k0 + scol, &Bs[pp][r0 * 32]);
    }
  };

  const int nt = K >> 5;
  stage(0, 0);
  int cur = 0;
  for (int t = 0; t < nt; t++) {
    if (t + 1 < nt) {
      stage((t + 1) << 5, cur ^ 1);
      asm volatile("s_waitcnt vmcnt(4)" ::: "memory");  // stage(t) landed
    } else {
      asm volatile("s_waitcnt vmcnt(0)" ::: "memory");
    }
    __builtin_amdgcn_sched_barrier(0);
    __builtin_amdgcn_s_barrier();
    __builtin_amdgcn_sched_barrier(0);
    short8 a[8], b[4];
#pragma unroll
    for (int i = 0; i < 8; i++)
      a[i] = *(const short8*)&As[cur][(wm * 128 + i * 16 + lrow) * 32 + lq * 8];
#pragma unroll
    for (int j = 0; j < 4; j++)
      b[j] = *(const short8*)&Bs[cur][(wnn * 64 + j * 16 + lrow) * 32 + lq * 8];
#pragma unroll
    for (int i = 0; i < 8; i++)
#pragma unroll
      for (int j = 0; j < 4; j++)
        acc[i][j] = __builtin_amdgcn_mfma_f32_16x16x32_bf16(a[i], b[j],
                                                            acc[i][j], 0, 0, 0);
    __builtin_amdgcn_sched_barrier(0);
    __builtin_amdgcn_s_barrier();
    __builtin_amdgcn_sched_barrier(0);
    cur ^= 1;
  }

#pragma unroll
  for (int i = 0; i < 8; i++) {
#pragma unroll
    for (int j = 0; j < 4; j++) {
      int colg = n0 + wnn * 64 + j * 16 + lrow;
      float bb = bias[colg];
#pragma unroll
      for (int r = 0; r < 4; r++) {
        int rowg = m0 + wm * 128 + i * 16 + lq * 4 + r;
        float v = acc[i][j][r] + bb;
        if (ACT == 0) {
          v = fmaxf(v, 0.0f);
          C0b[(size_t)rowg * N + colg] = f2bf(v);
        } else {
          v = 1e-6f + softplus_fast(v);
          if (colg < split) C0f[(size_t)rowg * split + colg] = v;
          else              C1f[(size_t)rowg * split + (colg - split)] = v;
        }
      }
    }
  }
}

// ---------------------------------------------------------------------------
extern "C" void kernel_launch(void* const* d_in, const int* in_sizes, int n_in,
                              void* d_out, int out_size, void* d_ws,
                              size_t ws_size, hipStream_t stream) {
  const float* x   = (const float*)d_in[0];
  const float* w1  = (const float*)d_in[1];  const float* b1  = (const float*)d_in[2];
  const float* w2  = (const float*)d_in[3];  const float* b2  = (const float*)d_in[4];
  const float* w3  = (const float*)d_in[5];  const float* b3  = (const float*)d_in[6];
  const float* w41 = (const float*)d_in[7];  const float* b41 = (const float*)d_in[8];
  const float* w42 = (const float*)d_in[9];  const float* b42 = (const float*)d_in[10];
  const float* w4  = (const float*)d_in[11]; const float* b4  = (const float*)d_in[12];
  const float* w5  = (const float*)d_in[13]; const float* b5  = (const float*)d_in[14];
  const float* w6  = (const float*)d_in[15]; const float* b6  = (const float*)d_in[16];
  const float* w7  = (const float*)d_in[17]; const float* b7  = (const float*)d_in[18];
  float* out = (float*)d_out;
  float* ws  = (float*)d_ws;
  ushort* wsu = (ushort*)d_ws;

  // output layout (floats): recon_al | recon_be | logalpha | logbeta | z
  float* recon_a = out;
  float* recon_b = out + 16777216;
  float* la      = out + 33554432;
  float* lb      = out + 34078720;
  float* zz      = out + 34603008;

  // ---- workspace layout (ushort offsets unless noted); peak 124 MB.
  ushort* xh   = wsu;              // [0, 16777216)            dead after fc1
  ushort* xl   = wsu + 16777216;   // [16777216, 33554432)     dead after fc1
  ushort* w1Th = wsu + 33554432;   // [.., 35651584)           dead after fc1
  ushort* w1Tl = wsu + 35651584;   // [.., 37748736)
  ushort* w2Th = wsu + 37748736;   // [.., 38797312)           dead after fc2
  ushort* w2Tl = wsu + 38797312;   // [.., 39845888)
  ushort* h1h  = wsu + 39845888;   // [.., 48234496)           dead after fc2
  ushort* h1l  = wsu + 48234496;   // [.., 56623104)
  ushort* w3Th = wsu + 16777216;   // overwrites xl AFTER fc1  dead after fc3
  ushort* w3Tl = wsu + 18874368;   // [.., 20971520)
  ushort* h2h  = wsu;              // overwrites xh AFTER fc1  dead after fc3
  ushort* h2l  = wsu + 8388608;    // [.., 16777216)
  // fc3 output: split pair (over dead w1T/w2T/h1); dead after dual_mfma
  ushort* h3h  = wsu + 20971520;   // [20971520, 37748736)
  ushort* h3l  = wsu + 37748736;   // [37748736, 54525952)
  // fc41|fc42 concat weights, transposed+split [128, 2048] over dead w3T
  ushort* wcatTh = wsu + 16777216; // [16777216, 17039360)
  ushort* wcatTl = wsu + 17039360; // [17039360, 17301504)
  // split-K partials [8][8192][128] fp32 = 33.5 MB over dead x/h2 region
  float*  Ppart = ws;              // float [0, 8388608) = ushort [0,16777216)
  // decoder (bf16), after h3 region — over dead h1l tail:
  ushort* w4T = wsu + 54525952;    // [64,2048]   -> 54657024
  ushort* w5T = wsu + 54657024;    // [1024,2048] -> 56754176
  ushort* w6T = wsu + 56754176;    // [1024,1024] -> 57802752
  ushort* w7T = wsu + 57802752;    // [4096,1024] -> 61997056
  // zb: in dead h3l region — fused sampler READS Ppart (ushort [0,16777216))
  // so zb must NOT alias it (it did pre-fusion). h3l dead after dual_mfma;
  // h4b [20971520,37748736) ends exactly at zb's start -> disjoint.
  ushort* zb  = wsu + 37748736;    // [37748736, 38273024)
  ushort* h4b = wsu + 20971520;    // [.., 37748736)    (over dead h3h)
  ushort* h5b = wsu + 524288;      // [.., 8912896)     (over dead Ppart)
  ushort* h6b = wsu + 8912896;     // [.., 17301504)    (over dead Ppart/wcat)

  dim3 blk(256);
  // ---- prep: split x and encoder weights into f16 (hi, lo*2^11) pairs
  split_f16<<<dim3(2048), blk, 0, stream>>>(x, xh, xl, 4194304);
  transpose_split_f16<<<dim3(32, 64), blk, 0, stream>>>(w1, w1Th, w1Tl, 2048, 1024);
  transpose_split_f16<<<dim3(32, 32), blk, 0, stream>>>(w2, w2Th, w2Tl, 1024, 1024);
  // ---- encoder: split-f16 MFMA (error ~1e-6 rel)
  gemm_f16x3<1><<<dim3(8, 64), blk, 0, stream>>>(xh, xl, w1Th, w1Tl, b1,
                                                 h1h, h1l, nullptr, 8192, 1024, 2048);
  transpose_split_f16<<<dim3(64, 32), blk, 0, stream>>>(w3, w3Th, w3Tl, 1024, 2048);
  gemm_f16x3<1><<<dim3(8, 64), blk, 0, stream>>>(h1h, h1l, w2Th, w2Tl, b2,
                                                 h2h, h2l, nullptr, 8192, 1024, 1024);
  // decoder weight prep (regions free only after fc2 reads h1l)
  transpose_bf16<<<dim3(64, 2),   blk, 0, stream>>>(w4, w4T, 64,   2048);
  transpose_bf16<<<dim3(32, 64),  blk, 0, stream>>>(w5, w5T, 2048, 1024);
  transpose_bf16<<<dim3(32, 32),  blk, 0, stream>>>(w6, w6T, 1024, 1024);
  transpose_bf16<<<dim3(128, 32), blk, 0, stream>>>(w7, w7T, 1024, 4096);
  // fc3 -> split pair (feeds MFMA fc41/42)
  gemm_f16x3<1><<<dim3(16, 64), blk, 0, stream>>>(h2h, h2l, w3Th, w3Tl, b3,
                                                  h3h, h3l, nullptr, 8192, 2048, 1024);
  // fc41/42: split-K MFMA; reduce fused into sampler
  transpose_split_f16<<<dim3(2, 64), blk, 0, stream>>>(w41, wcatTh, wcatTl, 2048, 64);
  transpose_split_f16<<<dim3(2, 64), blk, 0, stream>>>(w42, wcatTh + 64 * 2048,
                                                       wcatTl + 64 * 2048, 2048, 64);
  dual_mfma<<<dim3(8, 64), blk, 0, stream>>>(h3h, h3l, wcatTh, wcatTl, Ppart);
  // reparameterize (fused: reduce + exact softplus + sampling; emits bf16 z)
  gamma_sampler<<<dim3(2048), blk, 0, stream>>>(Ppart, b41, b42, la, lb, zz, zb);
  // decoder (bf16 MFMA)
  gemm_bf16<0><<<dim3(16, 64), blk, 0, stream>>>(zb,  w4T, b4, h4b, nullptr, nullptr, 8192, 2048, 64, 0);
  gemm_bf16<0><<<dim3(8, 64),  blk, 0, stream>>>(h4b, w5T, b5, h5b, nullptr, nullptr, 8192, 1024, 2048, 0);
  gemm_bf16<0><<<dim3(8, 64),  blk, 0, stream>>>(h5b, w6T, b6, h6b, nullptr, nullptr, 8192, 1024, 1024, 0);
  // fc7: 256x256-tile 8-wave kernel (512 blocks = 2/CU)
  gemm_bf16_256<3><<<dim3(16, 32), dim3(512), 0, stream>>>(
      h6b, w7T, b7, nullptr, recon_a, recon_b, 8192, 4096, 1024, 2048);
  (void)in_sizes; (void)n_in; (void)out_size; (void)ws_size;
}

// Round 8
// 901.759 us; speedup vs baseline: 1.9413x; 1.0158x over previous
//
#include <hip/hip_runtime.h>
#include <stdint.h>

#define DEVFN static __device__ __forceinline__

typedef __attribute__((ext_vector_type(8))) short short8;
typedef __attribute__((ext_vector_type(4))) float floatx4;
typedef _Float16 half8 __attribute__((ext_vector_type(8)));

// ---------------- Threefry-2x32 (20 rounds), exactly as JAX ----------------
DEVFN uint32_t rotl32(uint32_t v, int d) { return (v << d) | (v >> (32 - d)); }

DEVFN void tf2x32(uint32_t k0, uint32_t k1, uint32_t x0, uint32_t x1,
                  uint32_t& o0, uint32_t& o1) {
  uint32_t k2 = k0 ^ k1 ^ 0x1BD11BDAu;
  x0 += k0; x1 += k1;
  x0 += x1; x1 = rotl32(x1, 13); x1 ^= x0;
  x0 += x1; x1 = rotl32(x1, 15); x1 ^= x0;
  x0 += x1; x1 = rotl32(x1, 26); x1 ^= x0;
  x0 += x1; x1 = rotl32(x1, 6);  x1 ^= x0;
  x0 += k1; x1 += k2 + 1u;
  x0 += x1; x1 = rotl32(x1, 17); x1 ^= x0;
  x0 += x1; x1 = rotl32(x1, 29); x1 ^= x0;
  x0 += x1; x1 = rotl32(x1, 16); x1 ^= x0;
  x0 += x1; x1 = rotl32(x1, 24); x1 ^= x0;
  x0 += k2; x1 += k0 + 2u;
  x0 += x1; x1 = rotl32(x1, 13); x1 ^= x0;
  x0 += x1; x1 = rotl32(x1, 15); x1 ^= x0;
  x0 += x1; x1 = rotl32(x1, 26); x1 ^= x0;
  x0 += x1; x1 = rotl32(x1, 6);  x1 ^= x0;
  x0 += k0; x1 += k1 + 3u;
  x0 += x1; x1 = rotl32(x1, 17); x1 ^= x0;
  x0 += x1; x1 = rotl32(x1, 29); x1 ^= x0;
  x0 += x1; x1 = rotl32(x1, 16); x1 ^= x0;
  x0 += x1; x1 = rotl32(x1, 24); x1 ^= x0;
  x0 += k1; x1 += k2 + 4u;
  x0 += x1; x1 = rotl32(x1, 13); x1 ^= x0;
  x0 += x1; x1 = rotl32(x1, 15); x1 ^= x0;
  x0 += x1; x1 = rotl32(x1, 26); x1 ^= x0;
  x0 += x1; x1 = rotl32(x1, 6);  x1 ^= x0;
  x0 += k2; x1 += k0 + 5u;
  o0 = x0; o1 = x1;
}

// ---------------- XLA/CHLO f32 erf_inv (Giles), w = -log1p(-x^2) -----------
DEVFN float erfinv_f32(float x) {
#pragma clang fp contract(off)
  float w = -log1pf(-(x * x));
  float p;
  if (w < 5.0f) {
    w = w - 2.5f;
    p = 2.81022636e-08f;
    p = 3.43273939e-07f + p * w;
    p = -3.5233877e-06f + p * w;
    p = -4.39150654e-06f + p * w;
    p = 0.00021858087f + p * w;
    p = -0.00125372503f + p * w;
    p = -0.00417768164f + p * w;
    p = 0.246640727f + p * w;
    p = 1.50140941f + p * w;
  } else {
    w = __fsqrt_rn(w) - 3.0f;
    p = -0.000200214257f;
    p = 0.000100950558f + p * w;
    p = 0.00134934322f + p * w;
    p = -0.00367342844f + p * w;
    p = 0.00573950773f + p * w;
    p = -0.0076224613f + p * w;
    p = 0.00943887047f + p * w;
    p = 1.00167406f + p * w;
    p = 2.83297682f + p * w;
  }
  return p * x;
}

// jax.nn.softplus(x) = logaddexp(x,0) = max(x,0) + log1p(exp(-|x|))
// EXACT version (feeds discrete accept/reject via logalpha)
DEVFN float softplus_ref(float v) {
#pragma clang fp contract(off)
  return fmaxf(v, 0.0f) + log1pf(expf(-fabsf(v)));
}

// FAST version for recon outputs only (abs err ~1e-6 << 0.23 threshold)
DEVFN float softplus_fast(float v) {
  float e = __expf(-fabsf(v));
  return fmaxf(v, 0.0f) + __logf(1.0f + e);
}

// fp32 -> bf16 RNE
DEVFN ushort f2bf(float f) {
  uint32_t u = __float_as_uint(f);
  uint32_t r = (u + 0x7FFFu + ((u >> 16) & 1u)) >> 16;
  return (ushort)r;
}

// fp32 -> (f16 hi, f16 lo*2048) split. a = hi + lo/2048 + O(2^-23 |a|).
DEVFN void split2(float a, ushort& hb, ushort& lb) {
  _Float16 h = (_Float16)a;
  float r = (a - (float)h) * 2048.0f;  // a-hf exact (Sterbenz); *2^11 exact
  _Float16 l = (_Float16)r;
  hb = __builtin_bit_cast(unsigned short, h);
  lb = __builtin_bit_cast(unsigned short, l);
}

// async global->LDS, 16 B per lane; lds must be wave-uniform base
DEVFN void gl2lds16(const void* g, void* l) {
  __builtin_amdgcn_global_load_lds(
      (const __attribute__((address_space(1))) void*)g,
      (__attribute__((address_space(3))) void*)l, 16, 0, 0);
}

// XCD-chunked blockIdx swizzle (T1/m204): bijective when nwg % 8 == 0.
DEVFN int xcd_swizzle(int bid, int nwg) {
  if ((nwg & 7) == 0) return (bid & 7) * (nwg >> 3) + (bid >> 3);
  return bid;
}

// ---- T2 bank-conflict swizzle for [rows][32]-ushort LDS tiles (64B rows) ---
// Unswizzled, ds_read_b128 at (row*64B + lq*16B): rows r and r+2 share a bank
// quad -> 8-way conflict (2.94x, m136) = 8.4M SQ_LDS_BANK_CONFLICT on fc1.
// Fix (rule #21: both-sides-or-neither with global_load_lds): LDS slot
// (row, cg) holds global (row, cg ^ ((row>>1)&3)); gl2lds16 SOURCE is
// per-lane so we swizzle the source column-group; ds_read applies the same
// XOR. (row>>1)&3 == (lrow>>1)&3 for all row bases used (multiples of 16).

// ---------------- elementwise split: x -> (xh, xl) f16 pairs ----------------
__global__ __launch_bounds__(256) void split_f16(
    const float* __restrict__ in, ushort* __restrict__ oh,
    ushort* __restrict__ ol, int n4) {
  int idx = blockIdx.x * 256 + threadIdx.x;
  int stride = gridDim.x * 256;
  for (int i = idx; i < n4; i += stride) {
    float4 a = ((const float4*)in)[i];
    ushort h0, h1, h2, h3, l0, l1, l2, l3;
    split2(a.x, h0, l0); split2(a.y, h1, l1);
    split2(a.z, h2, l2); split2(a.w, h3, l3);
    ushort4 hv; hv.x = h0; hv.y = h1; hv.z = h2; hv.w = h3;
    ushort4 lv; lv.x = l0; lv.y = l1; lv.z = l2; lv.w = l3;
    ((ushort4*)oh)[i] = hv;
    ((ushort4*)ol)[i] = lv;
  }
}

// ---------------- transpose + f16-split: out*[c][r] = split(in[r][c]) -------
__global__ __launch_bounds__(256) void transpose_split_f16(
    const float* __restrict__ in, ushort* __restrict__ oh,
    ushort* __restrict__ ol, int R, int C) {
  __shared__ float tile[32][33];
  const int c0 = blockIdx.x * 32, r0 = blockIdx.y * 32;
  const int tx = threadIdx.x & 31, ty = threadIdx.x >> 5;
#pragma unroll
  for (int i = ty; i < 32; i += 8)
    tile[i][tx] = in[(size_t)(r0 + i) * C + c0 + tx];
  __syncthreads();
#pragma unroll
  for (int i = ty; i < 32; i += 8) {
    ushort hb, lb;
    split2(tile[tx][i], hb, lb);
    size_t o = (size_t)(c0 + i) * R + r0 + tx;
    oh[o] = hb; ol[o] = lb;
  }
}

// ---------------- split-f16 MFMA GEMM: C = act(A @ Bt^T + bias) -------------
// acc1 = Ah*Bh ; acc2 = Ah*Bl + Al*Bh ; result = acc1 + acc2/2048  (fp32).
// 2-deep counted-vmcnt pipeline + T2 source-swizzled LDS (see note above).
// ACT 1: relu -> split pair. ACT 2: fp32.
template <int ACT>
__global__ __launch_bounds__(256) void gemm_f16x3(
    const ushort* __restrict__ Ah, const ushort* __restrict__ Al,
    const ushort* __restrict__ Bh, const ushort* __restrict__ Bl,
    const float* __restrict__ bias, ushort* __restrict__ Oh,
    ushort* __restrict__ Ol, float* __restrict__ Of, int M, int N, int K) {
  __shared__ ushort AsH[2][128 * 32];
  __shared__ ushort AsL[2][128 * 32];
  __shared__ ushort BsH[2][128 * 32];
  __shared__ ushort BsL[2][128 * 32];
  const int tid = threadIdx.x;
  const int wave = tid >> 6, lane = tid & 63;
  const int nbx = gridDim.x;
  const int bid = xcd_swizzle(blockIdx.y * nbx + blockIdx.x, nbx * gridDim.y);
  const int m0 = (bid / nbx) * 128, n0 = (bid % nbx) * 128;
  const int lrow = lane & 15, lq = lane >> 4;
  const int wm = wave & 1, wn = wave >> 1;
  const int srow = lane >> 2;
  // source col-group swizzled: cg' = (lane&3) ^ ((srow>>1)&3)
  const int scol = (((lane & 3) ^ ((lane >> 3) & 3)) << 3);
  // read col offset swizzled identically
  const int lqs8 = ((lq ^ ((lrow >> 1) & 3)) << 3);

  floatx4 acc1[4][4], acc2[4][4];
#pragma unroll
  for (int i = 0; i < 4; i++)
#pragma unroll
    for (int j = 0; j < 4; j++) {
      acc1[i][j] = (floatx4){0.f, 0.f, 0.f, 0.f};
      acc2[i][j] = (floatx4){0.f, 0.f, 0.f, 0.f};
    }

  // 8 gl2lds16 per wave per stage (S=8)
  auto stage = [&](int k0, int pp) {
#pragma unroll
    for (int h = 0; h < 2; h++) {
      int r0 = wave * 32 + h * 16;
      gl2lds16(Ah + (size_t)(m0 + r0 + srow) * K + k0 + scol, &AsH[pp][r0 * 32]);
      gl2lds16(Al + (size_t)(m0 + r0 + srow) * K + k0 + scol, &AsL[pp][r0 * 32]);
      gl2lds16(Bh + (size_t)(n0 + r0 + srow) * K + k0 + scol, &BsH[pp][r0 * 32]);
      gl2lds16(Bl + (size_t)(n0 + r0 + srow) * K + k0 + scol, &BsL[pp][r0 * 32]);
    }
  };

  const int nt = K >> 5;
  stage(0, 0);
  int cur = 0;
  for (int t = 0; t < nt; t++) {
    if (t + 1 < nt) {
      stage((t + 1) << 5, cur ^ 1);
      asm volatile("s_waitcnt vmcnt(8)" ::: "memory");  // stage(t) landed
    } else {
      asm volatile("s_waitcnt vmcnt(0)" ::: "memory");
    }
    __builtin_amdgcn_sched_barrier(0);
    __builtin_amdgcn_s_barrier();   // all waves' stage(t) visible
    __builtin_amdgcn_sched_barrier(0);
    half8 ah[4], al[4];
#pragma unroll
    for (int i = 0; i < 4; i++) {
      ah[i] = *(const half8*)&AsH[cur][(wm * 64 + i * 16 + lrow) * 32 + lqs8];
      al[i] = *(const half8*)&AsL[cur][(wm * 64 + i * 16 + lrow) * 32 + lqs8];
    }
#pragma unroll
    for (int j = 0; j < 4; j++) {
      half8 bh = *(const half8*)&BsH[cur][(wn * 64 + j * 16 + lrow) * 32 + lqs8];
      half8 bl = *(const half8*)&BsL[cur][(wn * 64 + j * 16 + lrow) * 32 + lqs8];
#pragma unroll
      for (int i = 0; i < 4; i++) {
        acc1[i][j] = __builtin_amdgcn_mfma_f32_16x16x32_f16(ah[i], bh,
                                                            acc1[i][j], 0, 0, 0);
        acc2[i][j] = __builtin_amdgcn_mfma_f32_16x16x32_f16(ah[i], bl,
                                                            acc2[i][j], 0, 0, 0);
        acc2[i][j] = __builtin_amdgcn_mfma_f32_16x16x32_f16(al[i], bh,
                                                            acc2[i][j], 0, 0, 0);
      }
    }
    __builtin_amdgcn_sched_barrier(0);
    __builtin_amdgcn_s_barrier();   // readers of buf[cur] done -> reusable
    __builtin_amdgcn_sched_barrier(0);
    cur ^= 1;
  }

  // C/D layout: col = lane&15, row = (lane>>4)*4 + reg  [measured m89/m91]
  const float INV2048 = 4.8828125e-4f;
#pragma unroll
  for (int i = 0; i < 4; i++) {
#pragma unroll
    for (int j = 0; j < 4; j++) {
      int colg = n0 + wn * 64 + j * 16 + lrow;
      float bb = bias[colg];
#pragma unroll
      for (int r = 0; r < 4; r++) {
        int rowg = m0 + wm * 64 + i * 16 + lq * 4 + r;
        float v = acc1[i][j][r] + acc2[i][j][r] * INV2048 + bb;
        v = fmaxf(v, 0.0f);
        if (ACT == 1) {
          ushort hb, lb;
          split2(v, hb, lb);
          size_t o = (size_t)rowg * N + colg;
          Oh[o] = hb; Ol[o] = lb;
        } else {
          Of[(size_t)rowg * N + colg] = v;
        }
      }
    }
  }
}

// ---------------- fc41+fc42 via split-K MFMA ---------------------------------
// logits[8192,128] = h3(split) @ wcat(split)^T, K=2048 in 8 chunks of 256.
__global__ __launch_bounds__(256) void dual_mfma(
    const ushort* __restrict__ Ah, const ushort* __restrict__ Al,
    const ushort* __restrict__ Bh, const ushort* __restrict__ Bl,
    float* __restrict__ P) {
  __shared__ ushort AsH[128 * 32];
  __shared__ ushort AsL[128 * 32];
  __shared__ ushort BsH[128 * 32];
  __shared__ ushort BsL[128 * 32];
  const int K = 2048;
  const int tid = threadIdx.x;
  const int wave = tid >> 6, lane = tid & 63;
  const int m0 = blockIdx.y * 128;
  const int kbase = blockIdx.x * 256;
  const int lrow = lane & 15, lq = lane >> 4;
  const int wm = wave & 1, wn = wave >> 1;
  const int srow = lane >> 2;
  const int scol = (((lane & 3) ^ ((lane >> 3) & 3)) << 3);  // T2 swizzle
  const int lqs8 = ((lq ^ ((lrow >> 1) & 3)) << 3);

  floatx4 acc1[4][4], acc2[4][4];
#pragma unroll
  for (int i = 0; i < 4; i++)
#pragma unroll
    for (int j = 0; j < 4; j++) {
      acc1[i][j] = (floatx4){0.f, 0.f, 0.f, 0.f};
      acc2[i][j] = (floatx4){0.f, 0.f, 0.f, 0.f};
    }

  for (int kk = 0; kk < 256; kk += 32) {
    int k0 = kbase + kk;
#pragma unroll
    for (int h = 0; h < 2; h++) {
      int r0 = wave * 32 + h * 16;
      gl2lds16(Ah + (size_t)(m0 + r0 + srow) * K + k0 + scol, &AsH[r0 * 32]);
      gl2lds16(Al + (size_t)(m0 + r0 + srow) * K + k0 + scol, &AsL[r0 * 32]);
      gl2lds16(Bh + (size_t)(r0 + srow) * K + k0 + scol, &BsH[r0 * 32]);
      gl2lds16(Bl + (size_t)(r0 + srow) * K + k0 + scol, &BsL[r0 * 32]);
    }
    __syncthreads();
    half8 ah[4], al[4];
#pragma unroll
    for (int i = 0; i < 4; i++) {
      ah[i] = *(const half8*)&AsH[(wm * 64 + i * 16 + lrow) * 32 + lqs8];
      al[i] = *(const half8*)&AsL[(wm * 64 + i * 16 + lrow) * 32 + lqs8];
    }
#pragma unroll
    for (int j = 0; j < 4; j++) {
      half8 bh = *(const half8*)&BsH[(wn * 64 + j * 16 + lrow) * 32 + lqs8];
      half8 bl = *(const half8*)&BsL[(wn * 64 + j * 16 + lrow) * 32 + lqs8];
#pragma unroll
      for (int i = 0; i < 4; i++) {
        acc1[i][j] = __builtin_amdgcn_mfma_f32_16x16x32_f16(ah[i], bh,
                                                            acc1[i][j], 0, 0, 0);
        acc2[i][j] = __builtin_amdgcn_mfma_f32_16x16x32_f16(ah[i], bl,
                                                            acc2[i][j], 0, 0, 0);
        acc2[i][j] = __builtin_amdgcn_mfma_f32_16x16x32_f16(al[i], bh,
                                                            acc2[i][j], 0, 0, 0);
      }
    }
    __syncthreads();
  }

  const float INV2048 = 4.8828125e-4f;
#pragma unroll
  for (int i = 0; i < 4; i++) {
#pragma unroll
    for (int j = 0; j < 4; j++) {
      int colg = wn * 64 + j * 16 + lrow;
#pragma unroll
      for (int r = 0; r < 4; r++) {
        int rowg = m0 + wm * 64 + i * 16 + lq * 4 + r;
        float v = acc1[i][j][r] + acc2[i][j][r] * INV2048;
        P[((size_t)blockIdx.x * 8192 + rowg) * 128 + colg] = v;
      }
    }
  }
}

// ---------------- Marsaglia-Tsang sampler + fused split-K reduce ------------
// Reduces 8 partials (fixed k-order), EXACT softplus, writes la/lb, samples.
// JAX partitionable threefry (bits = bits1 ^ bits2 for 32-bit draws).
__global__ __launch_bounds__(256) void gamma_sampler(
    const float* __restrict__ P, const float* __restrict__ b41,
    const float* __restrict__ b42, float* __restrict__ la,
    float* __restrict__ lb, float* __restrict__ z, ushort* __restrict__ zb) {
#pragma clang fp contract(off)
  const uint32_t i = blockIdx.x * 256u + threadIdx.x;
  const int row = i >> 6, col = i & 63;
  float sa = 0.0f, sb = 0.0f;
#pragma unroll
  for (int k = 0; k < 8; k++) {
    sa += P[((size_t)k * 8192 + row) * 128 + col];
    sb += P[((size_t)k * 8192 + row) * 128 + 64 + col];
  }
  const float al = 1e-6f + softplus_ref(sa + b41[col]);
  const float be = 1e-6f + softplus_ref(sb + b42[col]);
  la[i] = al;
  lb[i] = be;

  uint32_t k1a, k1b, k2a, k2b;
  tf2x32(0u, 42u, 0u, 0u, k1a, k1b);  // split: child key = both output words
  tf2x32(0u, 42u, 0u, 1u, k2a, k2b);

  const float LO = __uint_as_float(0xBF7FFFFFu);
  const float SQRT2 = __uint_as_float(0x3FB504F3u);
  const float USCALE = 1.0f - 1e-7f;

  const float d = (al + 1.0f) - 0.33333334f;
  const float c = 1.0f / __fsqrt_rn(9.0f * d);

  float es = 0.0f, us = 0.0f;
  bool done = false;
  for (int k = 0; k < 24; k++) {
    if (__all(done)) break;
    if (!done) {
      uint32_t n = (uint32_t)k * 524288u + i;
      uint32_t o0, o1, p0, p1;
      tf2x32(k1a, k1b, 0u, n, o0, o1);
      tf2x32(k2a, k2b, 0u, n, p0, p1);
      uint32_t eb = o0 ^ o1;  // JAX: bits = bits1 ^ bits2 (32-bit path)
      uint32_t ub = p0 ^ p1;
      float f = __uint_as_float((eb >> 9) | 0x3F800000u) - 1.0f;
      float un = f * 2.0f + LO;
      un = fmaxf(LO, un);
      float e = SQRT2 * erfinv_f32(un);
      float g = __uint_as_float((ub >> 9) | 0x3F800000u) - 1.0f;
      float u = g * USCALE + 1e-7f;
      u = fmaxf(1e-7f, u);
      if (k == 0) { es = e; us = u; }
      float v = 1.0f + c * e;
      if (v > 0.0f) {
        float v3 = (v * v) * v;
        float e2 = e * e;
        bool acc = false;
        float sq = 1.0f - (0.0331f * e2) * e2;
        if (u < sq) acc = true;
        else {
          float rhs = (0.5f * e) * e + d * ((1.0f - v3) + logf(v3));
          if (logf(u) < rhs) acc = true;
        }
        if (acc) { es = e; us = u; done = true; }
      }
    }
  }
  float vv = 1.0f + c * es;
  float vs = (vv * vv) * vv;
  float t = logf(d * vs + 1e-6f) + logf(us + 1e-6f) / (al + 1e-6f);
  float zv = expf(t) / (be + 1e-6f);
  z[i] = zv;
  zb[i] = f2bf(zv);
}

// ---------------- transpose + fp32->bf16: out[c][r] = bf16(in[r][c]) --------
__global__ __launch_bounds__(256) void transpose_bf16(
    const float* __restrict__ in, ushort* __restrict__ out, int R, int C) {
  __shared__ float tile[32][33];
  const int c0 = blockIdx.x * 32, r0 = blockIdx.y * 32;
  const int tx = threadIdx.x & 31, ty = threadIdx.x >> 5;
#pragma unroll
  for (int i = ty; i < 32; i += 8)
    tile[i][tx] = in[(size_t)(r0 + i) * C + c0 + tx];
  __syncthreads();
#pragma unroll
  for (int i = ty; i < 32; i += 8)
    out[(size_t)(c0 + i) * R + r0 + tx] = f2bf(tile[tx][i]);
}

// ---------------- bf16 MFMA GEMM, 3-deep counted-vmcnt pipeline (128²) ------
template <int ACT>
__global__ __launch_bounds__(256) void gemm_bf16(
    const ushort* __restrict__ A, const ushort* __restrict__ Bt,
    const float* __restrict__ bias, ushort* __restrict__ C0b,
    float* __restrict__ C0f, float* __restrict__ C1f,
    int M, int N, int K, int split) {
  __shared__ ushort As[3][128 * 32];
  __shared__ ushort Bs[3][128 * 32];
  const int tid = threadIdx.x;
  const int wave = tid >> 6, lane = tid & 63;
  const int nbx = gridDim.x;
  const int bid = xcd_swizzle(blockIdx.y * nbx + blockIdx.x, nbx * gridDim.y);
  const int m0 = (bid / nbx) * 128, n0 = (bid % nbx) * 128;
  const int lrow = lane & 15, lq = lane >> 4;
  const int wm = wave & 1, wn = wave >> 1;
  const int srow = lane >> 2;
  const int scol = (((lane & 3) ^ ((lane >> 3) & 3)) << 3);  // T2 swizzle
  const int lqs8 = ((lq ^ ((lrow >> 1) & 3)) << 3);

  floatx4 acc[4][4];
#pragma unroll
  for (int i = 0; i < 4; i++)
#pragma unroll
    for (int j = 0; j < 4; j++) acc[i][j] = (floatx4){0.f, 0.f, 0.f, 0.f};

  auto stage = [&](int k0, int pp) {
#pragma unroll
    for (int h = 0; h < 2; h++) {
      int r0 = wave * 32 + h * 16;
      gl2lds16(A + (size_t)(m0 + r0 + srow) * K + k0 + scol, &As[pp][r0 * 32]);
      gl2lds16(Bt + (size_t)(n0 + r0 + srow) * K + k0 + scol, &Bs[pp][r0 * 32]);
    }
  };

  const int nt = K >> 5;  // >= 2 for all layers (K >= 64)
  stage(0, 0);
  stage(32, 1);
  int cur = 0;
  for (int t = 0; t < nt; t++) {
    if (t + 2 < nt) {
      int nb = cur + 2; if (nb >= 3) nb -= 3;
      stage((t + 2) << 5, nb);
      asm volatile("s_waitcnt vmcnt(8)" ::: "memory");  // stage(t) landed
    } else if (t + 1 < nt) {
      asm volatile("s_waitcnt vmcnt(4)" ::: "memory");
    } else {
      asm volatile("s_waitcnt vmcnt(0)" ::: "memory");
    }
    __builtin_amdgcn_sched_barrier(0);
    __builtin_amdgcn_s_barrier();   // all waves' stage(t) visible
    __builtin_amdgcn_sched_barrier(0);
    short8 a[4], b[4];
#pragma unroll
    for (int i = 0; i < 4; i++) {
      a[i] = *(const short8*)&As[cur][(wm * 64 + i * 16 + lrow) * 32 + lqs8];
      b[i] = *(const short8*)&Bs[cur][(wn * 64 + i * 16 + lrow) * 32 + lqs8];
    }
#pragma unroll
    for (int i = 0; i < 4; i++)
#pragma unroll
      for (int j = 0; j < 4; j++)
        acc[i][j] = __builtin_amdgcn_mfma_f32_16x16x32_bf16(a[i], b[j],
                                                            acc[i][j], 0, 0, 0);
    __builtin_amdgcn_sched_barrier(0);
    __builtin_amdgcn_s_barrier();   // readers of buf[cur] done -> reusable
    __builtin_amdgcn_sched_barrier(0);
    cur = cur + 1; if (cur == 3) cur = 0;
  }

#pragma unroll
  for (int i = 0; i < 4; i++) {
#pragma unroll
    for (int j = 0; j < 4; j++) {
      int colg = n0 + wn * 64 + j * 16 + lrow;
      float bb = bias[colg];
#pragma unroll
      for (int r = 0; r < 4; r++) {
        int rowg = m0 + wm * 64 + i * 16 + lq * 4 + r;
        float v = acc[i][j][r] + bb;
        if (ACT == 0) {
          v = fmaxf(v, 0.0f);
          C0b[(size_t)rowg * N + colg] = f2bf(v);
        } else {
          v = 1e-6f + softplus_fast(v);
          if (colg < split) C0f[(size_t)rowg * split + colg] = v;
          else              C1f[(size_t)rowg * split + (colg - split)] = v;
        }
      }
    }
  }
}

// ---------------- bf16 MFMA GEMM, 256x256 tile, 8 waves, 2-deep pipeline ----
template <int ACT>
__global__ __launch_bounds__(512) void gemm_bf16_256(
    const ushort* __restrict__ A, const ushort* __restrict__ Bt,
    const float* __restrict__ bias, ushort* __restrict__ C0b,
    float* __restrict__ C0f, float* __restrict__ C1f,
    int M, int N, int K, int split) {
  __shared__ ushort As[2][256 * 32];
  __shared__ ushort Bs[2][256 * 32];
  const int tid = threadIdx.x;
  const int wave = tid >> 6, lane = tid & 63;
  const int nbx = gridDim.x;
  const int bid = xcd_swizzle(blockIdx.y * nbx + blockIdx.x, nbx * gridDim.y);
  const int m0 = (bid / nbx) * 256, n0 = (bid % nbx) * 256;
  const int lrow = lane & 15, lq = lane >> 4;
  const int wm = wave >> 2;        // 2 M-groups of 128 rows
  const int wnn = wave & 3;        // 4 N-groups of 64 cols
  const int srow = lane >> 2;
  const int scol = (((lane & 3) ^ ((lane >> 3) & 3)) << 3);  // T2 swizzle
  const int lqs8 = ((lq ^ ((lrow >> 1) & 3)) << 3);

  floatx4 acc[8][4];
#pragma unroll
  for (int i = 0; i < 8; i++)
#pragma unroll
    for (int j = 0; j < 4; j++) acc[i][j] = (floatx4){0.f, 0.f, 0.f, 0.f};

  auto stage = [&](int k0, int pp) {
#pragma unroll
    for (int h = 0; h < 2; h++) {
      int r0 = wave * 32 + h * 16;
      gl2lds16(A + (size_t)(m0 + r0 + srow) * K + k0 + scol, &As[pp][r0 * 32]);
      gl2lds16(Bt + (size_t)(n0 + r0 + srow) * K + k0 + scol, &Bs[pp][r0 * 32]);
    }
  };

  const int nt = K >> 5;
  stage(0, 0);
  int cur = 0;
  for (int t = 0; t < nt; t++) {
    if (t + 1 < nt) {
      stage((t + 1) << 5, cur ^ 1);
      asm volatile("s_waitcnt vmcnt(4)" ::: "memory");  // stage(t) landed
    } else {
      asm volatile("s_waitcnt vmcnt(0)" ::: "memory");
    }
    __builtin_amdgcn_sched_barrier(0);
    __builtin_amdgcn_s_barrier();
    __builtin_amdgcn_sched_barrier(0);
    short8 a[8], b[4];
#pragma unroll
    for (int i = 0; i < 8; i++)
      a[i] = *(const short8*)&As[cur][(wm * 128 + i * 16 + lrow) * 32 + lqs8];
#pragma unroll
    for (int j = 0; j < 4; j++)
      b[j] = *(const short8*)&Bs[cur][(wnn * 64 + j * 16 + lrow) * 32 + lqs8];
#pragma unroll
    for (int i = 0; i < 8; i++)
#pragma unroll
      for (int j = 0; j < 4; j++)
        acc[i][j] = __builtin_amdgcn_mfma_f32_16x16x32_bf16(a[i], b[j],
                                                            acc[i][j], 0, 0, 0);
    __builtin_amdgcn_sched_barrier(0);
    __builtin_amdgcn_s_barrier();
    __builtin_amdgcn_sched_barrier(0);
    cur ^= 1;
  }

#pragma unroll
  for (int i = 0; i < 8; i++) {
#pragma unroll
    for (int j = 0; j < 4; j++) {
      int colg = n0 + wnn * 64 + j * 16 + lrow;
      float bb = bias[colg];
#pragma unroll
      for (int r = 0; r < 4; r++) {
        int rowg = m0 + wm * 128 + i * 16 + lq * 4 + r;
        float v = acc[i][j][r] + bb;
        if (ACT == 0) {
          v = fmaxf(v, 0.0f);
          C0b[(size_t)rowg * N + colg] = f2bf(v);
        } else {
          v = 1e-6f + softplus_fast(v);
          if (colg < split) C0f[(size_t)rowg * split + colg] = v;
          else              C1f[(size_t)rowg * split + (colg - split)] = v;
        }
      }
    }
  }
}

// ---------------------------------------------------------------------------
extern "C" void kernel_launch(void* const* d_in, const int* in_sizes, int n_in,
                              void* d_out, int out_size, void* d_ws,
                              size_t ws_size, hipStream_t stream) {
  const float* x   = (const float*)d_in[0];
  const float* w1  = (const float*)d_in[1];  const float* b1  = (const float*)d_in[2];
  const float* w2  = (const float*)d_in[3];  const float* b2  = (const float*)d_in[4];
  const float* w3  = (const float*)d_in[5];  const float* b3  = (const float*)d_in[6];
  const float* w41 = (const float*)d_in[7];  const float* b41 = (const float*)d_in[8];
  const float* w42 = (const float*)d_in[9];  const float* b42 = (const float*)d_in[10];
  const float* w4  = (const float*)d_in[11]; const float* b4  = (const float*)d_in[12];
  const float* w5  = (const float*)d_in[13]; const float* b5  = (const float*)d_in[14];
  const float* w6  = (const float*)d_in[15]; const float* b6  = (const float*)d_in[16];
  const float* w7  = (const float*)d_in[17]; const float* b7  = (const float*)d_in[18];
  float* out = (float*)d_out;
  float* ws  = (float*)d_ws;
  ushort* wsu = (ushort*)d_ws;

  // output layout (floats): recon_al | recon_be | logalpha | logbeta | z
  float* recon_a = out;
  float* recon_b = out + 16777216;
  float* la      = out + 33554432;
  float* lb      = out + 34078720;
  float* zz      = out + 34603008;

  // ---- workspace layout (ushort offsets unless noted); peak 124 MB.
  ushort* xh   = wsu;              // [0, 16777216)            dead after fc1
  ushort* xl   = wsu + 16777216;   // [16777216, 33554432)     dead after fc1
  ushort* w1Th = wsu + 33554432;   // [.., 35651584)           dead after fc1
  ushort* w1Tl = wsu + 35651584;   // [.., 37748736)
  ushort* w2Th = wsu + 37748736;   // [.., 38797312)           dead after fc2
  ushort* w2Tl = wsu + 38797312;   // [.., 39845888)
  ushort* h1h  = wsu + 39845888;   // [.., 48234496)           dead after fc2
  ushort* h1l  = wsu + 48234496;   // [.., 56623104)
  ushort* w3Th = wsu + 16777216;   // overwrites xl AFTER fc1  dead after fc3
  ushort* w3Tl = wsu + 18874368;   // [.., 20971520)
  ushort* h2h  = wsu;              // overwrites xh AFTER fc1  dead after fc3
  ushort* h2l  = wsu + 8388608;    // [.., 16777216)
  // fc3 output: split pair (over dead w1T/w2T/h1); dead after dual_mfma
  ushort* h3h  = wsu + 20971520;   // [20971520, 37748736)
  ushort* h3l  = wsu + 37748736;   // [37748736, 54525952)
  // fc41|fc42 concat weights, transposed+split [128, 2048] over dead w3T
  ushort* wcatTh = wsu + 16777216; // [16777216, 17039360)
  ushort* wcatTl = wsu + 17039360; // [17039360, 17301504)
  // split-K partials [8][8192][128] fp32 = 33.5 MB over dead x/h2 region
  float*  Ppart = ws;              // float [0, 8388608) = ushort [0,16777216)
  // decoder (bf16), after h3 region — over dead h1l tail:
  ushort* w4T = wsu + 54525952;    // [64,2048]   -> 54657024
  ushort* w5T = wsu + 54657024;    // [1024,2048] -> 56754176
  ushort* w6T = wsu + 56754176;    // [1024,1024] -> 57802752
  ushort* w7T = wsu + 57802752;    // [4096,1024] -> 61997056
  // zb in dead h3l region (sampler reads Ppart so zb must not alias it)
  ushort* zb  = wsu + 37748736;    // [37748736, 38273024)
  ushort* h4b = wsu + 20971520;    // [.., 37748736)    (over dead h3h)
  ushort* h5b = wsu + 524288;      // [.., 8912896)     (over dead Ppart)
  ushort* h6b = wsu + 8912896;     // [.., 17301504)    (over dead Ppart/wcat)

  dim3 blk(256);
  // ---- prep: split x and encoder weights into f16 (hi, lo*2^11) pairs
  split_f16<<<dim3(2048), blk, 0, stream>>>(x, xh, xl, 4194304);
  transpose_split_f16<<<dim3(32, 64), blk, 0, stream>>>(w1, w1Th, w1Tl, 2048, 1024);
  transpose_split_f16<<<dim3(32, 32), blk, 0, stream>>>(w2, w2Th, w2Tl, 1024, 1024);
  // ---- encoder: split-f16 MFMA (error ~1e-6 rel)
  gemm_f16x3<1><<<dim3(8, 64), blk, 0, stream>>>(xh, xl, w1Th, w1Tl, b1,
                                                 h1h, h1l, nullptr, 8192, 1024, 2048);
  transpose_split_f16<<<dim3(64, 32), blk, 0, stream>>>(w3, w3Th, w3Tl, 1024, 2048);
  gemm_f16x3<1><<<dim3(8, 64), blk, 0, stream>>>(h1h, h1l, w2Th, w2Tl, b2,
                                                 h2h, h2l, nullptr, 8192, 1024, 1024);
  // decoder weight prep (regions free only after fc2 reads h1l)
  transpose_bf16<<<dim3(64, 2),   blk, 0, stream>>>(w4, w4T, 64,   2048);
  transpose_bf16<<<dim3(32, 64),  blk, 0, stream>>>(w5, w5T, 2048, 1024);
  transpose_bf16<<<dim3(32, 32),  blk, 0, stream>>>(w6, w6T, 1024, 1024);
  transpose_bf16<<<dim3(128, 32), blk, 0, stream>>>(w7, w7T, 1024, 4096);
  // fc3 -> split pair (feeds MFMA fc41/42)
  gemm_f16x3<1><<<dim3(16, 64), blk, 0, stream>>>(h2h, h2l, w3Th, w3Tl, b3,
                                                  h3h, h3l, nullptr, 8192, 2048, 1024);
  // fc41/42: split-K MFMA; reduce fused into sampler
  transpose_split_f16<<<dim3(2, 64), blk, 0, stream>>>(w41, wcatTh, wcatTl, 2048, 64);
  transpose_split_f16<<<dim3(2, 64), blk, 0, stream>>>(w42, wcatTh + 64 * 2048,
                                                       wcatTl + 64 * 2048, 2048, 64);
  dual_mfma<<<dim3(8, 64), blk, 0, stream>>>(h3h, h3l, wcatTh, wcatTl, Ppart);
  // reparameterize (fused: reduce + exact softplus + sampling; emits bf16 z)
  gamma_sampler<<<dim3(2048), blk, 0, stream>>>(Ppart, b41, b42, la, lb, zz, zb);
  // decoder (bf16 MFMA)
  gemm_bf16<0><<<dim3(16, 64), blk, 0, stream>>>(zb,  w4T, b4, h4b, nullptr, nullptr, 8192, 2048, 64, 0);
  gemm_bf16<0><<<dim3(8, 64),  blk, 0, stream>>>(h4b, w5T, b5, h5b, nullptr, nullptr, 8192, 1024, 2048, 0);
  gemm_bf16<0><<<dim3(8, 64),  blk, 0, stream>>>(h5b, w6T, b6, h6b, nullptr, nullptr, 8192, 1024, 1024, 0);
  // fc7: 256x256-tile 8-wave kernel (512 blocks = 2/CU)
  gemm_bf16_256<3><<<dim3(16, 32), dim3(512), 0, stream>>>(
      h6b, w7T, b7, nullptr, recon_a, recon_b, 8192, 4096, 1024, 2048);
  (void)in_sizes; (void)n_in; (void)out_size; (void)ws_size;
}